// Round 3
// baseline (940.444 us; speedup 1.0000x reference)
//
#include <hip/hip_runtime.h>

#define BB 8
#define NN 4096
#define DD 256
#define HH 4
#define DHH 64
#define KPP 256
#define KNN 128

typedef float f32x4 __attribute__((ext_vector_type(4)));
typedef short bf16x8 __attribute__((ext_vector_type(8)));

#define FLAG_TRANSB 1
#define FLAG_RELU   2

__device__ __forceinline__ float bf2f(unsigned short u){
  union { unsigned int i; float f; } v; v.i = ((unsigned int)u) << 16; return v.f;
}
__device__ __forceinline__ unsigned short f2bf(float f){
  union { float f; unsigned int i; } v; v.f = f;
  return (unsigned short)((v.i + 0x7FFFu + ((v.i >> 16) & 1u)) >> 16);
}
__device__ __forceinline__ void gload16(const void* g, void* l){
  __builtin_amdgcn_global_load_lds((const __attribute__((address_space(1))) void*)g,
                                   (__attribute__((address_space(3))) void*)l, 16, 0, 0);
}

// ---------------- masked-mean stats (2-stage) ----------------
__global__ void stats_part(const float* __restrict__ x, const int* __restrict__ mask,
                           float* __restrict__ part, float* __restrict__ pcnt){
  int b = blockIdx.y, c = blockIdx.x, d = threadIdx.x;
  int n0 = c * 128;
  float sp = 0.f, sn = 0.f; int cp = 0, cn = 0;
  const float* xb = x + ((long)b*NN + n0)*DD + d;
  const int* mb = mask + (long)b*NN + n0;
  for (int r = 0; r < 128; r++){
    int mv = mb[r];
    float v = xb[(long)r*DD];
    if (mv == 1){ sp += v; cp++; }
    else if (mv == -1){ sn += v; cn++; }
  }
  part[(((long)(b*32+c)*2+0)*DD)+d] = sp;
  part[(((long)(b*32+c)*2+1)*DD)+d] = sn;
  if (d == 0){ pcnt[(b*32+c)*2+0] = (float)cp; pcnt[(b*32+c)*2+1] = (float)cn; }
}

__global__ void stats_final(const float* __restrict__ part, const float* __restrict__ pcnt,
                            float* __restrict__ posq){
  int b = blockIdx.x, d = threadIdx.x;
  float sp=0.f, sn=0.f, cp=0.f, cn=0.f;
  for (int c = 0; c < 32; c++){
    sp += part[(((long)(b*32+c)*2+0)*DD)+d];
    sn += part[(((long)(b*32+c)*2+1)*DD)+d];
    cp += pcnt[(b*32+c)*2+0];
    cn += pcnt[(b*32+c)*2+1];
  }
  posq[(long)(b*2+0)*DD + d] = sp / (cp + 1e-6f);
  posq[(long)(b*2+1)*DD + d] = sn / (cn + 1e-6f);
}

// ---------------- sim vectors: v = W @ q, c = b . q ----------------
__global__ void sim_vec(const float* __restrict__ Wp, const float* __restrict__ bp,
                        const float* __restrict__ Wn, const float* __restrict__ bn,
                        const float* __restrict__ posq, float* __restrict__ vvec,
                        float* __restrict__ cscal){
  int b = blockIdx.x, k = threadIdx.x;
  const float* qp = posq + (long)(b*2+0)*DD;
  const float* qn = posq + (long)(b*2+1)*DD;
  float vp = 0.f, vn = 0.f;
  for (int j = 0; j < DD; j++){ vp += Wp[(long)k*DD+j]*qp[j]; vn += Wn[(long)k*DD+j]*qn[j]; }
  vvec[(long)(b*2+0)*DD+k] = vp; vvec[(long)(b*2+1)*DD+k] = vn;
  __shared__ float red[256];
  red[k] = bp[k]*qp[k];
  __syncthreads();
  for (int s = 128; s > 0; s >>= 1){ if (k < s) red[k] += red[k+s]; __syncthreads(); }
  if (k == 0) cscal[b*2+0] = red[0];
  __syncthreads();
  red[k] = bn[k]*qn[k];
  __syncthreads();
  for (int s = 128; s > 0; s >>= 1){ if (k < s) red[k] += red[k+s]; __syncthreads(); }
  if (k == 0) cscal[b*2+1] = red[0];
}

// ---------------- fused sims + LN-core of x ----------------
// one wave per row: sims -> simP/simN, (x-m)/sqrt(var) -> xhat (bf16)
__global__ void sim_norm_kernel(const float* __restrict__ x, const float* __restrict__ vvec,
                                const float* __restrict__ cscal,
                                float* __restrict__ simP, float* __restrict__ simN,
                                unsigned short* __restrict__ xhat){
  int b = blockIdx.y;
  int w = threadIdx.x >> 6, lane = threadIdx.x & 63;
  int n = blockIdx.x*4 + w;
  long row = (long)b*NN + n;
  const float4* xr = (const float4*)(x + row*DD);
  float4 xv = xr[lane];
  float4 a = ((const float4*)(vvec + (long)(b*2+0)*DD))[lane];
  float4 c = ((const float4*)(vvec + (long)(b*2+1)*DD))[lane];
  float sp = xv.x*a.x + xv.y*a.y + xv.z*a.z + xv.w*a.w;
  float sn = xv.x*c.x + xv.y*c.y + xv.z*c.z + xv.w*c.w;
  float s  = xv.x+xv.y+xv.z+xv.w;
  float q  = xv.x*xv.x+xv.y*xv.y+xv.z*xv.z+xv.w*xv.w;
  for (int off = 32; off; off >>= 1){
    sp += __shfl_xor(sp, off); sn += __shfl_xor(sn, off);
    s  += __shfl_xor(s, off);  q  += __shfl_xor(q, off);
  }
  float m = s*(1.f/256.f);
  float var = q*(1.f/256.f) - m*m;
  float rinv = rsqrtf(var + 1e-5f);
  ushort4 o;
  o.x = f2bf((xv.x-m)*rinv); o.y = f2bf((xv.y-m)*rinv);
  o.z = f2bf((xv.z-m)*rinv); o.w = f2bf((xv.w-m)*rinv);
  ((ushort4*)(xhat + row*DD))[lane] = o;
  if (lane == 0){
    float zp = sp + cscal[b*2+0], zn = sn + cscal[b*2+1];
    simP[row] = 1.f/(1.f+expf(-zp));
    simN[row] = 1.f/(1.f+expf(-zn));
  }
}

// ---------------- exact top-k via 3-pass radix select ----------------
// sims are sigmoid outputs: positive floats -> bit pattern is monotone.
__global__ __launch_bounds__(256) void topk_radix(const float* __restrict__ simP,
                                                  const float* __restrict__ simN,
                                                  int* __restrict__ idxb, float* __restrict__ wb){
  __shared__ unsigned int vals[4096];
  __shared__ unsigned int hist[4096];
  __shared__ unsigned short eql[4096];
  __shared__ unsigned int sB1, sRem1, sB2, sRem2, sT, sCG, sCnt, sEq;
  int id = blockIdx.x; int sgn = id & 1, b = id >> 1;
  int K = (sgn == 0) ? KPP : KNN;
  const float* s = (sgn == 0 ? simP : simN) + (long)b*NN;
  int t = threadIdx.x;
  for (int i = t; i < 4096; i += 256){ vals[i] = __float_as_uint(s[i]); hist[i] = 0; }
  __syncthreads();
  // pass 1: bits [31:20]
  for (int i = t; i < 4096; i += 256) atomicAdd(&hist[vals[i] >> 20], 1u);
  __syncthreads();
  if (t == 0){
    unsigned int c = 0; int B = 4095;
    for (; B >= 0; B--){ c += hist[B]; if (c >= (unsigned)K) break; }
    sB1 = B; sRem1 = K - (c - hist[B]); sCG = c - hist[B];
  }
  __syncthreads();
  unsigned int B1 = sB1; unsigned int rem1 = sRem1;
  for (int i = t; i < 4096; i += 256) hist[i] = 0;
  __syncthreads();
  // pass 2: bits [19:8] among top12==B1
  for (int i = t; i < 4096; i += 256){
    unsigned v = vals[i];
    if ((v >> 20) == B1) atomicAdd(&hist[(v >> 8) & 0xFFFu], 1u);
  }
  __syncthreads();
  if (t == 0){
    unsigned int c = 0; int B = 4095;
    for (; B >= 0; B--){ c += hist[B]; if (c >= rem1) break; }
    sB2 = B; sRem2 = rem1 - (c - hist[B]); sCG += c - hist[B];
  }
  __syncthreads();
  unsigned int B2 = sB2; unsigned int rem2 = sRem2;
  unsigned int pre = (B1 << 12) | B2;  // bits [31:8]
  hist[t] = 0;
  __syncthreads();
  // pass 3: bits [7:0] among prefix==pre
  for (int i = t; i < 4096; i += 256){
    unsigned v = vals[i];
    if ((v >> 8) == pre) atomicAdd(&hist[v & 0xFFu], 1u);
  }
  __syncthreads();
  if (t == 0){
    unsigned int c = 0; int B = 255;
    for (; B >= 0; B--){ c += hist[B]; if (c >= rem2) break; }
    sT = (pre << 8) | (unsigned)B; sCG += c - hist[B];
    sCnt = 0; sEq = 0;
  }
  __syncthreads();
  unsigned int T = sT, cg = sCG;
  int* oi = idxb + (long)id*256;
  float* ow = wb + (long)id*256;
  for (int i = t; i < 4096; i += 256){
    unsigned v = vals[i];
    if (v > T){ unsigned p = atomicAdd(&sCnt, 1u); oi[p] = i; ow[p] = __uint_as_float(v); }
    else if (v == T){ unsigned e = atomicAdd(&sEq, 1u); eql[e] = (unsigned short)i; }
  }
  __syncthreads();
  int ne = K - (int)cg;          // take ne equals, lowest indices (jax tie-break)
  int eqn = (int)sEq;
  for (int e = t; e < eqn; e += 256){
    int myi = eql[e]; int r = 0;
    for (int e2 = 0; e2 < eqn; e2++) r += (eql[e2] < myi);
    if (r < ne){ oi[cg + r] = myi; ow[cg + r] = __uint_as_float(T); }
  }
}

// ---------------- gather masked nodes (stacked pos 0-255, neg 256-383) ----------------
__global__ void gather_nodes(const float* __restrict__ x, const int* __restrict__ idxb,
                             const float* __restrict__ wb, float* __restrict__ node){
  int b = blockIdx.y, i = blockIdx.x, d = threadIdx.x;
  int sgn = (i < KPP) ? 0 : 1;
  int ii = (sgn == 0) ? i : i - KPP;
  int idx = idxb[(long)(b*2+sgn)*256+ii];
  float w = wb[(long)(b*2+sgn)*256+ii];
  float val = (w > 0.6f) ? x[((long)b*NN + idx)*DD + d] : 0.f;
  node[((long)b*384 + i)*DD + d] = val;
}

// ---------------- dual row softmax ----------------
__global__ void softmax_dual(float* __restrict__ A0, int L0, int rpb0, long bs0, int rows0,
                             float* __restrict__ A1, int L1, int rpb1, long bs1, int rows1){
  int w = threadIdx.x >> 6, lane = threadIdx.x & 63;
  long row = (long)blockIdx.x*4 + w;
  float* A; int L, rpb; long bs;
  if (row < rows0){ A = A0; L = L0; rpb = rpb0; bs = bs0; }
  else { row -= rows0; if (row >= rows1) return; A = A1; L = L1; rpb = rpb1; bs = bs1; }
  int b = (int)(row / rpb), r = (int)(row % rpb);
  float* a = A + (long)b*bs + (long)r*L;
  int e = L >> 6;
  float vals[4]; float mx = -1e30f;
  for (int j = 0; j < e; j++){ vals[j] = a[lane*e+j]; mx = fmaxf(mx, vals[j]); }
  for (int off = 32; off; off >>= 1) mx = fmaxf(mx, __shfl_xor(mx, off));
  float sum = 0.f;
  for (int j = 0; j < e; j++){ vals[j] = expf(vals[j]-mx); sum += vals[j]; }
  for (int off = 32; off; off >>= 1) sum += __shfl_xor(sum, off);
  float rinv = 1.f/sum;
  for (int j = 0; j < e; j++) a[lane*e+j] = vals[j]*rinv;
}

// ---------------- row LayerNorm core (no affine) f32 -> bf16 ----------------
__global__ void rownorm_kernel(const float* __restrict__ X, unsigned short* __restrict__ Y, int rows){
  int w = threadIdx.x >> 6, lane = threadIdx.x & 63;
  long row = (long)blockIdx.x*4 + w;
  if (row >= rows) return;
  const float4* xr = (const float4*)(X + row*DD);
  float4 xv = xr[lane];
  float s = xv.x+xv.y+xv.z+xv.w;
  float q = xv.x*xv.x+xv.y*xv.y+xv.z*xv.z+xv.w*xv.w;
  for (int off = 32; off; off >>= 1){ s += __shfl_xor(s, off); q += __shfl_xor(q, off); }
  float m = s*(1.f/256.f);
  float var = q*(1.f/256.f) - m*m;
  float rinv = rsqrtf(var + 1e-5f);
  ushort4 o;
  o.x = f2bf((xv.x-m)*rinv); o.y = f2bf((xv.y-m)*rinv);
  o.z = f2bf((xv.z-m)*rinv); o.w = f2bf((xv.w-m)*rinv);
  ((ushort4*)(Y + row*DD))[lane] = o;
}

// ---------------- weight fold: BT[n][k] = g[k]*W[k][n] (bf16) ----------------
struct FoldArgs { const float* W[9]; const float* g[9]; unsigned short* BT[9]; };
struct BiasArgs { const float* W[7]; const float* b[7]; const float* addb[7]; float* out[7]; };

__global__ void fold_w(FoldArgs fa){
  int m = blockIdx.y, tile = blockIdx.x, t = threadIdx.x;
  const float* W = fa.W[m]; const float* g = fa.g[m]; unsigned short* BT = fa.BT[m];
  __shared__ float T[64][65];
  int tn = (tile & 3)*64, tk = (tile >> 2)*64;
  #pragma unroll 4
  for (int p = 0; p < 16; p++){
    int kl = p*4 + (t >> 6), nl = t & 63;
    float v = W[(long)(tk+kl)*256 + tn + nl];
    if (g) v *= g[tk+kl];
    T[kl][nl] = v;
  }
  __syncthreads();
  #pragma unroll 4
  for (int p = 0; p < 16; p++){
    int nl = p*4 + (t >> 6), kl = t & 63;
    BT[(long)(tn+nl)*256 + tk + kl] = f2bf(T[kl][nl]);
  }
}

__global__ void fold_b(BiasArgs ba){
  int m = blockIdx.x, n = threadIdx.x;
  const float* W = ba.W[m]; const float* b = ba.b[m];
  float s = (ba.addb[m] != nullptr) ? ba.addb[m][n] : 0.f;
  for (int k = 0; k < 256; k++) s += b[k]*W[(long)k*256+n];
  ba.out[m][n] = s;
}

// ---------------- multi-parameter f32 GEMM 64x64 (GCN path) ----------------
struct GP {
  const float* A; long sAb; int lda;
  const float* B; long sBb; int ldb;
  float* C; long sCb; int ldc;
  const int* pidx; const float* pe;   // optional epilogue: C += pe[pidx[b*512+row]*256 + col]
  int M, N, K; float alpha; int flags;
};
struct GP4 { GP p[4]; };

__global__ __launch_bounds__(256) void gemm_multi(GP4 g4){
  GP p = g4.p[blockIdx.z >> 3];
  int b = blockIdx.z & 7;
  int m0 = blockIdx.y*64, n0 = blockIdx.x*64;
  if (m0 >= p.M || n0 >= p.N) return;
  __shared__ __align__(16) unsigned short As[64*40];
  __shared__ __align__(16) unsigned short Bs[64*40];
  const float* Ab = p.A + (long)b*p.sAb;
  const float* Bb = p.B + (long)b*p.sBb;
  int t = threadIdx.x;
  int w = t >> 6, lane = t & 63, lrowi = lane & 15, lquad = lane >> 4;
  int wm = w >> 1, wn = w & 1;
  f32x4 acc[2][2];
  #pragma unroll
  for (int i = 0; i < 2; i++)
    #pragma unroll
    for (int j = 0; j < 2; j++) acc[i][j] = (f32x4){0.f,0.f,0.f,0.f};
  int am = t >> 2, akq = t & 3;
  for (int k0 = 0; k0 < p.K; k0 += 32){
    {
      const float4* s4 = (const float4*)(Ab + (long)(m0+am)*p.lda + k0 + akq*8);
      float4 u = s4[0], vv = s4[1];
      unsigned short tmp[8];
      tmp[0]=f2bf(u.x); tmp[1]=f2bf(u.y); tmp[2]=f2bf(u.z); tmp[3]=f2bf(u.w);
      tmp[4]=f2bf(vv.x); tmp[5]=f2bf(vv.y); tmp[6]=f2bf(vv.z); tmp[7]=f2bf(vv.w);
      *(uint4*)(&As[am*40 + akq*8]) = *(uint4*)tmp;
    }
    if (p.flags & FLAG_TRANSB){
      const float4* s4 = (const float4*)(Bb + (long)(n0+am)*p.ldb + k0 + akq*8);
      float4 u = s4[0], vv = s4[1];
      unsigned short tmp[8];
      tmp[0]=f2bf(u.x); tmp[1]=f2bf(u.y); tmp[2]=f2bf(u.z); tmp[3]=f2bf(u.w);
      tmp[4]=f2bf(vv.x); tmp[5]=f2bf(vv.y); tmp[6]=f2bf(vv.z); tmp[7]=f2bf(vv.w);
      *(uint4*)(&Bs[am*40 + akq*8]) = *(uint4*)tmp;
    } else {
      int bn = t & 63, bkb = (t >> 6)*8;
      #pragma unroll
      for (int j = 0; j < 8; j++)
        Bs[bn*40 + bkb + j] = f2bf(Bb[(long)(k0+bkb+j)*p.ldb + n0 + bn]);
    }
    __syncthreads();
    bf16x8 af[2], bfr[2];
    #pragma unroll
    for (int i = 0; i < 2; i++)
      af[i] = *(const bf16x8*)(&As[(wm*32 + i*16 + lrowi)*40 + lquad*8]);
    #pragma unroll
    for (int j = 0; j < 2; j++)
      bfr[j] = *(const bf16x8*)(&Bs[(wn*32 + j*16 + lrowi)*40 + lquad*8]);
    #pragma unroll
    for (int i = 0; i < 2; i++)
      #pragma unroll
      for (int j = 0; j < 2; j++)
        acc[i][j] = __builtin_amdgcn_mfma_f32_16x16x32_bf16(af[i], bfr[j], acc[i][j], 0, 0, 0);
    __syncthreads();
  }
  float* Cb = p.C + (long)b*p.sCb;
  #pragma unroll
  for (int i = 0; i < 2; i++)
    #pragma unroll
    for (int j = 0; j < 2; j++){
      int col = n0 + wn*32 + j*16 + lrowi;
      #pragma unroll
      for (int r = 0; r < 4; r++){
        int row = m0 + wm*32 + i*16 + lquad*4 + r;
        float v = p.alpha*acc[i][j][r];
        if (p.flags & FLAG_RELU) v = fmaxf(v, 0.f);
        if (p.pidx != nullptr){
          int idx = p.pidx[b*512 + row];
          v += p.pe[(long)idx*256 + col];
        }
        Cb[(long)row*p.ldc + col] = v;
      }
    }
}

// ---------------- fast 128x128 bf16 GEMM (K=256), global_load_lds staging ----------------
// C = R + gate .* (A @ BT^T + bias)
template<typename OT, bool RES, bool GATE>
__global__ __launch_bounds__(256) void gemm128(
    const unsigned short* __restrict__ A, long sAb,
    const unsigned short* __restrict__ BT,
    OT* __restrict__ C, long sCb, int ldc,
    const float* __restrict__ R, long sRb,
    const float* __restrict__ bias, const float* __restrict__ gate)
{
  __shared__ __align__(16) unsigned short As[4096];
  __shared__ __align__(16) unsigned short Bs[4096];
  int t = threadIdx.x;
  int w = t >> 6, lane = t & 63, lrowi = lane & 15, lquad = lane >> 4;
  int wm = w >> 1, wn = w & 1;
  int m0 = blockIdx.y*128, n0 = blockIdx.x*128;
  const unsigned short* Ab = A + (long)blockIdx.z*sAb + (long)m0*256;
  const unsigned short* Bb = BT + (long)n0*256;
  int g0 = t, g1 = 256 + t;
  int row0 = g0 >> 2, kq0 = g0 & 3;
  int row1 = g1 >> 2, kq1 = g1 & 3;
  f32x4 acc[4][4];
  #pragma unroll
  for (int i = 0; i < 4; i++)
    #pragma unroll
    for (int j = 0; j < 4; j++) acc[i][j] = (f32x4){0.f,0.f,0.f,0.f};

  for (int k0 = 0; k0 < 256; k0 += 32){
    gload16(Ab + (long)row0*256 + k0 + kq0*8, &As[g0*8]);
    gload16(Ab + (long)row1*256 + k0 + kq1*8, &As[g1*8]);
    gload16(Bb + (long)row0*256 + k0 + kq0*8, &Bs[g0*8]);
    gload16(Bb + (long)row1*256 + k0 + kq1*8, &Bs[g1*8]);
    __syncthreads();
    bf16x8 af[4], bfr[4];
    #pragma unroll
    for (int i = 0; i < 4; i++)
      af[i] = *(const bf16x8*)(&As[((wm*64 + i*16 + lrowi)*4 + lquad)*8]);
    #pragma unroll
    for (int j = 0; j < 4; j++)
      bfr[j] = *(const bf16x8*)(&Bs[((wn*64 + j*16 + lrowi)*4 + lquad)*8]);
    #pragma unroll
    for (int i = 0; i < 4; i++)
      #pragma unroll
      for (int j = 0; j < 4; j++)
        acc[i][j] = __builtin_amdgcn_mfma_f32_16x16x32_bf16(af[i], bfr[j], acc[i][j], 0, 0, 0);
    __syncthreads();
  }
  OT* Cb = C + (long)blockIdx.z*sCb;
  const float* Rb = RES ? (R + (long)blockIdx.z*sRb) : nullptr;
  #pragma unroll
  for (int j = 0; j < 4; j++){
    int col = n0 + wn*64 + j*16 + lrowi;
    float bv = bias[col];
    float gv = GATE ? gate[col] : 1.f;
    #pragma unroll
    for (int i = 0; i < 4; i++){
      #pragma unroll
      for (int r = 0; r < 4; r++){
        int row = m0 + wm*64 + i*16 + lquad*4 + r;
        float v = acc[i][j][r] + bv;
        if (GATE) v *= gv;
        if (RES) v += Rb[(long)row*256 + col];
        if constexpr (sizeof(OT) == 4) Cb[(long)row*ldc + col] = v;
        else                           Cb[(long)row*ldc + col] = f2bf(v);
      }
    }
  }
}

// ---------------- flash cross-attention with optional K-split ----------------
__global__ __launch_bounds__(256) void flash_kernel(
    const unsigned short* __restrict__ Q, long sQb, int ldq,
    const unsigned short* __restrict__ Kt, const unsigned short* __restrict__ Vt,
    long sKb, int ldkv,
    unsigned short* __restrict__ O, long sOb,
    float* __restrict__ Opart, float* __restrict__ Mpart, float* __restrict__ Lpart,
    int Nq, int Nk, int nsplit, float scale)
{
  __shared__ __align__(16) unsigned short Kl[32*72];
  __shared__ __align__(16) unsigned short Vl[64*40];
  __shared__ __align__(16) unsigned short Pl[4*16*40];
  int b = blockIdx.z, h = blockIdx.y;
  int nqt = Nq >> 6;
  int qtile = blockIdx.x % nqt, split = blockIdx.x / nqt;
  int kchunk = Nk / nsplit;
  int kbeg = split*kchunk, kend = kbeg + kchunk;
  int t = threadIdx.x, w = t >> 6, lane = t & 63, lrowi = lane & 15, lquad = lane >> 4;
  int q0 = qtile*64 + w*16;
  const unsigned short* Qb = Q + (long)b*sQb + h*DHH;
  const unsigned short* Kb = Kt + (long)b*sKb + h*DHH;
  const unsigned short* Vb = Vt + (long)b*sKb + h*DHH;
  bf16x8 qa[2];
  #pragma unroll
  for (int kt = 0; kt < 2; kt++)
    qa[kt] = *(const bf16x8*)(Qb + (long)(q0+lrowi)*ldq + kt*32 + lquad*8);

  f32x4 o[4];
  #pragma unroll
  for (int cj = 0; cj < 4; cj++) o[cj] = (f32x4){0.f,0.f,0.f,0.f};
  float mrow[4] = {-INFINITY,-INFINITY,-INFINITY,-INFINITY};
  float lsum[4] = {0.f,0.f,0.f,0.f};
  int skq = t >> 3;
  int sdq = (t & 7)*8;
  unsigned short* Pw = &Pl[w*16*40];

  for (int kt0 = kbeg; kt0 < kend; kt0 += 32){
    {
      uint4 kv = *(const uint4*)(Kb + (long)(kt0+skq)*ldkv + sdq);
      *(uint4*)(&Kl[skq*72 + sdq]) = kv;
      uint4 vv = *(const uint4*)(Vb + (long)(kt0+skq)*ldkv + sdq);
      const unsigned short* vp = (const unsigned short*)&vv;
      #pragma unroll
      for (int j = 0; j < 8; j++) Vl[(sdq+j)*40 + skq] = vp[j];
    }
    __syncthreads();
    f32x4 S0 = (f32x4){0.f,0.f,0.f,0.f}, S1 = (f32x4){0.f,0.f,0.f,0.f};
    {
      bf16x8 kb0 = *(const bf16x8*)(&Kl[(0*16+lrowi)*72 + lquad*8]);
      bf16x8 kb1 = *(const bf16x8*)(&Kl[(0*16+lrowi)*72 + 32 + lquad*8]);
      S0 = __builtin_amdgcn_mfma_f32_16x16x32_bf16(qa[0], kb0, S0, 0, 0, 0);
      S0 = __builtin_amdgcn_mfma_f32_16x16x32_bf16(qa[1], kb1, S0, 0, 0, 0);
      bf16x8 kb2 = *(const bf16x8*)(&Kl[(1*16+lrowi)*72 + lquad*8]);
      bf16x8 kb3 = *(const bf16x8*)(&Kl[(1*16+lrowi)*72 + 32 + lquad*8]);
      S1 = __builtin_amdgcn_mfma_f32_16x16x32_bf16(qa[0], kb2, S1, 0, 0, 0);
      S1 = __builtin_amdgcn_mfma_f32_16x16x32_bf16(qa[1], kb3, S1, 0, 0, 0);
    }
    #pragma unroll
    for (int r = 0; r < 4; r++){ S0[r] *= scale; S1[r] *= scale; }
    float al[4];
    #pragma unroll
    for (int r = 0; r < 4; r++){
      float m2 = fmaxf(S0[r], S1[r]);
      #pragma unroll
      for (int off = 1; off < 16; off <<= 1) m2 = fmaxf(m2, __shfl_xor(m2, off));
      float mn = fmaxf(mrow[r], m2);
      al[r] = __expf(mrow[r] - mn);
      mrow[r] = mn;
      float p0 = __expf(S0[r]-mn), p1 = __expf(S1[r]-mn);
      S0[r] = p0; S1[r] = p1;
      float s = p0 + p1;
      #pragma unroll
      for (int off = 1; off < 16; off <<= 1) s += __shfl_xor(s, off);
      lsum[r] = lsum[r]*al[r] + s;
    }
    #pragma unroll
    for (int cj = 0; cj < 4; cj++)
      #pragma unroll
      for (int r = 0; r < 4; r++) o[cj][r] *= al[r];
    #pragma unroll
    for (int r = 0; r < 4; r++){
      Pw[(lquad*4+r)*40 + lrowi]      = f2bf(S0[r]);
      Pw[(lquad*4+r)*40 + 16 + lrowi] = f2bf(S1[r]);
    }
    __asm__ volatile("s_waitcnt lgkmcnt(0)" ::: "memory");
    bf16x8 pa = *(const bf16x8*)(&Pw[lrowi*40 + lquad*8]);
    #pragma unroll
    for (int cj = 0; cj < 4; cj++){
      bf16x8 vb = *(const bf16x8*)(&Vl[(cj*16+lrowi)*40 + lquad*8]);
      o[cj] = __builtin_amdgcn_mfma_f32_16x16x32_bf16(pa, vb, o[cj], 0, 0, 0);
    }
    __syncthreads();
  }
  if (nsplit > 1){
    int p = (b*HH + h)*nsplit + split;
    float* Op = Opart + (long)p*Nq*DHH;
    #pragma unroll
    for (int r = 0; r < 4; r++){
      int row = q0 + lquad*4 + r;
      #pragma unroll
      for (int cj = 0; cj < 4; cj++)
        Op[(long)row*DHH + cj*16 + lrowi] = o[cj][r];
      if (lrowi == 0){
        Mpart[(long)p*Nq + row] = mrow[r];
        Lpart[(long)p*Nq + row] = lsum[r];
      }
    }
  } else {
    unsigned short* Ob = O + (long)b*sOb + h*DHH;
    #pragma unroll
    for (int r = 0; r < 4; r++){
      float rl = 1.f/lsum[r];
      int row = q0 + lquad*4 + r;
      #pragma unroll
      for (int cj = 0; cj < 4; cj++)
        Ob[(long)row*DD + cj*16 + lrowi] = f2bf(o[cj][r]*rl);
    }
  }
}

// ---------------- flash split combine ----------------
__global__ void flash_combine(const float* __restrict__ Opart, const float* __restrict__ Mpart,
                              const float* __restrict__ Lpart, unsigned short* __restrict__ O,
                              long sOb, int Nq, int nsplit){
  int gr = blockIdx.x*4 + (threadIdx.x >> 6);
  int d = threadIdx.x & 63;
  int bh = gr / Nq, row = gr % Nq;
  float M = -INFINITY;
  for (int s = 0; s < nsplit; s++)
    M = fmaxf(M, Mpart[((long)bh*nsplit + s)*Nq + row]);
  float accO = 0.f, accL = 0.f;
  for (int s = 0; s < nsplit; s++){
    long p = (long)bh*nsplit + s;
    float wv = __expf(Mpart[p*Nq + row] - M);
    accL += wv*Lpart[p*Nq + row];
    accO += wv*Opart[(p*Nq + row)*DHH + d];
  }
  int b = bh / HH, h = bh % HH;
  O[(long)b*sOb + (long)row*DD + h*DHH + d] = f2bf(accO/accL);
}

// ---------------- host ----------------
extern "C" void kernel_launch(void* const* d_in, const int* in_sizes, int n_in,
                              void* d_out, int out_size, void* d_ws, size_t ws_size,
                              hipStream_t stream) {
  (void)in_sizes; (void)n_in; (void)out_size; (void)ws_size;
  const float* x        = (const float*)d_in[0];
  const int*   mask     = (const int*)d_in[1];
  const float* pos_emb  = (const float*)d_in[2];
  const float* sim_p_w  = (const float*)d_in[3];
  const float* sim_p_b  = (const float*)d_in[4];
  const float* sim_n_w  = (const float*)d_in[5];
  const float* sim_n_b  = (const float*)d_in[6];
  const float* adj_w    = (const float*)d_in[7];
  const float* gnn_p_w1 = (const float*)d_in[8];
  const float* gnn_p_w2 = (const float*)d_in[9];
  const float* gnn_n_w1 = (const float*)d_in[10];
  const float* gnn_n_w2 = (const float*)d_in[11];
  const float* ln1_g = (const float*)d_in[12]; const float* ln1_b = (const float*)d_in[13];
  const float* ln2_g = (const float*)d_in[14]; const float* ln2_b = (const float*)d_in[15];
  const float* ln3_g = (const float*)d_in[16]; const float* ln3_b = (const float*)d_in[17];
  const float* ln4_g = (const float*)d_in[18]; const float* ln4_b = (const float*)d_in[19];
  const float* ln5_g = (const float*)d_in[20]; const float* ln5_b = (const float*)d_in[21];
  const float* i2q_wq = (const float*)d_in[22];
  const float* i2q_wk = (const float*)d_in[23];
  const float* i2q_wv = (const float*)d_in[24];
  const float* i2q_wo = (const float*)d_in[25];
  const float* q2i_wq = (const float*)d_in[26];
  const float* q2i_wk = (const float*)d_in[27];
  const float* q2i_wv = (const float*)d_in[28];
  const float* q2i_wo = (const float*)d_in[29];
  const float* i2q_bo = (const float*)d_in[30];
  const float* q2i_bo = (const float*)d_in[31];
  const float* mlp_w  = (const float*)d_in[32];
  const float* mlp_b  = (const float*)d_in[33];
  const float* g_i2t  = (const float*)d_in[34];
  const float* g_t2i  = (const float*)d_in[35];

  float* out  = (float*)d_out;
  float* simP = out + (size_t)BB*NN*DD;
  float* simN = simP + (size_t)BB*NN;

  char* w8 = (char*)d_ws;
  size_t off = 0;
  auto take = [&](size_t bytes)->void*{
    void* p = (void*)(w8 + off);
    off += (bytes + 255) & ~(size_t)255;
    return p;
  };
  float* part   = (float*)take((size_t)BB*32*2*DD*4);
  float* pcnt   = (float*)take((size_t)BB*32*2*4);
  float* posq   = (float*)take((size_t)BB*2*DD*4);
  float* vvec   = (float*)take((size_t)BB*2*DD*4);
  float* cscal  = (float*)take((size_t)BB*2*4);
  int*   idxb   = (int*)take((size_t)BB*2*256*4);
  float* wb     = (float*)take((size_t)BB*2*256*4);
  float* node   = (float*)take((size_t)BB*384*DD*4);
  float* gA     = (float*)take((size_t)BB*384*DD*4);   // also t3
  float* gadjP  = (float*)take((size_t)BB*256*256*4);
  float* gadjN  = (float*)take((size_t)BB*128*128*4);
  float* query  = (float*)take((size_t)BB*384*DD*4);   // also t1
  float* query2 = (float*)take((size_t)BB*384*DD*4);   // also t2
  unsigned short* xhatq  = (unsigned short*)take((size_t)BB*384*DD*2);
  unsigned short* qh     = (unsigned short*)take((size_t)BB*384*DD*2);
  unsigned short* attnZ  = (unsigned short*)take((size_t)BB*384*DD*2);
  unsigned short* xhatq2 = (unsigned short*)take((size_t)BB*384*DD*2);
  unsigned short* kv2    = (unsigned short*)take((size_t)BB*384*512*2);
  unsigned short* xhat   = (unsigned short*)take((size_t)BB*NN*DD*2);
  unsigned short* kvq    = (unsigned short*)take((size_t)BB*NN*768*2);
  float* featb2 = (float*)take((size_t)BB*NN*DD*4);
  float* Mpart  = (float*)take((size_t)BB*HH*8*384*4);
  float* Lpart  = (float*)take((size_t)BB*HH*8*384*4);
  unsigned short* wTq1  = (unsigned short*)take((size_t)65536*2);
  unsigned short* wTbig = (unsigned short*)take((size_t)3*65536*2);
  unsigned short* wTkv2 = (unsigned short*)take((size_t)2*65536*2);
  unsigned short* wTmlp = (unsigned short*)take((size_t)65536*2);
  unsigned short* wTo1  = (unsigned short*)take((size_t)65536*2);
  unsigned short* wTo2  = (unsigned short*)take((size_t)65536*2);
  float* biasQ1  = (float*)take(256*4);
  float* biasBig = (float*)take(768*4);
  float* biasKV2 = (float*)take(512*4);
  float* biasMlp = (float*)take(256*4);
  // overlays (disjoint lifetimes):
  float* t1 = query;
  float* t2 = query2;
  float* t3 = gA;
  unsigned short* attn2 = xhat;
  unsigned short* xhat5 = kvq;
  float* Opart = featb2;

  const long sQ  = 384L*DD;
  const long sX  = (long)NN*DD;
  const float* NF = nullptr;

  // ---- weight folds ----
  FoldArgs fa;
  fa.W[0]=i2q_wq; fa.g[0]=ln1_g; fa.BT[0]=wTq1;
  fa.W[1]=i2q_wk; fa.g[1]=ln2_g; fa.BT[1]=wTbig;
  fa.W[2]=i2q_wv; fa.g[2]=ln2_g; fa.BT[2]=wTbig + 256*256;
  fa.W[3]=q2i_wq; fa.g[3]=ln3_g; fa.BT[3]=wTbig + 512*256;
  fa.W[4]=q2i_wk; fa.g[4]=ln4_g; fa.BT[4]=wTkv2;
  fa.W[5]=q2i_wv; fa.g[5]=ln4_g; fa.BT[5]=wTkv2 + 256*256;
  fa.W[6]=mlp_w;  fa.g[6]=ln5_g; fa.BT[6]=wTmlp;
  fa.W[7]=i2q_wo; fa.g[7]=nullptr; fa.BT[7]=wTo1;
  fa.W[8]=q2i_wo; fa.g[8]=nullptr; fa.BT[8]=wTo2;
  fold_w<<<dim3(16,9), 256, 0, stream>>>(fa);
  BiasArgs ba;
  ba.W[0]=i2q_wq; ba.b[0]=ln1_b; ba.addb[0]=nullptr; ba.out[0]=biasQ1;
  ba.W[1]=i2q_wk; ba.b[1]=ln2_b; ba.addb[1]=nullptr; ba.out[1]=biasBig;
  ba.W[2]=i2q_wv; ba.b[2]=ln2_b; ba.addb[2]=nullptr; ba.out[2]=biasBig+256;
  ba.W[3]=q2i_wq; ba.b[3]=ln3_b; ba.addb[3]=nullptr; ba.out[3]=biasBig+512;
  ba.W[4]=q2i_wk; ba.b[4]=ln4_b; ba.addb[4]=nullptr; ba.out[4]=biasKV2;
  ba.W[5]=q2i_wv; ba.b[5]=ln4_b; ba.addb[5]=nullptr; ba.out[5]=biasKV2+256;
  ba.W[6]=mlp_w;  ba.b[6]=ln5_b; ba.addb[6]=mlp_b;   ba.out[6]=biasMlp;
  fold_b<<<7, 256, 0, stream>>>(ba);

  // ---- stats / sims / topk / gather ----
  stats_part<<<dim3(32, BB), 256, 0, stream>>>(x, mask, part, pcnt);
  stats_final<<<BB, 256, 0, stream>>>(part, pcnt, posq);
  sim_vec<<<BB, 256, 0, stream>>>(sim_p_w, sim_p_b, sim_n_w, sim_n_b, posq, vvec, cscal);
  sim_norm_kernel<<<dim3(NN/4, BB), 256, 0, stream>>>(x, vvec, cscal, simP, simN, xhat);
  topk_radix<<<2*BB, 256, 0, stream>>>(simP, simN, idxb, wb);
  gather_nodes<<<dim3(KPP+KNN, BB), 256, 0, stream>>>(x, idxb, wb, node);

  // ---- GCN (pos/neg paired) ----
  GP z = {};
  // [g1 | t1pos | t1neg] in one launch
  {
    GP4 g;
    g.p[0] = { node, 384L*DD, 256, adj_w, 0, 256, gA, 384L*DD, 256, nullptr, nullptr, 384, 256, 256, 1.f, 0 };
    g.p[1] = { node, 384L*DD, 256, gnn_p_w1, 0, 256, t1, 384L*DD, 256, nullptr, nullptr, 256, 256, 256, 1.f, 0 };
    g.p[2] = { node + 256L*DD, 384L*DD, 256, gnn_n_w1, 0, 256, t1 + 256L*DD, 384L*DD, 256, nullptr, nullptr, 128, 256, 256, 1.f, 0 };
    g.p[3] = z;
    gemm_multi<<<dim3(4,6,3*BB), 256, 0, stream>>>(g);
  }
  // gadj = softmax( gA @ node^T * scale )
  {
    GP4 g;
    g.p[0] = { gA, 384L*DD, 256, node, 384L*DD, 256, gadjP, 65536L, 256, nullptr, nullptr, 256, 256, 256, 0.0625f, FLAG_TRANSB };
    g.p[1] = { gA + 256L*DD, 384L*DD, 256, node + 256L*DD, 384L*DD, 256, gadjN, 16384L, 128, nullptr, nullptr, 128, 128, 256, 0.0625f, FLAG_TRANSB };
    g.p[2] = z; g.p[3] = z;
    gemm_multi<<<dim3(4,4,2*BB), 256, 0, stream>>>(g);
  }
  softmax_dual<<<768, 256, 0, stream>>>(gadjP, 256, 256, 65536L, BB*256,
                                        gadjN, 128, 128, 16384L, BB*128);
  // t2 = relu(adj @ t1)
  {
    GP4 g;
    g.p[0] = { gadjP, 65536L, 256, t1, 384L*DD, 256, t2, 384L*DD, 256, nullptr, nullptr, 256, 256, 256, 1.f, FLAG_RELU };
    g.p[1] = { gadjN, 16384L, 128, t1 + 256L*DD, 384L*DD, 256, t2 + 256L*DD, 384L*DD, 256, nullptr, nullptr, 128, 256, 128, 1.f, FLAG_RELU };
    g.p[2] = z; g.p[3] = z;
    gemm_multi<<<dim3(4,4,2*BB), 256, 0, stream>>>(g);
  }
  // t3 = t2 @ w2
  {
    GP4 g;
    g.p[0] = { t2, 384L*DD, 256, gnn_p_w2, 0, 256, t3, 384L*DD, 256, nullptr, nullptr, 256, 256, 256, 1.f, 0 };
    g.p[1] = { t2 + 256L*DD, 384L*DD, 256, gnn_n_w2, 0, 256, t3 + 256L*DD, 384L*DD, 256, nullptr, nullptr, 128, 256, 256, 1.f, 0 };
    g.p[2] = z; g.p[3] = z;
    gemm_multi<<<dim3(4,4,2*BB), 256, 0, stream>>>(g);
  }
  // query = adj @ t3 + pos_emb[idx]  (gather fused in epilogue)
  {
    GP4 g;
    g.p[0] = { gadjP, 65536L, 256, t3, 384L*DD, 256, query, 384L*DD, 256, idxb, pos_emb, 256, 256, 256, 1.f, 0 };
    g.p[1] = { gadjN, 16384L, 128, t3 + 256L*DD, 384L*DD, 256, query + 256L*DD, 384L*DD, 256, idxb + 256, pos_emb, 128, 256, 128, 1.f, 0 };
    g.p[2] = z; g.p[3] = z;
    gemm_multi<<<dim3(4,4,2*BB), 256, 0, stream>>>(g);
  }

  // ---- LN core of query ----
  rownorm_kernel<<<BB*384/4, 256, 0, stream>>>(query, xhatq, BB*384);

  // (a) qh = xhatq @ wq' + b'
  gemm128<unsigned short,false,false><<<dim3(2,3,BB),256,0,stream>>>(
      xhatq, sQ, wTq1, qh, sQ, 256, NF, 0, biasQ1, NF);
  // (b) [kh|vh|qh2] = xhat @ [wk'|wv'|wq2'] + b'
  gemm128<unsigned short,false,false><<<dim3(6,32,BB),256,0,stream>>>(
      xhat, sX, wTbig, kvq, (long)NN*768, 768, NF, 0, biasBig, NF);
  // i2q flash (K-split 8) + combine
  flash_kernel<<<dim3(6*8, HH, BB), 256, 0, stream>>>(
      qh, sQ, 256, kvq, kvq + 256, (long)NN*768, 768,
      attnZ, sQ, Opart, Mpart, Lpart, 384, NN, 8, 0.125f);
  flash_combine<<<BB*HH*384/4, 256, 0, stream>>>(Opart, Mpart, Lpart, attnZ, sQ, 384, 8);
  // (c) query2 = query + g_i2t .* (attnZ @ wo + bo)
  gemm128<float,true,true><<<dim3(2,3,BB),256,0,stream>>>(
      attnZ, sQ, wTo1, query2, sQ, 256, query, sQ, i2q_bo, g_i2t);

  // ---- q2i ----
  rownorm_kernel<<<BB*384/4, 256, 0, stream>>>(query2, xhatq2, BB*384);
  // (d) [k2|v2] = xhatq2 @ [wk2'|wv2'] + b'
  gemm128<unsigned short,false,false><<<dim3(4,3,BB),256,0,stream>>>(
      xhatq2, sQ, wTkv2, kv2, 384L*512, 512, NF, 0, biasKV2, NF);
  flash_kernel<<<dim3(NN/64, HH, BB), 256, 0, stream>>>(
      kvq + 512, (long)NN*768, 768, kv2, kv2 + 256, 384L*512, 512,
      attn2, sX, nullptr, nullptr, nullptr, NN, 384, 1, 0.125f);
  // (e) featb2 = x + g_t2i .* (attn2 @ wo + bo)
  gemm128<float,true,true><<<dim3(2,32,BB),256,0,stream>>>(
      attn2, sX, wTo2, featb2, sX, 256, x, sX, q2i_bo, g_t2i);

  // ---- final MLP ----
  rownorm_kernel<<<BB*NN/4, 256, 0, stream>>>(featb2, xhat5, BB*NN);
  // (f) out = featb2 + xhat5 @ mlp' + b'
  gemm128<float,true,false><<<dim3(2,32,BB),256,0,stream>>>(
      xhat5, sX, wTmlp, out, sX, 256, featb2, sX, biasMlp, NF);
}

// Round 4
// 605.487 us; speedup vs baseline: 1.5532x; 1.5532x over previous
//
#include <hip/hip_runtime.h>

#define BB 8
#define NN 4096
#define DD 256
#define HH 4
#define DHH 64
#define KPP 256
#define KNN 128

typedef float f32x4 __attribute__((ext_vector_type(4)));
typedef short bf16x8 __attribute__((ext_vector_type(8)));

#define FLAG_TRANSB 1
#define FLAG_RELU   2

__device__ __forceinline__ float bf2f(unsigned short u){
  union { unsigned int i; float f; } v; v.i = ((unsigned int)u) << 16; return v.f;
}
__device__ __forceinline__ unsigned short f2bf(float f){
  union { float f; unsigned int i; } v; v.f = f;
  return (unsigned short)((v.i + 0x7FFFu + ((v.i >> 16) & 1u)) >> 16);
}
__device__ __forceinline__ void gload16(const void* g, void* l){
  __builtin_amdgcn_global_load_lds((const __attribute__((address_space(1))) void*)g,
                                   (__attribute__((address_space(3))) void*)l, 16, 0, 0);
}

// ---------------- masked-mean stats (2-stage) ----------------
__global__ void stats_part(const float* __restrict__ x, const int* __restrict__ mask,
                           float* __restrict__ part, float* __restrict__ pcnt){
  int b = blockIdx.y, c = blockIdx.x, d = threadIdx.x;
  int n0 = c * 128;
  float sp = 0.f, sn = 0.f; int cp = 0, cn = 0;
  const float* xb = x + ((long)b*NN + n0)*DD + d;
  const int* mb = mask + (long)b*NN + n0;
  for (int r = 0; r < 128; r++){
    int mv = mb[r];
    float v = xb[(long)r*DD];
    if (mv == 1){ sp += v; cp++; }
    else if (mv == -1){ sn += v; cn++; }
  }
  part[(((long)(b*32+c)*2+0)*DD)+d] = sp;
  part[(((long)(b*32+c)*2+1)*DD)+d] = sn;
  if (d == 0){ pcnt[(b*32+c)*2+0] = (float)cp; pcnt[(b*32+c)*2+1] = (float)cn; }
}

__global__ void stats_final(const float* __restrict__ part, const float* __restrict__ pcnt,
                            float* __restrict__ posq){
  int b = blockIdx.x, d = threadIdx.x;
  float sp=0.f, sn=0.f, cp=0.f, cn=0.f;
  for (int c = 0; c < 32; c++){
    sp += part[(((long)(b*32+c)*2+0)*DD)+d];
    sn += part[(((long)(b*32+c)*2+1)*DD)+d];
    cp += pcnt[(b*32+c)*2+0];
    cn += pcnt[(b*32+c)*2+1];
  }
  posq[(long)(b*2+0)*DD + d] = sp / (cp + 1e-6f);
  posq[(long)(b*2+1)*DD + d] = sn / (cn + 1e-6f);
}

// ---------------- sim vectors: v = W @ q, c = b . q ----------------
__global__ void sim_vec(const float* __restrict__ Wp, const float* __restrict__ bp,
                        const float* __restrict__ Wn, const float* __restrict__ bn,
                        const float* __restrict__ posq, float* __restrict__ vvec,
                        float* __restrict__ cscal){
  int b = blockIdx.x, k = threadIdx.x;
  const float* qp = posq + (long)(b*2+0)*DD;
  const float* qn = posq + (long)(b*2+1)*DD;
  float vp = 0.f, vn = 0.f;
  for (int j = 0; j < DD; j++){ vp += Wp[(long)k*DD+j]*qp[j]; vn += Wn[(long)k*DD+j]*qn[j]; }
  vvec[(long)(b*2+0)*DD+k] = vp; vvec[(long)(b*2+1)*DD+k] = vn;
  __shared__ float red[256];
  red[k] = bp[k]*qp[k];
  __syncthreads();
  for (int s = 128; s > 0; s >>= 1){ if (k < s) red[k] += red[k+s]; __syncthreads(); }
  if (k == 0) cscal[b*2+0] = red[0];
  __syncthreads();
  red[k] = bn[k]*qn[k];
  __syncthreads();
  for (int s = 128; s > 0; s >>= 1){ if (k < s) red[k] += red[k+s]; __syncthreads(); }
  if (k == 0) cscal[b*2+1] = red[0];
}

// ---------------- fused sims + LN-core of x ----------------
__global__ void sim_norm_kernel(const float* __restrict__ x, const float* __restrict__ vvec,
                                const float* __restrict__ cscal,
                                float* __restrict__ simP, float* __restrict__ simN,
                                unsigned short* __restrict__ xhat){
  int b = blockIdx.y;
  int w = threadIdx.x >> 6, lane = threadIdx.x & 63;
  int n = blockIdx.x*4 + w;
  long row = (long)b*NN + n;
  const float4* xr = (const float4*)(x + row*DD);
  float4 xv = xr[lane];
  float4 a = ((const float4*)(vvec + (long)(b*2+0)*DD))[lane];
  float4 c = ((const float4*)(vvec + (long)(b*2+1)*DD))[lane];
  float sp = xv.x*a.x + xv.y*a.y + xv.z*a.z + xv.w*a.w;
  float sn = xv.x*c.x + xv.y*c.y + xv.z*c.z + xv.w*c.w;
  float s  = xv.x+xv.y+xv.z+xv.w;
  float q  = xv.x*xv.x+xv.y*xv.y+xv.z*xv.z+xv.w*xv.w;
  for (int off = 32; off; off >>= 1){
    sp += __shfl_xor(sp, off); sn += __shfl_xor(sn, off);
    s  += __shfl_xor(s, off);  q  += __shfl_xor(q, off);
  }
  float m = s*(1.f/256.f);
  float var = q*(1.f/256.f) - m*m;
  float rinv = rsqrtf(var + 1e-5f);
  ushort4 o;
  o.x = f2bf((xv.x-m)*rinv); o.y = f2bf((xv.y-m)*rinv);
  o.z = f2bf((xv.z-m)*rinv); o.w = f2bf((xv.w-m)*rinv);
  ((ushort4*)(xhat + row*DD))[lane] = o;
  if (lane == 0){
    float zp = sp + cscal[b*2+0], zn = sn + cscal[b*2+1];
    simP[row] = 1.f/(1.f+expf(-zp));
    simN[row] = 1.f/(1.f+expf(-zn));
  }
}

// ---------------- exact top-k via 3-pass radix select (parallel scans) ----------------
__global__ __launch_bounds__(256) void topk_radix(const float* __restrict__ simP,
                                                  const float* __restrict__ simN,
                                                  int* __restrict__ idxb, float* __restrict__ wb){
  __shared__ unsigned int vals[4096];
  __shared__ unsigned int hist[4096];
  __shared__ unsigned short eql[4096];
  __shared__ unsigned int tsum[256];
  __shared__ unsigned int sB, sRem, sCG, sCnt, sEq;
  int id = blockIdx.x; int sgn = id & 1, b = id >> 1;
  int K = (sgn == 0) ? KPP : KNN;
  const float* s = (sgn == 0 ? simP : simN) + (long)b*NN;
  int t = threadIdx.x;
  if (t == 0){ sCG = 0; sCnt = 0; sEq = 0; }
  for (int i = t; i < 4096; i += 256){ vals[i] = __float_as_uint(s[i]); hist[i] = 0; }
  __syncthreads();

  // parallel threshold search over NB bins: find largest B with suffix_count(B) >= need.
  // writes sB, sRem; adds count(>threshold-bucket) into sCG.
  auto find_thresh = [&](int NB, unsigned need){
    int per = NB >> 8;
    int base = t*per;
    unsigned local = 0;
    for (int j = 0; j < per; j++) local += hist[base+j];
    tsum[t] = local;
    __syncthreads();
    #pragma unroll
    for (int st = 1; st < 256; st <<= 1){
      unsigned v = (t + st < 256) ? tsum[t+st] : 0u;
      __syncthreads();
      tsum[t] += v;
      __syncthreads();
    }
    unsigned after = (t < 255) ? tsum[t+1] : 0u;
    if (after < need && after + local >= need){
      unsigned c = after;
      for (int j = per-1; j >= 0; j--){
        unsigned h = hist[base+j];
        c += h;
        if (c >= need){
          sB = (unsigned)(base+j);
          sRem = need - (c - h);
          atomicAdd(&sCG, c - h);
          break;
        }
      }
    }
    __syncthreads();
  };

  // pass 1: bits [31:20]
  for (int i = t; i < 4096; i += 256) atomicAdd(&hist[vals[i] >> 20], 1u);
  __syncthreads();
  find_thresh(4096, (unsigned)K);
  unsigned B1 = sB, rem1 = sRem;
  __syncthreads();
  for (int i = t; i < 4096; i += 256) hist[i] = 0;
  __syncthreads();
  // pass 2: bits [19:8] among top12==B1
  for (int i = t; i < 4096; i += 256){
    unsigned v = vals[i];
    if ((v >> 20) == B1) atomicAdd(&hist[(v >> 8) & 0xFFFu], 1u);
  }
  __syncthreads();
  find_thresh(4096, rem1);
  unsigned B2 = sB, rem2 = sRem;
  unsigned pre = (B1 << 12) | B2;   // bits [31:8]
  __syncthreads();
  hist[t] = 0;
  __syncthreads();
  // pass 3: bits [7:0] among prefix==pre
  for (int i = t; i < 4096; i += 256){
    unsigned v = vals[i];
    if ((v >> 8) == pre) atomicAdd(&hist[v & 0xFFu], 1u);
  }
  __syncthreads();
  find_thresh(256, rem2);
  unsigned T = (pre << 8) | sB;
  unsigned cg = sCG;
  __syncthreads();

  int* oi = idxb + (long)id*256;
  float* ow = wb + (long)id*256;
  for (int i = t; i < 4096; i += 256){
    unsigned v = vals[i];
    if (v > T){ unsigned p = atomicAdd(&sCnt, 1u); oi[p] = i; ow[p] = __uint_as_float(v); }
    else if (v == T){ unsigned e = atomicAdd(&sEq, 1u); eql[e] = (unsigned short)i; }
  }
  __syncthreads();
  int ne = K - (int)cg;          // take ne equals, lowest indices (jax tie-break)
  int eqn = (int)sEq;
  for (int e = t; e < eqn; e += 256){
    int myi = eql[e]; int r = 0;
    for (int e2 = 0; e2 < eqn; e2++) r += (eql[e2] < myi);
    if (r < ne){ oi[cg + r] = myi; ow[cg + r] = __uint_as_float(T); }
  }
}

// ---------------- gather masked nodes (stacked pos 0-255, neg 256-383) ----------------
__global__ void gather_nodes(const float* __restrict__ x, const int* __restrict__ idxb,
                             const float* __restrict__ wb, float* __restrict__ node){
  int b = blockIdx.y, i = blockIdx.x, d = threadIdx.x;
  int sgn = (i < KPP) ? 0 : 1;
  int ii = (sgn == 0) ? i : i - KPP;
  int idx = idxb[(long)(b*2+sgn)*256+ii];
  float w = wb[(long)(b*2+sgn)*256+ii];
  float val = (w > 0.6f) ? x[((long)b*NN + idx)*DD + d] : 0.f;
  node[((long)b*384 + i)*DD + d] = val;
}

// ---------------- dual row softmax ----------------
__global__ void softmax_dual(float* __restrict__ A0, int L0, int rpb0, long bs0, int rows0,
                             float* __restrict__ A1, int L1, int rpb1, long bs1, int rows1){
  int w = threadIdx.x >> 6, lane = threadIdx.x & 63;
  long row = (long)blockIdx.x*4 + w;
  float* A; int L, rpb; long bs;
  if (row < rows0){ A = A0; L = L0; rpb = rpb0; bs = bs0; }
  else { row -= rows0; if (row >= rows1) return; A = A1; L = L1; rpb = rpb1; bs = bs1; }
  int b = (int)(row / rpb), r = (int)(row % rpb);
  float* a = A + (long)b*bs + (long)r*L;
  int e = L >> 6;
  float vals[4]; float mx = -1e30f;
  for (int j = 0; j < e; j++){ vals[j] = a[lane*e+j]; mx = fmaxf(mx, vals[j]); }
  for (int off = 32; off; off >>= 1) mx = fmaxf(mx, __shfl_xor(mx, off));
  float sum = 0.f;
  for (int j = 0; j < e; j++){ vals[j] = expf(vals[j]-mx); sum += vals[j]; }
  for (int off = 32; off; off >>= 1) sum += __shfl_xor(sum, off);
  float rinv = 1.f/sum;
  for (int j = 0; j < e; j++) a[lane*e+j] = vals[j]*rinv;
}

// ---------------- row LayerNorm core (no affine) f32 -> bf16 ----------------
__global__ void rownorm_kernel(const float* __restrict__ X, unsigned short* __restrict__ Y, int rows){
  int w = threadIdx.x >> 6, lane = threadIdx.x & 63;
  long row = (long)blockIdx.x*4 + w;
  if (row >= rows) return;
  const float4* xr = (const float4*)(X + row*DD);
  float4 xv = xr[lane];
  float s = xv.x+xv.y+xv.z+xv.w;
  float q = xv.x*xv.x+xv.y*xv.y+xv.z*xv.z+xv.w*xv.w;
  for (int off = 32; off; off >>= 1){ s += __shfl_xor(s, off); q += __shfl_xor(q, off); }
  float m = s*(1.f/256.f);
  float var = q*(1.f/256.f) - m*m;
  float rinv = rsqrtf(var + 1e-5f);
  ushort4 o;
  o.x = f2bf((xv.x-m)*rinv); o.y = f2bf((xv.y-m)*rinv);
  o.z = f2bf((xv.z-m)*rinv); o.w = f2bf((xv.w-m)*rinv);
  ((ushort4*)(Y + row*DD))[lane] = o;
}

// ---------------- weight fold: BT[n][k] = g[k]*W[k][n] (bf16) ----------------
struct FoldArgs { const float* W[9]; const float* g[9]; unsigned short* BT[9]; };
struct BiasArgs { const float* W[7]; const float* b[7]; const float* addb[7]; float* out[7]; };

__global__ void fold_w(FoldArgs fa){
  int m = blockIdx.y, tile = blockIdx.x, t = threadIdx.x;
  const float* W = fa.W[m]; const float* g = fa.g[m]; unsigned short* BT = fa.BT[m];
  __shared__ float T[64][65];
  int tn = (tile & 3)*64, tk = (tile >> 2)*64;
  #pragma unroll 4
  for (int p = 0; p < 16; p++){
    int kl = p*4 + (t >> 6), nl = t & 63;
    float v = W[(long)(tk+kl)*256 + tn + nl];
    if (g) v *= g[tk+kl];
    T[kl][nl] = v;
  }
  __syncthreads();
  #pragma unroll 4
  for (int p = 0; p < 16; p++){
    int nl = p*4 + (t >> 6), kl = t & 63;
    BT[(long)(tn+nl)*256 + tk + kl] = f2bf(T[kl][nl]);
  }
}

__global__ void fold_b(BiasArgs ba){
  int m = blockIdx.x, n = threadIdx.x;
  const float* W = ba.W[m]; const float* b = ba.b[m];
  float s = (ba.addb[m] != nullptr) ? ba.addb[m][n] : 0.f;
  for (int k = 0; k < 256; k++) s += b[k]*W[(long)k*256+n];
  ba.out[m][n] = s;
}

// ---------------- multi-parameter f32 GEMM 64x64 (GCN path) ----------------
struct GP {
  const float* A; long sAb; int lda;
  const float* B; long sBb; int ldb;
  float* C; long sCb; int ldc;
  const int* pidx; const float* pe;   // optional epilogue: C += pe[pidx[b*512+row]*256 + col]
  int M, N, K; float alpha; int flags;
};
struct GP4 { GP p[4]; };

__global__ __launch_bounds__(256) void gemm_multi(GP4 g4){
  GP p = g4.p[blockIdx.z >> 3];
  int b = blockIdx.z & 7;
  int m0 = blockIdx.y*64, n0 = blockIdx.x*64;
  if (m0 >= p.M || n0 >= p.N) return;
  __shared__ __align__(16) unsigned short As[64*40];
  __shared__ __align__(16) unsigned short Bs[64*40];
  const float* Ab = p.A + (long)b*p.sAb;
  const float* Bb = p.B + (long)b*p.sBb;
  int t = threadIdx.x;
  int w = t >> 6, lane = t & 63, lrowi = lane & 15, lquad = lane >> 4;
  int wm = w >> 1, wn = w & 1;
  f32x4 acc[2][2];
  #pragma unroll
  for (int i = 0; i < 2; i++)
    #pragma unroll
    for (int j = 0; j < 2; j++) acc[i][j] = (f32x4){0.f,0.f,0.f,0.f};
  int am = t >> 2, akq = t & 3;
  for (int k0 = 0; k0 < p.K; k0 += 32){
    {
      const float4* s4 = (const float4*)(Ab + (long)(m0+am)*p.lda + k0 + akq*8);
      float4 u = s4[0], vv = s4[1];
      unsigned short tmp[8];
      tmp[0]=f2bf(u.x); tmp[1]=f2bf(u.y); tmp[2]=f2bf(u.z); tmp[3]=f2bf(u.w);
      tmp[4]=f2bf(vv.x); tmp[5]=f2bf(vv.y); tmp[6]=f2bf(vv.z); tmp[7]=f2bf(vv.w);
      *(uint4*)(&As[am*40 + akq*8]) = *(uint4*)tmp;
    }
    if (p.flags & FLAG_TRANSB){
      const float4* s4 = (const float4*)(Bb + (long)(n0+am)*p.ldb + k0 + akq*8);
      float4 u = s4[0], vv = s4[1];
      unsigned short tmp[8];
      tmp[0]=f2bf(u.x); tmp[1]=f2bf(u.y); tmp[2]=f2bf(u.z); tmp[3]=f2bf(u.w);
      tmp[4]=f2bf(vv.x); tmp[5]=f2bf(vv.y); tmp[6]=f2bf(vv.z); tmp[7]=f2bf(vv.w);
      *(uint4*)(&Bs[am*40 + akq*8]) = *(uint4*)tmp;
    } else {
      int bn = t & 63, bkb = (t >> 6)*8;
      #pragma unroll
      for (int j = 0; j < 8; j++)
        Bs[bn*40 + bkb + j] = f2bf(Bb[(long)(k0+bkb+j)*p.ldb + n0 + bn]);
    }
    __syncthreads();
    bf16x8 af[2], bfr[2];
    #pragma unroll
    for (int i = 0; i < 2; i++)
      af[i] = *(const bf16x8*)(&As[(wm*32 + i*16 + lrowi)*40 + lquad*8]);
    #pragma unroll
    for (int j = 0; j < 2; j++)
      bfr[j] = *(const bf16x8*)(&Bs[(wn*32 + j*16 + lrowi)*40 + lquad*8]);
    #pragma unroll
    for (int i = 0; i < 2; i++)
      #pragma unroll
      for (int j = 0; j < 2; j++)
        acc[i][j] = __builtin_amdgcn_mfma_f32_16x16x32_bf16(af[i], bfr[j], acc[i][j], 0, 0, 0);
    __syncthreads();
  }
  float* Cb = p.C + (long)b*p.sCb;
  #pragma unroll
  for (int i = 0; i < 2; i++)
    #pragma unroll
    for (int j = 0; j < 2; j++){
      int col = n0 + wn*32 + j*16 + lrowi;
      #pragma unroll
      for (int r = 0; r < 4; r++){
        int row = m0 + wm*32 + i*16 + lquad*4 + r;
        float v = p.alpha*acc[i][j][r];
        if (p.flags & FLAG_RELU) v = fmaxf(v, 0.f);
        if (p.pidx != nullptr){
          int idx = p.pidx[b*512 + row];
          v += p.pe[(long)idx*256 + col];
        }
        Cb[(long)row*p.ldc + col] = v;
      }
    }
}

// ---------------- fast 128x128 bf16 GEMM (K=256), global_load_lds staging ----------------
// C = R + gate .* (A @ BT^T + bias)
template<typename OT, bool RES, bool GATE>
__global__ __launch_bounds__(256) void gemm128(
    const unsigned short* __restrict__ A, long sAb,
    const unsigned short* __restrict__ BT,
    OT* __restrict__ C, long sCb, int ldc,
    const float* __restrict__ R, long sRb,
    const float* __restrict__ bias, const float* __restrict__ gate)
{
  __shared__ __align__(16) unsigned short As[4096];
  __shared__ __align__(16) unsigned short Bs[4096];
  int t = threadIdx.x;
  int w = t >> 6, lane = t & 63, lrowi = lane & 15, lquad = lane >> 4;
  int wm = w >> 1, wn = w & 1;
  int m0 = blockIdx.y*128, n0 = blockIdx.x*128;
  const unsigned short* Ab = A + (long)blockIdx.z*sAb + (long)m0*256;
  const unsigned short* Bb = BT + (long)n0*256;
  int g0 = t, g1 = 256 + t;
  int row0 = g0 >> 2, kq0 = g0 & 3;
  int row1 = g1 >> 2, kq1 = g1 & 3;
  f32x4 acc[4][4];
  #pragma unroll
  for (int i = 0; i < 4; i++)
    #pragma unroll
    for (int j = 0; j < 4; j++) acc[i][j] = (f32x4){0.f,0.f,0.f,0.f};

  for (int k0 = 0; k0 < 256; k0 += 32){
    gload16(Ab + (long)row0*256 + k0 + kq0*8, &As[g0*8]);
    gload16(Ab + (long)row1*256 + k0 + kq1*8, &As[g1*8]);
    gload16(Bb + (long)row0*256 + k0 + kq0*8, &Bs[g0*8]);
    gload16(Bb + (long)row1*256 + k0 + kq1*8, &Bs[g1*8]);
    __syncthreads();
    bf16x8 af[4], bfr[4];
    #pragma unroll
    for (int i = 0; i < 4; i++)
      af[i] = *(const bf16x8*)(&As[((wm*64 + i*16 + lrowi)*4 + lquad)*8]);
    #pragma unroll
    for (int j = 0; j < 4; j++)
      bfr[j] = *(const bf16x8*)(&Bs[((wn*64 + j*16 + lrowi)*4 + lquad)*8]);
    #pragma unroll
    for (int i = 0; i < 4; i++)
      #pragma unroll
      for (int j = 0; j < 4; j++)
        acc[i][j] = __builtin_amdgcn_mfma_f32_16x16x32_bf16(af[i], bfr[j], acc[i][j], 0, 0, 0);
    __syncthreads();
  }
  OT* Cb = C + (long)blockIdx.z*sCb;
  const float* Rb = RES ? (R + (long)blockIdx.z*sRb) : nullptr;
  #pragma unroll
  for (int j = 0; j < 4; j++){
    int col = n0 + wn*64 + j*16 + lrowi;
    float bv = bias[col];
    float gv = GATE ? gate[col] : 1.f;
    #pragma unroll
    for (int i = 0; i < 4; i++){
      #pragma unroll
      for (int r = 0; r < 4; r++){
        int row = m0 + wm*64 + i*16 + lquad*4 + r;
        float v = acc[i][j][r] + bv;
        if (GATE) v *= gv;
        if (RES) v += Rb[(long)row*256 + col];
        if constexpr (sizeof(OT) == 4) Cb[(long)row*ldc + col] = v;
        else                           Cb[(long)row*ldc + col] = f2bf(v);
      }
    }
  }
}

// ---------------- flash cross-attention with optional K-split ----------------
__global__ __launch_bounds__(256) void flash_kernel(
    const unsigned short* __restrict__ Q, long sQb, int ldq,
    const unsigned short* __restrict__ Kt, const unsigned short* __restrict__ Vt,
    long sKb, int ldkv,
    unsigned short* __restrict__ O, long sOb,
    float* __restrict__ Opart, float* __restrict__ Mpart, float* __restrict__ Lpart,
    int Nq, int Nk, int nsplit, float scale)
{
  __shared__ __align__(16) unsigned short Kl[32*72];
  __shared__ __align__(16) unsigned short Vl[64*40];
  __shared__ __align__(16) unsigned short Pl[4*16*40];
  int b = blockIdx.z, h = blockIdx.y;
  int nqt = Nq >> 6;
  int qtile = blockIdx.x % nqt, split = blockIdx.x / nqt;
  int kchunk = Nk / nsplit;
  int kbeg = split*kchunk, kend = kbeg + kchunk;
  int t = threadIdx.x, w = t >> 6, lane = t & 63, lrowi = lane & 15, lquad = lane >> 4;
  int q0 = qtile*64 + w*16;
  const unsigned short* Qb = Q + (long)b*sQb + h*DHH;
  const unsigned short* Kb = Kt + (long)b*sKb + h*DHH;
  const unsigned short* Vb = Vt + (long)b*sKb + h*DHH;
  bf16x8 qa[2];
  #pragma unroll
  for (int kt = 0; kt < 2; kt++)
    qa[kt] = *(const bf16x8*)(Qb + (long)(q0+lrowi)*ldq + kt*32 + lquad*8);

  f32x4 o[4];
  #pragma unroll
  for (int cj = 0; cj < 4; cj++) o[cj] = (f32x4){0.f,0.f,0.f,0.f};
  float mrow[4] = {-INFINITY,-INFINITY,-INFINITY,-INFINITY};
  float lsum[4] = {0.f,0.f,0.f,0.f};
  int skq = t >> 3;
  int sdq = (t & 7)*8;
  unsigned short* Pw = &Pl[w*16*40];

  for (int kt0 = kbeg; kt0 < kend; kt0 += 32){
    {
      uint4 kv = *(const uint4*)(Kb + (long)(kt0+skq)*ldkv + sdq);
      *(uint4*)(&Kl[skq*72 + sdq]) = kv;
      uint4 vv = *(const uint4*)(Vb + (long)(kt0+skq)*ldkv + sdq);
      const unsigned short* vp = (const unsigned short*)&vv;
      #pragma unroll
      for (int j = 0; j < 8; j++) Vl[(sdq+j)*40 + skq] = vp[j];
    }
    __syncthreads();
    f32x4 S0 = (f32x4){0.f,0.f,0.f,0.f}, S1 = (f32x4){0.f,0.f,0.f,0.f};
    {
      bf16x8 kb0 = *(const bf16x8*)(&Kl[(0*16+lrowi)*72 + lquad*8]);
      bf16x8 kb1 = *(const bf16x8*)(&Kl[(0*16+lrowi)*72 + 32 + lquad*8]);
      S0 = __builtin_amdgcn_mfma_f32_16x16x32_bf16(qa[0], kb0, S0, 0, 0, 0);
      S0 = __builtin_amdgcn_mfma_f32_16x16x32_bf16(qa[1], kb1, S0, 0, 0, 0);
      bf16x8 kb2 = *(const bf16x8*)(&Kl[(1*16+lrowi)*72 + lquad*8]);
      bf16x8 kb3 = *(const bf16x8*)(&Kl[(1*16+lrowi)*72 + 32 + lquad*8]);
      S1 = __builtin_amdgcn_mfma_f32_16x16x32_bf16(qa[0], kb2, S1, 0, 0, 0);
      S1 = __builtin_amdgcn_mfma_f32_16x16x32_bf16(qa[1], kb3, S1, 0, 0, 0);
    }
    #pragma unroll
    for (int r = 0; r < 4; r++){ S0[r] *= scale; S1[r] *= scale; }
    float al[4];
    #pragma unroll
    for (int r = 0; r < 4; r++){
      float m2 = fmaxf(S0[r], S1[r]);
      #pragma unroll
      for (int off = 1; off < 16; off <<= 1) m2 = fmaxf(m2, __shfl_xor(m2, off));
      float mn = fmaxf(mrow[r], m2);
      al[r] = __expf(mrow[r] - mn);
      mrow[r] = mn;
      float p0 = __expf(S0[r]-mn), p1 = __expf(S1[r]-mn);
      S0[r] = p0; S1[r] = p1;
      float s = p0 + p1;
      #pragma unroll
      for (int off = 1; off < 16; off <<= 1) s += __shfl_xor(s, off);
      lsum[r] = lsum[r]*al[r] + s;
    }
    #pragma unroll
    for (int cj = 0; cj < 4; cj++)
      #pragma unroll
      for (int r = 0; r < 4; r++) o[cj][r] *= al[r];
    #pragma unroll
    for (int r = 0; r < 4; r++){
      Pw[(lquad*4+r)*40 + lrowi]      = f2bf(S0[r]);
      Pw[(lquad*4+r)*40 + 16 + lrowi] = f2bf(S1[r]);
    }
    __asm__ volatile("s_waitcnt lgkmcnt(0)" ::: "memory");
    bf16x8 pa = *(const bf16x8*)(&Pw[lrowi*40 + lquad*8]);
    #pragma unroll
    for (int cj = 0; cj < 4; cj++){
      bf16x8 vb = *(const bf16x8*)(&Vl[(cj*16+lrowi)*40 + lquad*8]);
      o[cj] = __builtin_amdgcn_mfma_f32_16x16x32_bf16(pa, vb, o[cj], 0, 0, 0);
    }
    __syncthreads();
  }
  if (nsplit > 1){
    int p = (b*HH + h)*nsplit + split;
    float* Op = Opart + (long)p*Nq*DHH;
    #pragma unroll
    for (int r = 0; r < 4; r++){
      int row = q0 + lquad*4 + r;
      #pragma unroll
      for (int cj = 0; cj < 4; cj++)
        Op[(long)row*DHH + cj*16 + lrowi] = o[cj][r];
      if (lrowi == 0){
        Mpart[(long)p*Nq + row] = mrow[r];
        Lpart[(long)p*Nq + row] = lsum[r];
      }
    }
  } else {
    unsigned short* Ob = O + (long)b*sOb + h*DHH;
    #pragma unroll
    for (int r = 0; r < 4; r++){
      float rl = 1.f/lsum[r];
      int row = q0 + lquad*4 + r;
      #pragma unroll
      for (int cj = 0; cj < 4; cj++)
        Ob[(long)row*DD + cj*16 + lrowi] = f2bf(o[cj][r]*rl);
    }
  }
}

// ---------------- flash split combine ----------------
__global__ void flash_combine(const float* __restrict__ Opart, const float* __restrict__ Mpart,
                              const float* __restrict__ Lpart, unsigned short* __restrict__ O,
                              long sOb, int Nq, int nsplit){
  int gr = blockIdx.x*4 + (threadIdx.x >> 6);
  int d = threadIdx.x & 63;
  int bh = gr / Nq, row = gr % Nq;
  float M = -INFINITY;
  for (int s = 0; s < nsplit; s++)
    M = fmaxf(M, Mpart[((long)bh*nsplit + s)*Nq + row]);
  float accO = 0.f, accL = 0.f;
  for (int s = 0; s < nsplit; s++){
    long p = (long)bh*nsplit + s;
    float wv = __expf(Mpart[p*Nq + row] - M);
    accL += wv*Lpart[p*Nq + row];
    accO += wv*Opart[(p*Nq + row)*DHH + d];
  }
  int b = bh / HH, h = bh % HH;
  O[(long)b*sOb + (long)row*DD + h*DHH + d] = f2bf(accO/accL);
}

// ---------------- host ----------------
extern "C" void kernel_launch(void* const* d_in, const int* in_sizes, int n_in,
                              void* d_out, int out_size, void* d_ws, size_t ws_size,
                              hipStream_t stream) {
  (void)in_sizes; (void)n_in; (void)out_size; (void)ws_size;
  const float* x        = (const float*)d_in[0];
  const int*   mask     = (const int*)d_in[1];
  const float* pos_emb  = (const float*)d_in[2];
  const float* sim_p_w  = (const float*)d_in[3];
  const float* sim_p_b  = (const float*)d_in[4];
  const float* sim_n_w  = (const float*)d_in[5];
  const float* sim_n_b  = (const float*)d_in[6];
  const float* adj_w    = (const float*)d_in[7];
  const float* gnn_p_w1 = (const float*)d_in[8];
  const float* gnn_p_w2 = (const float*)d_in[9];
  const float* gnn_n_w1 = (const float*)d_in[10];
  const float* gnn_n_w2 = (const float*)d_in[11];
  const float* ln1_g = (const float*)d_in[12]; const float* ln1_b = (const float*)d_in[13];
  const float* ln2_g = (const float*)d_in[14]; const float* ln2_b = (const float*)d_in[15];
  const float* ln3_g = (const float*)d_in[16]; const float* ln3_b = (const float*)d_in[17];
  const float* ln4_g = (const float*)d_in[18]; const float* ln4_b = (const float*)d_in[19];
  const float* ln5_g = (const float*)d_in[20]; const float* ln5_b = (const float*)d_in[21];
  const float* i2q_wq = (const float*)d_in[22];
  const float* i2q_wk = (const float*)d_in[23];
  const float* i2q_wv = (const float*)d_in[24];
  const float* i2q_wo = (const float*)d_in[25];
  const float* q2i_wq = (const float*)d_in[26];
  const float* q2i_wk = (const float*)d_in[27];
  const float* q2i_wv = (const float*)d_in[28];
  const float* q2i_wo = (const float*)d_in[29];
  const float* i2q_bo = (const float*)d_in[30];
  const float* q2i_bo = (const float*)d_in[31];
  const float* mlp_w  = (const float*)d_in[32];
  const float* mlp_b  = (const float*)d_in[33];
  const float* g_i2t  = (const float*)d_in[34];
  const float* g_t2i  = (const float*)d_in[35];

  float* out  = (float*)d_out;
  float* simP = out + (size_t)BB*NN*DD;
  float* simN = simP + (size_t)BB*NN;

  char* w8 = (char*)d_ws;
  size_t off = 0;
  auto take = [&](size_t bytes)->void*{
    void* p = (void*)(w8 + off);
    off += (bytes + 255) & ~(size_t)255;
    return p;
  };
  float* part   = (float*)take((size_t)BB*32*2*DD*4);
  float* pcnt   = (float*)take((size_t)BB*32*2*4);
  float* posq   = (float*)take((size_t)BB*2*DD*4);
  float* vvec   = (float*)take((size_t)BB*2*DD*4);
  float* cscal  = (float*)take((size_t)BB*2*4);
  int*   idxb   = (int*)take((size_t)BB*2*256*4);
  float* wb     = (float*)take((size_t)BB*2*256*4);
  float* node   = (float*)take((size_t)BB*384*DD*4);
  float* gA     = (float*)take((size_t)BB*384*DD*4);   // also t3
  float* gadjP  = (float*)take((size_t)BB*256*256*4);
  float* gadjN  = (float*)take((size_t)BB*128*128*4);
  float* query  = (float*)take((size_t)BB*384*DD*4);   // also t1
  float* query2 = (float*)take((size_t)BB*384*DD*4);   // also t2
  unsigned short* xhatq  = (unsigned short*)take((size_t)BB*384*DD*2);
  unsigned short* qh     = (unsigned short*)take((size_t)BB*384*DD*2);
  unsigned short* attnZ  = (unsigned short*)take((size_t)BB*384*DD*2);
  unsigned short* xhatq2 = (unsigned short*)take((size_t)BB*384*DD*2);
  unsigned short* kv2    = (unsigned short*)take((size_t)BB*384*512*2);
  unsigned short* xhat   = (unsigned short*)take((size_t)BB*NN*DD*2);
  unsigned short* kvq    = (unsigned short*)take((size_t)BB*NN*768*2);
  float* featb2 = (float*)take((size_t)BB*NN*DD*4);
  float* Mpart  = (float*)take((size_t)BB*HH*8*384*4);
  float* Lpart  = (float*)take((size_t)BB*HH*8*384*4);
  unsigned short* wTq1  = (unsigned short*)take((size_t)65536*2);
  unsigned short* wTbig = (unsigned short*)take((size_t)3*65536*2);
  unsigned short* wTkv2 = (unsigned short*)take((size_t)2*65536*2);
  unsigned short* wTmlp = (unsigned short*)take((size_t)65536*2);
  unsigned short* wTo1  = (unsigned short*)take((size_t)65536*2);
  unsigned short* wTo2  = (unsigned short*)take((size_t)65536*2);
  float* biasQ1  = (float*)take(256*4);
  float* biasBig = (float*)take(768*4);
  float* biasKV2 = (float*)take(512*4);
  float* biasMlp = (float*)take(256*4);
  // overlays (disjoint lifetimes):
  float* t1 = query;
  float* t2 = query2;
  float* t3 = gA;
  unsigned short* attn2 = xhat;
  unsigned short* xhat5 = kvq;
  float* Opart = featb2;

  const long sQ  = 384L*DD;
  const long sX  = (long)NN*DD;
  const float* NF = nullptr;

  // ---- weight folds ----
  FoldArgs fa;
  fa.W[0]=i2q_wq; fa.g[0]=ln1_g; fa.BT[0]=wTq1;
  fa.W[1]=i2q_wk; fa.g[1]=ln2_g; fa.BT[1]=wTbig;
  fa.W[2]=i2q_wv; fa.g[2]=ln2_g; fa.BT[2]=wTbig + 256*256;
  fa.W[3]=q2i_wq; fa.g[3]=ln3_g; fa.BT[3]=wTbig + 512*256;
  fa.W[4]=q2i_wk; fa.g[4]=ln4_g; fa.BT[4]=wTkv2;
  fa.W[5]=q2i_wv; fa.g[5]=ln4_g; fa.BT[5]=wTkv2 + 256*256;
  fa.W[6]=mlp_w;  fa.g[6]=ln5_g; fa.BT[6]=wTmlp;
  fa.W[7]=i2q_wo; fa.g[7]=nullptr; fa.BT[7]=wTo1;
  fa.W[8]=q2i_wo; fa.g[8]=nullptr; fa.BT[8]=wTo2;
  fold_w<<<dim3(16,9), 256, 0, stream>>>(fa);
  BiasArgs ba;
  ba.W[0]=i2q_wq; ba.b[0]=ln1_b; ba.addb[0]=nullptr; ba.out[0]=biasQ1;
  ba.W[1]=i2q_wk; ba.b[1]=ln2_b; ba.addb[1]=nullptr; ba.out[1]=biasBig;
  ba.W[2]=i2q_wv; ba.b[2]=ln2_b; ba.addb[2]=nullptr; ba.out[2]=biasBig+256;
  ba.W[3]=q2i_wq; ba.b[3]=ln3_b; ba.addb[3]=nullptr; ba.out[3]=biasBig+512;
  ba.W[4]=q2i_wk; ba.b[4]=ln4_b; ba.addb[4]=nullptr; ba.out[4]=biasKV2;
  ba.W[5]=q2i_wv; ba.b[5]=ln4_b; ba.addb[5]=nullptr; ba.out[5]=biasKV2+256;
  ba.W[6]=mlp_w;  ba.b[6]=ln5_b; ba.addb[6]=mlp_b;   ba.out[6]=biasMlp;
  fold_b<<<7, 256, 0, stream>>>(ba);

  // ---- stats / sims / topk / gather ----
  stats_part<<<dim3(32, BB), 256, 0, stream>>>(x, mask, part, pcnt);
  stats_final<<<BB, 256, 0, stream>>>(part, pcnt, posq);
  sim_vec<<<BB, 256, 0, stream>>>(sim_p_w, sim_p_b, sim_n_w, sim_n_b, posq, vvec, cscal);
  sim_norm_kernel<<<dim3(NN/4, BB), 256, 0, stream>>>(x, vvec, cscal, simP, simN, xhat);
  topk_radix<<<2*BB, 256, 0, stream>>>(simP, simN, idxb, wb);
  gather_nodes<<<dim3(KPP+KNN, BB), 256, 0, stream>>>(x, idxb, wb, node);

  // ---- GCN (pos/neg paired) ----
  GP z = {};
  // [g1 | t1pos | t1neg] in one launch
  {
    GP4 g;
    g.p[0] = { node, 384L*DD, 256, adj_w, 0, 256, gA, 384L*DD, 256, nullptr, nullptr, 384, 256, 256, 1.f, 0 };
    g.p[1] = { node, 384L*DD, 256, gnn_p_w1, 0, 256, t1, 384L*DD, 256, nullptr, nullptr, 256, 256, 256, 1.f, 0 };
    g.p[2] = { node + 256L*DD, 384L*DD, 256, gnn_n_w1, 0, 256, t1 + 256L*DD, 384L*DD, 256, nullptr, nullptr, 128, 256, 256, 1.f, 0 };
    g.p[3] = z;
    gemm_multi<<<dim3(4,6,3*BB), 256, 0, stream>>>(g);
  }
  // gadj = softmax( gA @ node^T * scale )
  {
    GP4 g;
    g.p[0] = { gA, 384L*DD, 256, node, 384L*DD, 256, gadjP, 65536L, 256, nullptr, nullptr, 256, 256, 256, 0.0625f, FLAG_TRANSB };
    g.p[1] = { gA + 256L*DD, 384L*DD, 256, node + 256L*DD, 384L*DD, 256, gadjN, 16384L, 128, nullptr, nullptr, 128, 128, 256, 0.0625f, FLAG_TRANSB };
    g.p[2] = z; g.p[3] = z;
    gemm_multi<<<dim3(4,4,2*BB), 256, 0, stream>>>(g);
  }
  softmax_dual<<<768, 256, 0, stream>>>(gadjP, 256, 256, 65536L, BB*256,
                                        gadjN, 128, 128, 16384L, BB*128);
  // t2 = relu(adj @ t1)
  {
    GP4 g;
    g.p[0] = { gadjP, 65536L, 256, t1, 384L*DD, 256, t2, 384L*DD, 256, nullptr, nullptr, 256, 256, 256, 1.f, FLAG_RELU };
    g.p[1] = { gadjN, 16384L, 128, t1 + 256L*DD, 384L*DD, 256, t2 + 256L*DD, 384L*DD, 256, nullptr, nullptr, 128, 256, 128, 1.f, FLAG_RELU };
    g.p[2] = z; g.p[3] = z;
    gemm_multi<<<dim3(4,4,2*BB), 256, 0, stream>>>(g);
  }
  // t3 = t2 @ w2
  {
    GP4 g;
    g.p[0] = { t2, 384L*DD, 256, gnn_p_w2, 0, 256, t3, 384L*DD, 256, nullptr, nullptr, 256, 256, 256, 1.f, 0 };
    g.p[1] = { t2 + 256L*DD, 384L*DD, 256, gnn_n_w2, 0, 256, t3 + 256L*DD, 384L*DD, 256, nullptr, nullptr, 128, 256, 256, 1.f, 0 };
    g.p[2] = z; g.p[3] = z;
    gemm_multi<<<dim3(4,4,2*BB), 256, 0, stream>>>(g);
  }
  // query = adj @ t3 + pos_emb[idx]  (gather fused in epilogue)
  {
    GP4 g;
    g.p[0] = { gadjP, 65536L, 256, t3, 384L*DD, 256, query, 384L*DD, 256, idxb, pos_emb, 256, 256, 256, 1.f, 0 };
    g.p[1] = { gadjN, 16384L, 128, t3 + 256L*DD, 384L*DD, 256, query + 256L*DD, 384L*DD, 256, idxb + 256, pos_emb, 128, 256, 128, 1.f, 0 };
    g.p[2] = z; g.p[3] = z;
    gemm_multi<<<dim3(4,4,2*BB), 256, 0, stream>>>(g);
  }

  // ---- LN core of query ----
  rownorm_kernel<<<BB*384/4, 256, 0, stream>>>(query, xhatq, BB*384);

  // (a) qh = xhatq @ wq' + b'
  gemm128<unsigned short,false,false><<<dim3(2,3,BB),256,0,stream>>>(
      xhatq, sQ, wTq1, qh, sQ, 256, NF, 0, biasQ1, NF);
  // (b) [kh|vh|qh2] = xhat @ [wk'|wv'|wq2'] + b'
  gemm128<unsigned short,false,false><<<dim3(6,32,BB),256,0,stream>>>(
      xhat, sX, wTbig, kvq, (long)NN*768, 768, NF, 0, biasBig, NF);
  // i2q flash (K-split 8) + combine
  flash_kernel<<<dim3(6*8, HH, BB), 256, 0, stream>>>(
      qh, sQ, 256, kvq, kvq + 256, (long)NN*768, 768,
      attnZ, sQ, Opart, Mpart, Lpart, 384, NN, 8, 0.125f);
  flash_combine<<<BB*HH*384/4, 256, 0, stream>>>(Opart, Mpart, Lpart, attnZ, sQ, 384, 8);
  // (c) query2 = query + g_i2t .* (attnZ @ wo + bo)
  gemm128<float,true,true><<<dim3(2,3,BB),256,0,stream>>>(
      attnZ, sQ, wTo1, query2, sQ, 256, query, sQ, i2q_bo, g_i2t);

  // ---- q2i ----
  rownorm_kernel<<<BB*384/4, 256, 0, stream>>>(query2, xhatq2, BB*384);
  // (d) [k2|v2] = xhatq2 @ [wk2'|wv2'] + b'
  gemm128<unsigned short,false,false><<<dim3(4,3,BB),256,0,stream>>>(
      xhatq2, sQ, wTkv2, kv2, 384L*512, 512, NF, 0, biasKV2, NF);
  flash_kernel<<<dim3(NN/64, HH, BB), 256, 0, stream>>>(
      kvq + 512, (long)NN*768, 768, kv2, kv2 + 256, 384L*512, 512,
      attn2, sX, nullptr, nullptr, nullptr, NN, 384, 1, 0.125f);
  // (e) featb2 = x + g_t2i .* (attn2 @ wo + bo)
  gemm128<float,true,true><<<dim3(2,32,BB),256,0,stream>>>(
      attn2, sX, wTo2, featb2, sX, 256, x, sX, q2i_bo, g_t2i);

  // ---- final MLP ----
  rownorm_kernel<<<BB*NN/4, 256, 0, stream>>>(featb2, xhat5, BB*NN);
  // (f) out = featb2 + xhat5 @ mlp' + b'
  gemm128<float,true,false><<<dim3(2,32,BB),256,0,stream>>>(
      xhat5, sX, wTmlp, out, sX, 256, featb2, sX, biasMlp, NF);
}

// Round 5
// 588.279 us; speedup vs baseline: 1.5986x; 1.0292x over previous
//
#include <hip/hip_runtime.h>

#define BB 8
#define NN 4096
#define DD 256
#define HH 4
#define DHH 64
#define KPP 256
#define KNN 128

typedef float f32x4 __attribute__((ext_vector_type(4)));
typedef short bf16x8 __attribute__((ext_vector_type(8)));
typedef short bf16x4 __attribute__((ext_vector_type(4)));

#define FLAG_TRANSB 1
#define FLAG_RELU   2

__device__ __forceinline__ float bf2f(unsigned short u){
  union { unsigned int i; float f; } v; v.i = ((unsigned int)u) << 16; return v.f;
}
__device__ __forceinline__ unsigned short f2bf(float f){
  union { float f; unsigned int i; } v; v.f = f;
  return (unsigned short)((v.i + 0x7FFFu + ((v.i >> 16) & 1u)) >> 16);
}
__device__ __forceinline__ void gload16(const void* g, void* l){
  __builtin_amdgcn_global_load_lds((const __attribute__((address_space(1))) void*)g,
                                   (__attribute__((address_space(3))) void*)l, 16, 0, 0);
}

// ---------------- masked-mean stats ----------------
__global__ void stats_part(const float* __restrict__ x, const int* __restrict__ mask,
                           float* __restrict__ part, float* __restrict__ pcnt){
  int b = blockIdx.y, c = blockIdx.x, d = threadIdx.x;
  int n0 = c * 128;
  float sp = 0.f, sn = 0.f; int cp = 0, cn = 0;
  const float* xb = x + ((long)b*NN + n0)*DD + d;
  const int* mb = mask + (long)b*NN + n0;
  for (int r = 0; r < 128; r++){
    int mv = mb[r];
    float v = xb[(long)r*DD];
    if (mv == 1){ sp += v; cp++; }
    else if (mv == -1){ sn += v; cn++; }
  }
  part[(((long)(b*32+c)*2+0)*DD)+d] = sp;
  part[(((long)(b*32+c)*2+1)*DD)+d] = sn;
  if (d == 0){ pcnt[(b*32+c)*2+0] = (float)cp; pcnt[(b*32+c)*2+1] = (float)cn; }
}

// ---------------- merged stats_final + sim_vec ----------------
__global__ void stats_vec(const float* __restrict__ part, const float* __restrict__ pcnt,
                          const float* __restrict__ Wp, const float* __restrict__ bp,
                          const float* __restrict__ Wn, const float* __restrict__ bn,
                          float* __restrict__ vvec, float* __restrict__ cscal){
  int b = blockIdx.x, k = threadIdx.x;
  __shared__ float qp[256], qn[256], red[256];
  {
    float sp=0.f, sn=0.f, cp=0.f, cn=0.f;
    for (int c = 0; c < 32; c++){
      sp += part[(((long)(b*32+c)*2+0)*DD)+k];
      sn += part[(((long)(b*32+c)*2+1)*DD)+k];
      cp += pcnt[(b*32+c)*2+0];
      cn += pcnt[(b*32+c)*2+1];
    }
    qp[k] = sp / (cp + 1e-6f);
    qn[k] = sn / (cn + 1e-6f);
  }
  __syncthreads();
  float vp = 0.f, vn = 0.f;
  for (int j = 0; j < DD; j++){ vp += Wp[(long)k*DD+j]*qp[j]; vn += Wn[(long)k*DD+j]*qn[j]; }
  vvec[(long)(b*2+0)*DD+k] = vp; vvec[(long)(b*2+1)*DD+k] = vn;
  red[k] = bp[k]*qp[k];
  __syncthreads();
  for (int s = 128; s > 0; s >>= 1){ if (k < s) red[k] += red[k+s]; __syncthreads(); }
  if (k == 0) cscal[b*2+0] = red[0];
  __syncthreads();
  red[k] = bn[k]*qn[k];
  __syncthreads();
  for (int s = 128; s > 0; s >>= 1){ if (k < s) red[k] += red[k+s]; __syncthreads(); }
  if (k == 0) cscal[b*2+1] = red[0];
}

// ---------------- fused sims + LN-core of x ----------------
__global__ void sim_norm_kernel(const float* __restrict__ x, const float* __restrict__ vvec,
                                const float* __restrict__ cscal,
                                float* __restrict__ simP, float* __restrict__ simN,
                                unsigned short* __restrict__ xhat){
  int b = blockIdx.y;
  int w = threadIdx.x >> 6, lane = threadIdx.x & 63;
  int n = blockIdx.x*4 + w;
  long row = (long)b*NN + n;
  const float4* xr = (const float4*)(x + row*DD);
  float4 xv = xr[lane];
  float4 a = ((const float4*)(vvec + (long)(b*2+0)*DD))[lane];
  float4 c = ((const float4*)(vvec + (long)(b*2+1)*DD))[lane];
  float sp = xv.x*a.x + xv.y*a.y + xv.z*a.z + xv.w*a.w;
  float sn = xv.x*c.x + xv.y*c.y + xv.z*c.z + xv.w*c.w;
  float s  = xv.x+xv.y+xv.z+xv.w;
  float q  = xv.x*xv.x+xv.y*xv.y+xv.z*xv.z+xv.w*xv.w;
  for (int off = 32; off; off >>= 1){
    sp += __shfl_xor(sp, off); sn += __shfl_xor(sn, off);
    s  += __shfl_xor(s, off);  q  += __shfl_xor(q, off);
  }
  float m = s*(1.f/256.f);
  float var = q*(1.f/256.f) - m*m;
  float rinv = rsqrtf(var + 1e-5f);
  ushort4 o;
  o.x = f2bf((xv.x-m)*rinv); o.y = f2bf((xv.y-m)*rinv);
  o.z = f2bf((xv.z-m)*rinv); o.w = f2bf((xv.w-m)*rinv);
  ((ushort4*)(xhat + row*DD))[lane] = o;
  if (lane == 0){
    float zp = sp + cscal[b*2+0], zn = sn + cscal[b*2+1];
    simP[row] = 1.f/(1.f+expf(-zp));
    simN[row] = 1.f/(1.f+expf(-zn));
  }
}

// ---------------- top-k (3-pass radix, parallel scans) + fused node gather ----------------
__global__ __launch_bounds__(256) void topk_radix(const float* __restrict__ simP,
                                                  const float* __restrict__ simN,
                                                  const float* __restrict__ x,
                                                  int* __restrict__ idxb, float* __restrict__ wb,
                                                  float* __restrict__ node){
  __shared__ unsigned int vals[4096];
  __shared__ unsigned int hist[4096];   // also reused: [0..255] sel idx, [256..511] sel val bits
  __shared__ unsigned short eql[4096];
  __shared__ unsigned int tsum[256];
  __shared__ unsigned int sB, sRem, sCG, sCnt, sEq;
  int id = blockIdx.x; int sgn = id & 1, b = id >> 1;
  int K = (sgn == 0) ? KPP : KNN;
  const float* s = (sgn == 0 ? simP : simN) + (long)b*NN;
  int t = threadIdx.x;
  if (t == 0){ sCG = 0; sCnt = 0; sEq = 0; }
  for (int i = t; i < 4096; i += 256){ vals[i] = __float_as_uint(s[i]); hist[i] = 0; }
  __syncthreads();

  auto find_thresh = [&](int NB, unsigned need){
    int per = NB >> 8;
    int base = t*per;
    unsigned local = 0;
    for (int j = 0; j < per; j++) local += hist[base+j];
    tsum[t] = local;
    __syncthreads();
    #pragma unroll
    for (int st = 1; st < 256; st <<= 1){
      unsigned v = (t + st < 256) ? tsum[t+st] : 0u;
      __syncthreads();
      tsum[t] += v;
      __syncthreads();
    }
    unsigned after = (t < 255) ? tsum[t+1] : 0u;
    if (after < need && after + local >= need){
      unsigned c = after;
      for (int j = per-1; j >= 0; j--){
        unsigned h = hist[base+j];
        c += h;
        if (c >= need){
          sB = (unsigned)(base+j);
          sRem = need - (c - h);
          atomicAdd(&sCG, c - h);
          break;
        }
      }
    }
    __syncthreads();
  };

  for (int i = t; i < 4096; i += 256) atomicAdd(&hist[vals[i] >> 20], 1u);
  __syncthreads();
  find_thresh(4096, (unsigned)K);
  unsigned B1 = sB, rem1 = sRem;
  __syncthreads();
  for (int i = t; i < 4096; i += 256) hist[i] = 0;
  __syncthreads();
  for (int i = t; i < 4096; i += 256){
    unsigned v = vals[i];
    if ((v >> 20) == B1) atomicAdd(&hist[(v >> 8) & 0xFFFu], 1u);
  }
  __syncthreads();
  find_thresh(4096, rem1);
  unsigned B2 = sB, rem2 = sRem;
  unsigned pre = (B1 << 12) | B2;
  __syncthreads();
  hist[t] = 0;
  __syncthreads();
  for (int i = t; i < 4096; i += 256){
    unsigned v = vals[i];
    if ((v >> 8) == pre) atomicAdd(&hist[v & 0xFFu], 1u);
  }
  __syncthreads();
  find_thresh(256, rem2);
  unsigned T = (pre << 8) | sB;
  unsigned cg = sCG;
  __syncthreads();
  hist[t] = 0;      // clear for reuse as selection mirror
  __syncthreads();

  int* oi = idxb + (long)id*256;
  float* ow = wb + (long)id*256;
  for (int i = t; i < 4096; i += 256){
    unsigned v = vals[i];
    if (v > T){
      unsigned p = atomicAdd(&sCnt, 1u);
      oi[p] = i; ow[p] = __uint_as_float(v);
      hist[p] = (unsigned)i; hist[256+p] = v;
    }
    else if (v == T){ unsigned e = atomicAdd(&sEq, 1u); eql[e] = (unsigned short)i; }
  }
  __syncthreads();
  int ne = K - (int)cg;
  int eqn = (int)sEq;
  for (int e = t; e < eqn; e += 256){
    int myi = eql[e]; int r = 0;
    for (int e2 = 0; e2 < eqn; e2++) r += (eql[e2] < myi);
    if (r < ne){
      oi[cg + r] = myi; ow[cg + r] = __uint_as_float(T);
      hist[cg + r] = (unsigned)myi; hist[256 + cg + r] = T;
    }
  }
  __syncthreads();
  // fused gather: node rows (pos at 0, neg at 256)
  int rbase = (sgn == 0) ? 0 : KPP;
  int lane = t & 63, rw = t >> 6;
  for (int i0 = 0; i0 < K; i0 += 4){
    int r = i0 + rw;
    int idx = (int)hist[r];
    float wv = __uint_as_float(hist[256 + r]);
    float4 vsel;
    if (wv > 0.6f) vsel = ((const float4*)(x + ((long)b*NN + idx)*DD))[lane];
    else vsel = (float4){0.f,0.f,0.f,0.f};
    ((float4*)(node + ((long)b*384 + rbase + r)*DD))[lane] = vsel;
  }
}

// ---------------- dual row softmax ----------------
__global__ void softmax_dual(float* __restrict__ A0, int L0, int rpb0, long bs0, int rows0,
                             float* __restrict__ A1, int L1, int rpb1, long bs1, int rows1){
  int w = threadIdx.x >> 6, lane = threadIdx.x & 63;
  long row = (long)blockIdx.x*4 + w;
  float* A; int L, rpb; long bs;
  if (row < rows0){ A = A0; L = L0; rpb = rpb0; bs = bs0; }
  else { row -= rows0; if (row >= rows1) return; A = A1; L = L1; rpb = rpb1; bs = bs1; }
  int b = (int)(row / rpb), r = (int)(row % rpb);
  float* a = A + (long)b*bs + (long)r*L;
  int e = L >> 6;
  float vals[4]; float mx = -1e30f;
  for (int j = 0; j < e; j++){ vals[j] = a[lane*e+j]; mx = fmaxf(mx, vals[j]); }
  for (int off = 32; off; off >>= 1) mx = fmaxf(mx, __shfl_xor(mx, off));
  float sum = 0.f;
  for (int j = 0; j < e; j++){ vals[j] = expf(vals[j]-mx); sum += vals[j]; }
  for (int off = 32; off; off >>= 1) sum += __shfl_xor(sum, off);
  float rinv = 1.f/sum;
  for (int j = 0; j < e; j++) a[lane*e+j] = vals[j]*rinv;
}

// ---------------- row LayerNorm core (no affine) f32 -> bf16 ----------------
__global__ void rownorm_kernel(const float* __restrict__ X, unsigned short* __restrict__ Y, int rows){
  int w = threadIdx.x >> 6, lane = threadIdx.x & 63;
  long row = (long)blockIdx.x*4 + w;
  if (row >= rows) return;
  const float4* xr = (const float4*)(X + row*DD);
  float4 xv = xr[lane];
  float s = xv.x+xv.y+xv.z+xv.w;
  float q = xv.x*xv.x+xv.y*xv.y+xv.z*xv.z+xv.w*xv.w;
  for (int off = 32; off; off >>= 1){ s += __shfl_xor(s, off); q += __shfl_xor(q, off); }
  float m = s*(1.f/256.f);
  float var = q*(1.f/256.f) - m*m;
  float rinv = rsqrtf(var + 1e-5f);
  ushort4 o;
  o.x = f2bf((xv.x-m)*rinv); o.y = f2bf((xv.y-m)*rinv);
  o.z = f2bf((xv.z-m)*rinv); o.w = f2bf((xv.w-m)*rinv);
  ((ushort4*)(Y + row*DD))[lane] = o;
}

// ---------------- weight fold ----------------
struct FoldArgs { const float* W[9]; const float* g[9]; unsigned short* BT[9]; };
struct BiasArgs { const float* W[7]; const float* b[7]; const float* addb[7]; float* out[7]; };

__global__ void fold_w(FoldArgs fa){
  int m = blockIdx.y, tile = blockIdx.x, t = threadIdx.x;
  const float* W = fa.W[m]; const float* g = fa.g[m]; unsigned short* BT = fa.BT[m];
  __shared__ float T[64][65];
  int tn = (tile & 3)*64, tk = (tile >> 2)*64;
  #pragma unroll 4
  for (int p = 0; p < 16; p++){
    int kl = p*4 + (t >> 6), nl = t & 63;
    float v = W[(long)(tk+kl)*256 + tn + nl];
    if (g) v *= g[tk+kl];
    T[kl][nl] = v;
  }
  __syncthreads();
  #pragma unroll 4
  for (int p = 0; p < 16; p++){
    int nl = p*4 + (t >> 6), kl = t & 63;
    BT[(long)(tn+nl)*256 + tk + kl] = f2bf(T[kl][nl]);
  }
}

__global__ void fold_b(BiasArgs ba){
  int m = blockIdx.x, n = threadIdx.x;
  const float* W = ba.W[m]; const float* b = ba.b[m];
  float s = (ba.addb[m] != nullptr) ? ba.addb[m][n] : 0.f;
  for (int k = 0; k < 256; k++) s += b[k]*W[(long)k*256+n];
  ba.out[m][n] = s;
}

// ---------------- multi-parameter f32 GEMM 64x64 (GCN path) ----------------
struct GP {
  const float* A; long sAb; int lda;
  const float* B; long sBb; int ldb;
  float* C; long sCb; int ldc;
  const int* pidx; const float* pe;
  int M, N, K; float alpha; int flags;
};
struct GP4 { GP p[4]; };

__global__ __launch_bounds__(256) void gemm_multi(GP4 g4){
  GP p = g4.p[blockIdx.z >> 3];
  int b = blockIdx.z & 7;
  int m0 = blockIdx.y*64, n0 = blockIdx.x*64;
  if (m0 >= p.M || n0 >= p.N) return;
  __shared__ __align__(16) unsigned short As[64*40];
  __shared__ __align__(16) unsigned short Bs[64*40];
  const float* Ab = p.A + (long)b*p.sAb;
  const float* Bb = p.B + (long)b*p.sBb;
  int t = threadIdx.x;
  int w = t >> 6, lane = t & 63, lrowi = lane & 15, lquad = lane >> 4;
  int wm = w >> 1, wn = w & 1;
  f32x4 acc[2][2];
  #pragma unroll
  for (int i = 0; i < 2; i++)
    #pragma unroll
    for (int j = 0; j < 2; j++) acc[i][j] = (f32x4){0.f,0.f,0.f,0.f};
  int am = t >> 2, akq = t & 3;
  for (int k0 = 0; k0 < p.K; k0 += 32){
    {
      const float4* s4 = (const float4*)(Ab + (long)(m0+am)*p.lda + k0 + akq*8);
      float4 u = s4[0], vv = s4[1];
      unsigned short tmp[8];
      tmp[0]=f2bf(u.x); tmp[1]=f2bf(u.y); tmp[2]=f2bf(u.z); tmp[3]=f2bf(u.w);
      tmp[4]=f2bf(vv.x); tmp[5]=f2bf(vv.y); tmp[6]=f2bf(vv.z); tmp[7]=f2bf(vv.w);
      *(uint4*)(&As[am*40 + akq*8]) = *(uint4*)tmp;
    }
    if (p.flags & FLAG_TRANSB){
      const float4* s4 = (const float4*)(Bb + (long)(n0+am)*p.ldb + k0 + akq*8);
      float4 u = s4[0], vv = s4[1];
      unsigned short tmp[8];
      tmp[0]=f2bf(u.x); tmp[1]=f2bf(u.y); tmp[2]=f2bf(u.z); tmp[3]=f2bf(u.w);
      tmp[4]=f2bf(vv.x); tmp[5]=f2bf(vv.y); tmp[6]=f2bf(vv.z); tmp[7]=f2bf(vv.w);
      *(uint4*)(&Bs[am*40 + akq*8]) = *(uint4*)tmp;
    } else {
      int bn = t & 63, bkb = (t >> 6)*8;
      #pragma unroll
      for (int j = 0; j < 8; j++)
        Bs[bn*40 + bkb + j] = f2bf(Bb[(long)(k0+bkb+j)*p.ldb + n0 + bn]);
    }
    __syncthreads();
    bf16x8 af[2], bfr[2];
    #pragma unroll
    for (int i = 0; i < 2; i++)
      af[i] = *(const bf16x8*)(&As[(wm*32 + i*16 + lrowi)*40 + lquad*8]);
    #pragma unroll
    for (int j = 0; j < 2; j++)
      bfr[j] = *(const bf16x8*)(&Bs[(wn*32 + j*16 + lrowi)*40 + lquad*8]);
    #pragma unroll
    for (int i = 0; i < 2; i++)
      #pragma unroll
      for (int j = 0; j < 2; j++)
        acc[i][j] = __builtin_amdgcn_mfma_f32_16x16x32_bf16(af[i], bfr[j], acc[i][j], 0, 0, 0);
    __syncthreads();
  }
  float* Cb = p.C + (long)b*p.sCb;
  #pragma unroll
  for (int i = 0; i < 2; i++)
    #pragma unroll
    for (int j = 0; j < 2; j++){
      int col = n0 + wn*32 + j*16 + lrowi;
      #pragma unroll
      for (int r = 0; r < 4; r++){
        int row = m0 + wm*32 + i*16 + lquad*4 + r;
        float v = p.alpha*acc[i][j][r];
        if (p.flags & FLAG_RELU) v = fmaxf(v, 0.f);
        if (p.pidx != nullptr){
          int idx = p.pidx[b*512 + row];
          v += p.pe[(long)idx*256 + col];
        }
        Cb[(long)row*p.ldc + col] = v;
      }
    }
}

// ---------------- fast 128x128 bf16 GEMM (K=256) ----------------
template<typename OT, bool RES, bool GATE>
__global__ __launch_bounds__(256) void gemm128(
    const unsigned short* __restrict__ A, long sAb,
    const unsigned short* __restrict__ BT,
    OT* __restrict__ C, long sCb, int ldc,
    const float* __restrict__ R, long sRb,
    const float* __restrict__ bias, const float* __restrict__ gate)
{
  __shared__ __align__(16) unsigned short As[4096];
  __shared__ __align__(16) unsigned short Bs[4096];
  int t = threadIdx.x;
  int w = t >> 6, lane = t & 63, lrowi = lane & 15, lquad = lane >> 4;
  int wm = w >> 1, wn = w & 1;
  int m0 = blockIdx.y*128, n0 = blockIdx.x*128;
  const unsigned short* Ab = A + (long)blockIdx.z*sAb + (long)m0*256;
  const unsigned short* Bb = BT + (long)n0*256;
  int g0 = t, g1 = 256 + t;
  int row0 = g0 >> 2, kq0 = g0 & 3;
  int row1 = g1 >> 2, kq1 = g1 & 3;
  f32x4 acc[4][4];
  #pragma unroll
  for (int i = 0; i < 4; i++)
    #pragma unroll
    for (int j = 0; j < 4; j++) acc[i][j] = (f32x4){0.f,0.f,0.f,0.f};

  for (int k0 = 0; k0 < 256; k0 += 32){
    gload16(Ab + (long)row0*256 + k0 + kq0*8, &As[g0*8]);
    gload16(Ab + (long)row1*256 + k0 + kq1*8, &As[g1*8]);
    gload16(Bb + (long)row0*256 + k0 + kq0*8, &Bs[g0*8]);
    gload16(Bb + (long)row1*256 + k0 + kq1*8, &Bs[g1*8]);
    __syncthreads();
    bf16x8 af[4], bfr[4];
    #pragma unroll
    for (int i = 0; i < 4; i++)
      af[i] = *(const bf16x8*)(&As[((wm*64 + i*16 + lrowi)*4 + lquad)*8]);
    #pragma unroll
    for (int j = 0; j < 4; j++)
      bfr[j] = *(const bf16x8*)(&Bs[((wn*64 + j*16 + lrowi)*4 + lquad)*8]);
    #pragma unroll
    for (int i = 0; i < 4; i++)
      #pragma unroll
      for (int j = 0; j < 4; j++)
        acc[i][j] = __builtin_amdgcn_mfma_f32_16x16x32_bf16(af[i], bfr[j], acc[i][j], 0, 0, 0);
    __syncthreads();
  }
  OT* Cb = C + (long)blockIdx.z*sCb;
  const float* Rb = RES ? (R + (long)blockIdx.z*sRb) : nullptr;
  #pragma unroll
  for (int j = 0; j < 4; j++){
    int col = n0 + wn*64 + j*16 + lrowi;
    float bv = bias[col];
    float gv = GATE ? gate[col] : 1.f;
    #pragma unroll
    for (int i = 0; i < 4; i++){
      #pragma unroll
      for (int r = 0; r < 4; r++){
        int row = m0 + wm*64 + i*16 + lquad*4 + r;
        float v = acc[i][j][r] + bv;
        if (GATE) v *= gv;
        if (RES) v += Rb[(long)row*256 + col];
        if constexpr (sizeof(OT) == 4) Cb[(long)row*ldc + col] = v;
        else                           Cb[(long)row*ldc + col] = f2bf(v);
      }
    }
  }
}

// ---------------- flash cross-attention, multi-fragment, optional K-split ----------------
template<int NFRAG>
__global__ __launch_bounds__(256) void flash_kernel(
    const unsigned short* __restrict__ Q, long sQb, int ldq,
    const unsigned short* __restrict__ Kt, const unsigned short* __restrict__ Vt,
    long sKb, int ldkv,
    unsigned short* __restrict__ O, long sOb,
    float* __restrict__ Opart, float* __restrict__ Mpart, float* __restrict__ Lpart,
    int Nq, int Nk, int nsplit, float scale)
{
  __shared__ __align__(16) unsigned short Kl[32*72];
  __shared__ __align__(16) unsigned short Vl[64*36];
  __shared__ __align__(16) unsigned short Pl[4*NFRAG*16*40];
  int b = blockIdx.z, h = blockIdx.y;
  int nqg = Nq / (64*NFRAG);
  int qg = blockIdx.x % nqg, split = blockIdx.x / nqg;
  int kchunk = Nk / nsplit;
  int kbeg = split*kchunk, kend = kbeg + kchunk;
  int t = threadIdx.x, w = t >> 6, lane = t & 63, lrowi = lane & 15, lquad = lane >> 4;
  int q0 = qg*(64*NFRAG) + w*(16*NFRAG);
  const unsigned short* Qb = Q + (long)b*sQb + h*DHH;
  const unsigned short* Kb = Kt + (long)b*sKb + h*DHH;
  const unsigned short* Vb = Vt + (long)b*sKb + h*DHH;
  bf16x8 qa[NFRAG][2];
  #pragma unroll
  for (int f = 0; f < NFRAG; f++)
    #pragma unroll
    for (int kt = 0; kt < 2; kt++)
      qa[f][kt] = *(const bf16x8*)(Qb + (long)(q0 + f*16 + lrowi)*ldq + kt*32 + lquad*8);

  f32x4 o[NFRAG][4];
  float mrow[NFRAG][4], lsum[NFRAG][4];
  #pragma unroll
  for (int f = 0; f < NFRAG; f++)
    #pragma unroll
    for (int cj = 0; cj < 4; cj++){
      o[f][cj] = (f32x4){0.f,0.f,0.f,0.f};
      mrow[f][cj] = -INFINITY; lsum[f][cj] = 0.f;
    }
  int skq = t >> 3;
  int sdq = (t & 7)*8;
  unsigned short* Pw = &Pl[w*(NFRAG*16*40)];

  for (int kt0 = kbeg; kt0 < kend; kt0 += 32){
    {
      uint4 kv = *(const uint4*)(Kb + (long)(kt0+skq)*ldkv + sdq);
      *(uint4*)(&Kl[skq*72 + sdq]) = kv;
      uint4 vv = *(const uint4*)(Vb + (long)(kt0+skq)*ldkv + sdq);
      const unsigned short* vp = (const unsigned short*)&vv;
      #pragma unroll
      for (int j = 0; j < 8; j++) Vl[(sdq+j)*36 + skq] = vp[j];
    }
    __syncthreads();
    // K fragments (shared across all q-frags)
    bf16x8 kb0 = *(const bf16x8*)(&Kl[(0*16+lrowi)*72 + lquad*8]);
    bf16x8 kb1 = *(const bf16x8*)(&Kl[(0*16+lrowi)*72 + 32 + lquad*8]);
    bf16x8 kb2 = *(const bf16x8*)(&Kl[(1*16+lrowi)*72 + lquad*8]);
    bf16x8 kb3 = *(const bf16x8*)(&Kl[(1*16+lrowi)*72 + 32 + lquad*8]);
    // V fragments (stride 36 -> two b64 reads each)
    union { bf16x8 v8; bf16x4 v4[2]; } vbu[4];
    #pragma unroll
    for (int cj = 0; cj < 4; cj++){
      const unsigned short* vb = &Vl[(cj*16+lrowi)*36 + lquad*8];
      vbu[cj].v4[0] = *(const bf16x4*)vb;
      vbu[cj].v4[1] = *(const bf16x4*)(vb + 4);
    }
    #pragma unroll
    for (int f = 0; f < NFRAG; f++){
      f32x4 S0 = (f32x4){0.f,0.f,0.f,0.f}, S1 = (f32x4){0.f,0.f,0.f,0.f};
      S0 = __builtin_amdgcn_mfma_f32_16x16x32_bf16(qa[f][0], kb0, S0, 0, 0, 0);
      S0 = __builtin_amdgcn_mfma_f32_16x16x32_bf16(qa[f][1], kb1, S0, 0, 0, 0);
      S1 = __builtin_amdgcn_mfma_f32_16x16x32_bf16(qa[f][0], kb2, S1, 0, 0, 0);
      S1 = __builtin_amdgcn_mfma_f32_16x16x32_bf16(qa[f][1], kb3, S1, 0, 0, 0);
      #pragma unroll
      for (int r = 0; r < 4; r++){ S0[r] *= scale; S1[r] *= scale; }
      float al[4];
      #pragma unroll
      for (int r = 0; r < 4; r++){
        float m2 = fmaxf(S0[r], S1[r]);
        #pragma unroll
        for (int off = 1; off < 16; off <<= 1) m2 = fmaxf(m2, __shfl_xor(m2, off));
        float mn = fmaxf(mrow[f][r], m2);
        al[r] = __expf(mrow[f][r] - mn);
        mrow[f][r] = mn;
        float p0 = __expf(S0[r]-mn), p1 = __expf(S1[r]-mn);
        S0[r] = p0; S1[r] = p1;
        float s = p0 + p1;
        #pragma unroll
        for (int off = 1; off < 16; off <<= 1) s += __shfl_xor(s, off);
        lsum[f][r] = lsum[f][r]*al[r] + s;
      }
      #pragma unroll
      for (int cj = 0; cj < 4; cj++)
        #pragma unroll
        for (int r = 0; r < 4; r++) o[f][cj][r] *= al[r];
      unsigned short* Pf = Pw + f*(16*40);
      #pragma unroll
      for (int r = 0; r < 4; r++){
        Pf[(lquad*4+r)*40 + lrowi]      = f2bf(S0[r]);
        Pf[(lquad*4+r)*40 + 16 + lrowi] = f2bf(S1[r]);
      }
    }
    __asm__ volatile("s_waitcnt lgkmcnt(0)" ::: "memory");
    #pragma unroll
    for (int f = 0; f < NFRAG; f++){
      bf16x8 pa = *(const bf16x8*)(&Pw[f*(16*40) + lrowi*40 + lquad*8]);
      #pragma unroll
      for (int cj = 0; cj < 4; cj++)
        o[f][cj] = __builtin_amdgcn_mfma_f32_16x16x32_bf16(pa, vbu[cj].v8, o[f][cj], 0, 0, 0);
    }
    __syncthreads();
  }
  if (nsplit > 1){
    int p = (b*HH + h)*nsplit + split;
    float* Op = Opart + (long)p*Nq*DHH;
    #pragma unroll
    for (int f = 0; f < NFRAG; f++)
      #pragma unroll
      for (int r = 0; r < 4; r++){
        int row = q0 + f*16 + lquad*4 + r;
        #pragma unroll
        for (int cj = 0; cj < 4; cj++)
          Op[(long)row*DHH + cj*16 + lrowi] = o[f][cj][r];
        if (lrowi == 0){
          Mpart[(long)p*Nq + row] = mrow[f][r];
          Lpart[(long)p*Nq + row] = lsum[f][r];
        }
      }
  } else {
    unsigned short* Ob = O + (long)b*sOb + h*DHH;
    #pragma unroll
    for (int f = 0; f < NFRAG; f++)
      #pragma unroll
      for (int r = 0; r < 4; r++){
        float rl = 1.f/lsum[f][r];
        int row = q0 + f*16 + lquad*4 + r;
        #pragma unroll
        for (int cj = 0; cj < 4; cj++)
          Ob[(long)row*DD + cj*16 + lrowi] = f2bf(o[f][cj][r]*rl);
      }
  }
}

// ---------------- flash split combine ----------------
__global__ void flash_combine(const float* __restrict__ Opart, const float* __restrict__ Mpart,
                              const float* __restrict__ Lpart, unsigned short* __restrict__ O,
                              long sOb, int Nq, int nsplit){
  int gr = blockIdx.x*4 + (threadIdx.x >> 6);
  int d = threadIdx.x & 63;
  int bh = gr / Nq, row = gr % Nq;
  float M = -INFINITY;
  for (int s = 0; s < nsplit; s++)
    M = fmaxf(M, Mpart[((long)bh*nsplit + s)*Nq + row]);
  float accO = 0.f, accL = 0.f;
  for (int s = 0; s < nsplit; s++){
    long p = (long)bh*nsplit + s;
    float wv = __expf(Mpart[p*Nq + row] - M);
    accL += wv*Lpart[p*Nq + row];
    accO += wv*Opart[(p*Nq + row)*DHH + d];
  }
  int b = bh / HH, h = bh % HH;
  O[(long)b*sOb + (long)row*DD + h*DHH + d] = f2bf(accO/accL);
}

// ---------------- host ----------------
extern "C" void kernel_launch(void* const* d_in, const int* in_sizes, int n_in,
                              void* d_out, int out_size, void* d_ws, size_t ws_size,
                              hipStream_t stream) {
  (void)in_sizes; (void)n_in; (void)out_size; (void)ws_size;
  const float* x        = (const float*)d_in[0];
  const int*   mask     = (const int*)d_in[1];
  const float* pos_emb  = (const float*)d_in[2];
  const float* sim_p_w  = (const float*)d_in[3];
  const float* sim_p_b  = (const float*)d_in[4];
  const float* sim_n_w  = (const float*)d_in[5];
  const float* sim_n_b  = (const float*)d_in[6];
  const float* adj_w    = (const float*)d_in[7];
  const float* gnn_p_w1 = (const float*)d_in[8];
  const float* gnn_p_w2 = (const float*)d_in[9];
  const float* gnn_n_w1 = (const float*)d_in[10];
  const float* gnn_n_w2 = (const float*)d_in[11];
  const float* ln1_g = (const float*)d_in[12]; const float* ln1_b = (const float*)d_in[13];
  const float* ln2_g = (const float*)d_in[14]; const float* ln2_b = (const float*)d_in[15];
  const float* ln3_g = (const float*)d_in[16]; const float* ln3_b = (const float*)d_in[17];
  const float* ln4_g = (const float*)d_in[18]; const float* ln4_b = (const float*)d_in[19];
  const float* ln5_g = (const float*)d_in[20]; const float* ln5_b = (const float*)d_in[21];
  const float* i2q_wq = (const float*)d_in[22];
  const float* i2q_wk = (const float*)d_in[23];
  const float* i2q_wv = (const float*)d_in[24];
  const float* i2q_wo = (const float*)d_in[25];
  const float* q2i_wq = (const float*)d_in[26];
  const float* q2i_wk = (const float*)d_in[27];
  const float* q2i_wv = (const float*)d_in[28];
  const float* q2i_wo = (const float*)d_in[29];
  const float* i2q_bo = (const float*)d_in[30];
  const float* q2i_bo = (const float*)d_in[31];
  const float* mlp_w  = (const float*)d_in[32];
  const float* mlp_b  = (const float*)d_in[33];
  const float* g_i2t  = (const float*)d_in[34];
  const float* g_t2i  = (const float*)d_in[35];

  float* out  = (float*)d_out;
  float* simP = out + (size_t)BB*NN*DD;
  float* simN = simP + (size_t)BB*NN;

  char* w8 = (char*)d_ws;
  size_t off = 0;
  auto take = [&](size_t bytes)->void*{
    void* p = (void*)(w8 + off);
    off += (bytes + 255) & ~(size_t)255;
    return p;
  };
  float* part   = (float*)take((size_t)BB*32*2*DD*4);
  float* pcnt   = (float*)take((size_t)BB*32*2*4);
  float* vvec   = (float*)take((size_t)BB*2*DD*4);
  float* cscal  = (float*)take((size_t)BB*2*4);
  int*   idxb   = (int*)take((size_t)BB*2*256*4);
  float* wb     = (float*)take((size_t)BB*2*256*4);
  float* node   = (float*)take((size_t)BB*384*DD*4);
  float* gA     = (float*)take((size_t)BB*384*DD*4);   // also t3
  float* gadjP  = (float*)take((size_t)BB*256*256*4);
  float* gadjN  = (float*)take((size_t)BB*128*128*4);
  float* query  = (float*)take((size_t)BB*384*DD*4);   // also t1
  float* query2 = (float*)take((size_t)BB*384*DD*4);   // also t2
  unsigned short* xhatq  = (unsigned short*)take((size_t)BB*384*DD*2);
  unsigned short* qh     = (unsigned short*)take((size_t)BB*384*DD*2);
  unsigned short* attnZ  = (unsigned short*)take((size_t)BB*384*DD*2);
  unsigned short* xhatq2 = (unsigned short*)take((size_t)BB*384*DD*2);
  unsigned short* kv2    = (unsigned short*)take((size_t)BB*384*512*2);
  unsigned short* xhat   = (unsigned short*)take((size_t)BB*NN*DD*2);
  unsigned short* kvq    = (unsigned short*)take((size_t)BB*NN*768*2);
  float* featb2 = (float*)take((size_t)BB*NN*DD*4);
  float* Mpart  = (float*)take((size_t)BB*HH*8*384*4);
  float* Lpart  = (float*)take((size_t)BB*HH*8*384*4);
  unsigned short* wTq1  = (unsigned short*)take((size_t)65536*2);
  unsigned short* wTbig = (unsigned short*)take((size_t)3*65536*2);
  unsigned short* wTkv2 = (unsigned short*)take((size_t)2*65536*2);
  unsigned short* wTmlp = (unsigned short*)take((size_t)65536*2);
  unsigned short* wTo1  = (unsigned short*)take((size_t)65536*2);
  unsigned short* wTo2  = (unsigned short*)take((size_t)65536*2);
  float* biasQ1  = (float*)take(256*4);
  float* biasBig = (float*)take(768*4);
  float* biasKV2 = (float*)take(512*4);
  float* biasMlp = (float*)take(256*4);
  // overlays (disjoint lifetimes):
  float* t1 = query;
  float* t2 = query2;
  float* t3 = gA;
  unsigned short* attn2 = xhat;
  unsigned short* xhat5 = kvq;
  float* Opart = featb2;

  const long sQ  = 384L*DD;
  const long sX  = (long)NN*DD;
  const float* NF = nullptr;

  // ---- weight folds ----
  FoldArgs fa;
  fa.W[0]=i2q_wq; fa.g[0]=ln1_g; fa.BT[0]=wTq1;
  fa.W[1]=i2q_wk; fa.g[1]=ln2_g; fa.BT[1]=wTbig;
  fa.W[2]=i2q_wv; fa.g[2]=ln2_g; fa.BT[2]=wTbig + 256*256;
  fa.W[3]=q2i_wq; fa.g[3]=ln3_g; fa.BT[3]=wTbig + 512*256;
  fa.W[4]=q2i_wk; fa.g[4]=ln4_g; fa.BT[4]=wTkv2;
  fa.W[5]=q2i_wv; fa.g[5]=ln4_g; fa.BT[5]=wTkv2 + 256*256;
  fa.W[6]=mlp_w;  fa.g[6]=ln5_g; fa.BT[6]=wTmlp;
  fa.W[7]=i2q_wo; fa.g[7]=nullptr; fa.BT[7]=wTo1;
  fa.W[8]=q2i_wo; fa.g[8]=nullptr; fa.BT[8]=wTo2;
  fold_w<<<dim3(16,9), 256, 0, stream>>>(fa);
  BiasArgs ba;
  ba.W[0]=i2q_wq; ba.b[0]=ln1_b; ba.addb[0]=nullptr; ba.out[0]=biasQ1;
  ba.W[1]=i2q_wk; ba.b[1]=ln2_b; ba.addb[1]=nullptr; ba.out[1]=biasBig;
  ba.W[2]=i2q_wv; ba.b[2]=ln2_b; ba.addb[2]=nullptr; ba.out[2]=biasBig+256;
  ba.W[3]=q2i_wq; ba.b[3]=ln3_b; ba.addb[3]=nullptr; ba.out[3]=biasBig+512;
  ba.W[4]=q2i_wk; ba.b[4]=ln4_b; ba.addb[4]=nullptr; ba.out[4]=biasKV2;
  ba.W[5]=q2i_wv; ba.b[5]=ln4_b; ba.addb[5]=nullptr; ba.out[5]=biasKV2+256;
  ba.W[6]=mlp_w;  ba.b[6]=ln5_b; ba.addb[6]=mlp_b;   ba.out[6]=biasMlp;
  fold_b<<<7, 256, 0, stream>>>(ba);

  // ---- stats / sims / topk+gather ----
  stats_part<<<dim3(32, BB), 256, 0, stream>>>(x, mask, part, pcnt);
  stats_vec<<<BB, 256, 0, stream>>>(part, pcnt, sim_p_w, sim_p_b, sim_n_w, sim_n_b, vvec, cscal);
  sim_norm_kernel<<<dim3(NN/4, BB), 256, 0, stream>>>(x, vvec, cscal, simP, simN, xhat);
  topk_radix<<<2*BB, 256, 0, stream>>>(simP, simN, x, idxb, wb, node);

  // ---- GCN (pos/neg paired) ----
  GP z = {};
  {
    GP4 g;
    g.p[0] = { node, 384L*DD, 256, adj_w, 0, 256, gA, 384L*DD, 256, nullptr, nullptr, 384, 256, 256, 1.f, 0 };
    g.p[1] = { node, 384L*DD, 256, gnn_p_w1, 0, 256, t1, 384L*DD, 256, nullptr, nullptr, 256, 256, 256, 1.f, 0 };
    g.p[2] = { node + 256L*DD, 384L*DD, 256, gnn_n_w1, 0, 256, t1 + 256L*DD, 384L*DD, 256, nullptr, nullptr, 128, 256, 256, 1.f, 0 };
    g.p[3] = z;
    gemm_multi<<<dim3(4,6,3*BB), 256, 0, stream>>>(g);
  }
  {
    GP4 g;
    g.p[0] = { gA, 384L*DD, 256, node, 384L*DD, 256, gadjP, 65536L, 256, nullptr, nullptr, 256, 256, 256, 0.0625f, FLAG_TRANSB };
    g.p[1] = { gA + 256L*DD, 384L*DD, 256, node + 256L*DD, 384L*DD, 256, gadjN, 16384L, 128, nullptr, nullptr, 128, 128, 256, 0.0625f, FLAG_TRANSB };
    g.p[2] = z; g.p[3] = z;
    gemm_multi<<<dim3(4,4,2*BB), 256, 0, stream>>>(g);
  }
  softmax_dual<<<768, 256, 0, stream>>>(gadjP, 256, 256, 65536L, BB*256,
                                        gadjN, 128, 128, 16384L, BB*128);
  {
    GP4 g;
    g.p[0] = { gadjP, 65536L, 256, t1, 384L*DD, 256, t2, 384L*DD, 256, nullptr, nullptr, 256, 256, 256, 1.f, FLAG_RELU };
    g.p[1] = { gadjN, 16384L, 128, t1 + 256L*DD, 384L*DD, 256, t2 + 256L*DD, 384L*DD, 256, nullptr, nullptr, 128, 256, 128, 1.f, FLAG_RELU };
    g.p[2] = z; g.p[3] = z;
    gemm_multi<<<dim3(4,4,2*BB), 256, 0, stream>>>(g);
  }
  {
    GP4 g;
    g.p[0] = { t2, 384L*DD, 256, gnn_p_w2, 0, 256, t3, 384L*DD, 256, nullptr, nullptr, 256, 256, 256, 1.f, 0 };
    g.p[1] = { t2 + 256L*DD, 384L*DD, 256, gnn_n_w2, 0, 256, t3 + 256L*DD, 384L*DD, 256, nullptr, nullptr, 128, 256, 256, 1.f, 0 };
    g.p[2] = z; g.p[3] = z;
    gemm_multi<<<dim3(4,4,2*BB), 256, 0, stream>>>(g);
  }
  {
    GP4 g;
    g.p[0] = { gadjP, 65536L, 256, t3, 384L*DD, 256, query, 384L*DD, 256, idxb, pos_emb, 256, 256, 256, 1.f, 0 };
    g.p[1] = { gadjN, 16384L, 128, t3 + 256L*DD, 384L*DD, 256, query + 256L*DD, 384L*DD, 256, idxb + 256, pos_emb, 128, 256, 128, 1.f, 0 };
    g.p[2] = z; g.p[3] = z;
    gemm_multi<<<dim3(4,4,2*BB), 256, 0, stream>>>(g);
  }

  // ---- LN core of query ----
  rownorm_kernel<<<BB*384/4, 256, 0, stream>>>(query, xhatq, BB*384);

  // (a) qh = xhatq @ wq' + b'
  gemm128<unsigned short,false,false><<<dim3(2,3,BB),256,0,stream>>>(
      xhatq, sQ, wTq1, qh, sQ, 256, NF, 0, biasQ1, NF);
  // (b) [kh|vh|qh2] = xhat @ [wk'|wv'|wq2'] + b'
  gemm128<unsigned short,false,false><<<dim3(6,32,BB),256,0,stream>>>(
      xhat, sX, wTbig, kvq, (long)NN*768, 768, NF, 0, biasBig, NF);
  // i2q flash (NFRAG=3, K-split 8) + combine
  flash_kernel<3><<<dim3(2*8, HH, BB), 256, 0, stream>>>(
      qh, sQ, 256, kvq, kvq + 256, (long)NN*768, 768,
      attnZ, sQ, Opart, Mpart, Lpart, 384, NN, 8, 0.125f);
  flash_combine<<<BB*HH*384/4, 256, 0, stream>>>(Opart, Mpart, Lpart, attnZ, sQ, 384, 8);
  // (c) query2 = query + g_i2t .* (attnZ @ wo + bo)
  gemm128<float,true,true><<<dim3(2,3,BB),256,0,stream>>>(
      attnZ, sQ, wTo1, query2, sQ, 256, query, sQ, i2q_bo, g_i2t);

  // ---- q2i ----
  rownorm_kernel<<<BB*384/4, 256, 0, stream>>>(query2, xhatq2, BB*384);
  // (d) [k2|v2] = xhatq2 @ [wk2'|wv2'] + b'
  gemm128<unsigned short,false,false><<<dim3(4,3,BB),256,0,stream>>>(
      xhatq2, sQ, wTkv2, kv2, 384L*512, 512, NF, 0, biasKV2, NF);
  flash_kernel<2><<<dim3(32, HH, BB), 256, 0, stream>>>(
      kvq + 512, (long)NN*768, 768, kv2, kv2 + 256, 384L*512, 512,
      attn2, sX, nullptr, nullptr, nullptr, NN, 384, 1, 0.125f);
  // (e) featb2 = x + g_t2i .* (attn2 @ wo + bo)
  gemm128<float,true,true><<<dim3(2,32,BB),256,0,stream>>>(
      attn2, sX, wTo2, featb2, sX, 256, x, sX, q2i_bo, g_t2i);

  // ---- final MLP ----
  rownorm_kernel<<<BB*NN/4, 256, 0, stream>>>(featb2, xhat5, BB*NN);
  gemm128<float,true,false><<<dim3(2,32,BB),256,0,stream>>>(
      xhat5, sX, wTmlp, out, sX, 256, featb2, sX, biasMlp, NF);
}

// Round 6
// 519.335 us; speedup vs baseline: 1.8109x; 1.1328x over previous
//
#include <hip/hip_runtime.h>

#define BB 8
#define NN 4096
#define DD 256
#define HH 4
#define DHH 64
#define KPP 256
#define KNN 128

typedef float f32x4 __attribute__((ext_vector_type(4)));
typedef short bf16x8 __attribute__((ext_vector_type(8)));
typedef short bf16x4 __attribute__((ext_vector_type(4)));

#define FLAG_TRANSB 1
#define FLAG_RELU   2

__device__ __forceinline__ float bf2f(unsigned short u){
  union { unsigned int i; float f; } v; v.i = ((unsigned int)u) << 16; return v.f;
}
__device__ __forceinline__ unsigned short f2bf(float f){
  union { float f; unsigned int i; } v; v.f = f;
  return (unsigned short)((v.i + 0x7FFFu + ((v.i >> 16) & 1u)) >> 16);
}
__device__ __forceinline__ void gload16(const void* g, void* l){
  __builtin_amdgcn_global_load_lds((const __attribute__((address_space(1))) void*)g,
                                   (__attribute__((address_space(3))) void*)l, 16, 0, 0);
}

// ---------------- masked-mean stats ----------------
__global__ void stats_part(const float* __restrict__ x, const int* __restrict__ mask,
                           float* __restrict__ part, float* __restrict__ pcnt){
  int b = blockIdx.y, c = blockIdx.x, d = threadIdx.x;
  int n0 = c * 128;
  float sp = 0.f, sn = 0.f; int cp = 0, cn = 0;
  const float* xb = x + ((long)b*NN + n0)*DD + d;
  const int* mb = mask + (long)b*NN + n0;
  for (int r = 0; r < 128; r++){
    int mv = mb[r];
    float v = xb[(long)r*DD];
    if (mv == 1){ sp += v; cp++; }
    else if (mv == -1){ sn += v; cn++; }
  }
  part[(((long)(b*32+c)*2+0)*DD)+d] = sp;
  part[(((long)(b*32+c)*2+1)*DD)+d] = sn;
  if (d == 0){ pcnt[(b*32+c)*2+0] = (float)cp; pcnt[(b*32+c)*2+1] = (float)cn; }
}

// ---------------- merged stats_final + sim_vec ----------------
__global__ void stats_vec(const float* __restrict__ part, const float* __restrict__ pcnt,
                          const float* __restrict__ Wp, const float* __restrict__ bp,
                          const float* __restrict__ Wn, const float* __restrict__ bn,
                          float* __restrict__ vvec, float* __restrict__ cscal){
  int b = blockIdx.x, k = threadIdx.x;
  __shared__ float qp[256], qn[256], red[256];
  {
    float sp=0.f, sn=0.f, cp=0.f, cn=0.f;
    for (int c = 0; c < 32; c++){
      sp += part[(((long)(b*32+c)*2+0)*DD)+k];
      sn += part[(((long)(b*32+c)*2+1)*DD)+k];
      cp += pcnt[(b*32+c)*2+0];
      cn += pcnt[(b*32+c)*2+1];
    }
    qp[k] = sp / (cp + 1e-6f);
    qn[k] = sn / (cn + 1e-6f);
  }
  __syncthreads();
  float vp = 0.f, vn = 0.f;
  for (int j = 0; j < DD; j++){ vp += Wp[(long)k*DD+j]*qp[j]; vn += Wn[(long)k*DD+j]*qn[j]; }
  vvec[(long)(b*2+0)*DD+k] = vp; vvec[(long)(b*2+1)*DD+k] = vn;
  red[k] = bp[k]*qp[k];
  __syncthreads();
  for (int s = 128; s > 0; s >>= 1){ if (k < s) red[k] += red[k+s]; __syncthreads(); }
  if (k == 0) cscal[b*2+0] = red[0];
  __syncthreads();
  red[k] = bn[k]*qn[k];
  __syncthreads();
  for (int s = 128; s > 0; s >>= 1){ if (k < s) red[k] += red[k+s]; __syncthreads(); }
  if (k == 0) cscal[b*2+1] = red[0];
}

// ---------------- fused sims + LN-core of x ----------------
__global__ void sim_norm_kernel(const float* __restrict__ x, const float* __restrict__ vvec,
                                const float* __restrict__ cscal,
                                float* __restrict__ simP, float* __restrict__ simN,
                                unsigned short* __restrict__ xhat){
  int b = blockIdx.y;
  int w = threadIdx.x >> 6, lane = threadIdx.x & 63;
  int n = blockIdx.x*4 + w;
  long row = (long)b*NN + n;
  const float4* xr = (const float4*)(x + row*DD);
  float4 xv = xr[lane];
  float4 a = ((const float4*)(vvec + (long)(b*2+0)*DD))[lane];
  float4 c = ((const float4*)(vvec + (long)(b*2+1)*DD))[lane];
  float sp = xv.x*a.x + xv.y*a.y + xv.z*a.z + xv.w*a.w;
  float sn = xv.x*c.x + xv.y*c.y + xv.z*c.z + xv.w*c.w;
  float s  = xv.x+xv.y+xv.z+xv.w;
  float q  = xv.x*xv.x+xv.y*xv.y+xv.z*xv.z+xv.w*xv.w;
  for (int off = 32; off; off >>= 1){
    sp += __shfl_xor(sp, off); sn += __shfl_xor(sn, off);
    s  += __shfl_xor(s, off);  q  += __shfl_xor(q, off);
  }
  float m = s*(1.f/256.f);
  float var = q*(1.f/256.f) - m*m;
  float rinv = rsqrtf(var + 1e-5f);
  ushort4 o;
  o.x = f2bf((xv.x-m)*rinv); o.y = f2bf((xv.y-m)*rinv);
  o.z = f2bf((xv.z-m)*rinv); o.w = f2bf((xv.w-m)*rinv);
  ((ushort4*)(xhat + row*DD))[lane] = o;
  if (lane == 0){
    float zp = sp + cscal[b*2+0], zn = sn + cscal[b*2+1];
    simP[row] = 1.f/(1.f+expf(-zp));
    simN[row] = 1.f/(1.f+expf(-zn));
  }
}

// ---------------- top-k (3-pass radix, parallel scans) + fused node gather ----------------
__global__ __launch_bounds__(256) void topk_radix(const float* __restrict__ simP,
                                                  const float* __restrict__ simN,
                                                  const float* __restrict__ x,
                                                  int* __restrict__ idxb, float* __restrict__ wb,
                                                  float* __restrict__ node){
  __shared__ unsigned int vals[4096];
  __shared__ unsigned int hist[4096];
  __shared__ unsigned short eql[4096];
  __shared__ unsigned int tsum[256];
  __shared__ unsigned int sB, sRem, sCG, sCnt, sEq;
  int id = blockIdx.x; int sgn = id & 1, b = id >> 1;
  int K = (sgn == 0) ? KPP : KNN;
  const float* s = (sgn == 0 ? simP : simN) + (long)b*NN;
  int t = threadIdx.x;
  if (t == 0){ sCG = 0; sCnt = 0; sEq = 0; }
  for (int i = t; i < 4096; i += 256){ vals[i] = __float_as_uint(s[i]); hist[i] = 0; }
  __syncthreads();

  auto find_thresh = [&](int NB, unsigned need){
    int per = NB >> 8;
    int base = t*per;
    unsigned local = 0;
    for (int j = 0; j < per; j++) local += hist[base+j];
    tsum[t] = local;
    __syncthreads();
    #pragma unroll
    for (int st = 1; st < 256; st <<= 1){
      unsigned v = (t + st < 256) ? tsum[t+st] : 0u;
      __syncthreads();
      tsum[t] += v;
      __syncthreads();
    }
    unsigned after = (t < 255) ? tsum[t+1] : 0u;
    if (after < need && after + local >= need){
      unsigned c = after;
      for (int j = per-1; j >= 0; j--){
        unsigned h = hist[base+j];
        c += h;
        if (c >= need){
          sB = (unsigned)(base+j);
          sRem = need - (c - h);
          atomicAdd(&sCG, c - h);
          break;
        }
      }
    }
    __syncthreads();
  };

  for (int i = t; i < 4096; i += 256) atomicAdd(&hist[vals[i] >> 20], 1u);
  __syncthreads();
  find_thresh(4096, (unsigned)K);
  unsigned B1 = sB, rem1 = sRem;
  __syncthreads();
  for (int i = t; i < 4096; i += 256) hist[i] = 0;
  __syncthreads();
  for (int i = t; i < 4096; i += 256){
    unsigned v = vals[i];
    if ((v >> 20) == B1) atomicAdd(&hist[(v >> 8) & 0xFFFu], 1u);
  }
  __syncthreads();
  find_thresh(4096, rem1);
  unsigned B2 = sB, rem2 = sRem;
  unsigned pre = (B1 << 12) | B2;
  __syncthreads();
  hist[t] = 0;
  __syncthreads();
  for (int i = t; i < 4096; i += 256){
    unsigned v = vals[i];
    if ((v >> 8) == pre) atomicAdd(&hist[v & 0xFFu], 1u);
  }
  __syncthreads();
  find_thresh(256, rem2);
  unsigned T = (pre << 8) | sB;
  unsigned cg = sCG;
  __syncthreads();
  hist[t] = 0;
  __syncthreads();

  int* oi = idxb + (long)id*256;
  float* ow = wb + (long)id*256;
  for (int i = t; i < 4096; i += 256){
    unsigned v = vals[i];
    if (v > T){
      unsigned p = atomicAdd(&sCnt, 1u);
      oi[p] = i; ow[p] = __uint_as_float(v);
      hist[p] = (unsigned)i; hist[256+p] = v;
    }
    else if (v == T){ unsigned e = atomicAdd(&sEq, 1u); eql[e] = (unsigned short)i; }
  }
  __syncthreads();
  int ne = K - (int)cg;
  int eqn = (int)sEq;
  for (int e = t; e < eqn; e += 256){
    int myi = eql[e]; int r = 0;
    for (int e2 = 0; e2 < eqn; e2++) r += (eql[e2] < myi);
    if (r < ne){
      oi[cg + r] = myi; ow[cg + r] = __uint_as_float(T);
      hist[cg + r] = (unsigned)myi; hist[256 + cg + r] = T;
    }
  }
  __syncthreads();
  int rbase = (sgn == 0) ? 0 : KPP;
  int lane = t & 63, rw = t >> 6;
  for (int i0 = 0; i0 < K; i0 += 4){
    int r = i0 + rw;
    int idx = (int)hist[r];
    float wv = __uint_as_float(hist[256 + r]);
    float4 vsel;
    if (wv > 0.6f) vsel = ((const float4*)(x + ((long)b*NN + idx)*DD))[lane];
    else vsel = (float4){0.f,0.f,0.f,0.f};
    ((float4*)(node + ((long)b*384 + rbase + r)*DD))[lane] = vsel;
  }
}

// ---------------- dual row softmax ----------------
__global__ void softmax_dual(float* __restrict__ A0, int L0, int rpb0, long bs0, int rows0,
                             float* __restrict__ A1, int L1, int rpb1, long bs1, int rows1){
  int w = threadIdx.x >> 6, lane = threadIdx.x & 63;
  long row = (long)blockIdx.x*4 + w;
  float* A; int L, rpb; long bs;
  if (row < rows0){ A = A0; L = L0; rpb = rpb0; bs = bs0; }
  else { row -= rows0; if (row >= rows1) return; A = A1; L = L1; rpb = rpb1; bs = bs1; }
  int b = (int)(row / rpb), r = (int)(row % rpb);
  float* a = A + (long)b*bs + (long)r*L;
  int e = L >> 6;
  float vals[4]; float mx = -1e30f;
  for (int j = 0; j < e; j++){ vals[j] = a[lane*e+j]; mx = fmaxf(mx, vals[j]); }
  for (int off = 32; off; off >>= 1) mx = fmaxf(mx, __shfl_xor(mx, off));
  float sum = 0.f;
  for (int j = 0; j < e; j++){ vals[j] = expf(vals[j]-mx); sum += vals[j]; }
  for (int off = 32; off; off >>= 1) sum += __shfl_xor(sum, off);
  float rinv = 1.f/sum;
  for (int j = 0; j < e; j++) a[lane*e+j] = vals[j]*rinv;
}

// ---------------- row LayerNorm core ----------------
__global__ void rownorm_kernel(const float* __restrict__ X, unsigned short* __restrict__ Y, int rows){
  int w = threadIdx.x >> 6, lane = threadIdx.x & 63;
  long row = (long)blockIdx.x*4 + w;
  if (row >= rows) return;
  const float4* xr = (const float4*)(X + row*DD);
  float4 xv = xr[lane];
  float s = xv.x+xv.y+xv.z+xv.w;
  float q = xv.x*xv.x+xv.y*xv.y+xv.z*xv.z+xv.w*xv.w;
  for (int off = 32; off; off >>= 1){ s += __shfl_xor(s, off); q += __shfl_xor(q, off); }
  float m = s*(1.f/256.f);
  float var = q*(1.f/256.f) - m*m;
  float rinv = rsqrtf(var + 1e-5f);
  ushort4 o;
  o.x = f2bf((xv.x-m)*rinv); o.y = f2bf((xv.y-m)*rinv);
  o.z = f2bf((xv.z-m)*rinv); o.w = f2bf((xv.w-m)*rinv);
  ((ushort4*)(Y + row*DD))[lane] = o;
}

// ---------------- weight fold ----------------
struct FoldArgs { const float* W[9]; const float* g[9]; unsigned short* BT[9]; };
struct BiasArgs { const float* W[7]; const float* b[7]; const float* addb[7]; float* out[7]; };

__global__ void fold_w(FoldArgs fa){
  int m = blockIdx.y, tile = blockIdx.x, t = threadIdx.x;
  const float* W = fa.W[m]; const float* g = fa.g[m]; unsigned short* BT = fa.BT[m];
  __shared__ float T[64][65];
  int tn = (tile & 3)*64, tk = (tile >> 2)*64;
  #pragma unroll 4
  for (int p = 0; p < 16; p++){
    int kl = p*4 + (t >> 6), nl = t & 63;
    float v = W[(long)(tk+kl)*256 + tn + nl];
    if (g) v *= g[tk+kl];
    T[kl][nl] = v;
  }
  __syncthreads();
  #pragma unroll 4
  for (int p = 0; p < 16; p++){
    int nl = p*4 + (t >> 6), kl = t & 63;
    BT[(long)(tn+nl)*256 + tk + kl] = f2bf(T[kl][nl]);
  }
}

__global__ void fold_b(BiasArgs ba){
  int m = blockIdx.x, n = threadIdx.x;
  const float* W = ba.W[m]; const float* b = ba.b[m];
  float s = (ba.addb[m] != nullptr) ? ba.addb[m][n] : 0.f;
  for (int k = 0; k < 256; k++) s += b[k]*W[(long)k*256+n];
  ba.out[m][n] = s;
}

// ---------------- multi-parameter f32 GEMM 64x64 (GCN path) ----------------
struct GP {
  const float* A; long sAb; int lda;
  const float* B; long sBb; int ldb;
  float* C; long sCb; int ldc;
  const int* pidx; const float* pe;
  int M, N, K; float alpha; int flags;
};
struct GP4 { GP p[4]; };

__global__ __launch_bounds__(256) void gemm_multi(GP4 g4){
  GP p = g4.p[blockIdx.z >> 3];
  int b = blockIdx.z & 7;
  int m0 = blockIdx.y*64, n0 = blockIdx.x*64;
  if (m0 >= p.M || n0 >= p.N) return;
  __shared__ __align__(16) unsigned short As[64*40];
  __shared__ __align__(16) unsigned short Bs[64*40];
  const float* Ab = p.A + (long)b*p.sAb;
  const float* Bb = p.B + (long)b*p.sBb;
  int t = threadIdx.x;
  int w = t >> 6, lane = t & 63, lrowi = lane & 15, lquad = lane >> 4;
  int wm = w >> 1, wn = w & 1;
  f32x4 acc[2][2];
  #pragma unroll
  for (int i = 0; i < 2; i++)
    #pragma unroll
    for (int j = 0; j < 2; j++) acc[i][j] = (f32x4){0.f,0.f,0.f,0.f};
  int am = t >> 2, akq = t & 3;
  for (int k0 = 0; k0 < p.K; k0 += 32){
    {
      const float4* s4 = (const float4*)(Ab + (long)(m0+am)*p.lda + k0 + akq*8);
      float4 u = s4[0], vv = s4[1];
      unsigned short tmp[8];
      tmp[0]=f2bf(u.x); tmp[1]=f2bf(u.y); tmp[2]=f2bf(u.z); tmp[3]=f2bf(u.w);
      tmp[4]=f2bf(vv.x); tmp[5]=f2bf(vv.y); tmp[6]=f2bf(vv.z); tmp[7]=f2bf(vv.w);
      *(uint4*)(&As[am*40 + akq*8]) = *(uint4*)tmp;
    }
    if (p.flags & FLAG_TRANSB){
      const float4* s4 = (const float4*)(Bb + (long)(n0+am)*p.ldb + k0 + akq*8);
      float4 u = s4[0], vv = s4[1];
      unsigned short tmp[8];
      tmp[0]=f2bf(u.x); tmp[1]=f2bf(u.y); tmp[2]=f2bf(u.z); tmp[3]=f2bf(u.w);
      tmp[4]=f2bf(vv.x); tmp[5]=f2bf(vv.y); tmp[6]=f2bf(vv.z); tmp[7]=f2bf(vv.w);
      *(uint4*)(&Bs[am*40 + akq*8]) = *(uint4*)tmp;
    } else {
      int bn = t & 63, bkb = (t >> 6)*8;
      #pragma unroll
      for (int j = 0; j < 8; j++)
        Bs[bn*40 + bkb + j] = f2bf(Bb[(long)(k0+bkb+j)*p.ldb + n0 + bn]);
    }
    __syncthreads();
    bf16x8 af[2], bfr[2];
    #pragma unroll
    for (int i = 0; i < 2; i++)
      af[i] = *(const bf16x8*)(&As[(wm*32 + i*16 + lrowi)*40 + lquad*8]);
    #pragma unroll
    for (int j = 0; j < 2; j++)
      bfr[j] = *(const bf16x8*)(&Bs[(wn*32 + j*16 + lrowi)*40 + lquad*8]);
    #pragma unroll
    for (int i = 0; i < 2; i++)
      #pragma unroll
      for (int j = 0; j < 2; j++)
        acc[i][j] = __builtin_amdgcn_mfma_f32_16x16x32_bf16(af[i], bfr[j], acc[i][j], 0, 0, 0);
    __syncthreads();
  }
  float* Cb = p.C + (long)b*p.sCb;
  #pragma unroll
  for (int i = 0; i < 2; i++)
    #pragma unroll
    for (int j = 0; j < 2; j++){
      int col = n0 + wn*32 + j*16 + lrowi;
      #pragma unroll
      for (int r = 0; r < 4; r++){
        int row = m0 + wm*32 + i*16 + lquad*4 + r;
        float v = p.alpha*acc[i][j][r];
        if (p.flags & FLAG_RELU) v = fmaxf(v, 0.f);
        if (p.pidx != nullptr){
          int idx = p.pidx[b*512 + row];
          v += p.pe[(long)idx*256 + col];
        }
        Cb[(long)row*p.ldc + col] = v;
      }
    }
}

// ---------------- fast 128x128 bf16 GEMM (K=256) ----------------
template<typename OT, bool RES, bool GATE>
__global__ __launch_bounds__(256) void gemm128(
    const unsigned short* __restrict__ A, long sAb,
    const unsigned short* __restrict__ BT,
    OT* __restrict__ C, long sCb, int ldc,
    const float* __restrict__ R, long sRb,
    const float* __restrict__ bias, const float* __restrict__ gate)
{
  __shared__ __align__(16) unsigned short As[4096];
  __shared__ __align__(16) unsigned short Bs[4096];
  int t = threadIdx.x;
  int w = t >> 6, lane = t & 63, lrowi = lane & 15, lquad = lane >> 4;
  int wm = w >> 1, wn = w & 1;
  int m0 = blockIdx.y*128, n0 = blockIdx.x*128;
  const unsigned short* Ab = A + (long)blockIdx.z*sAb + (long)m0*256;
  const unsigned short* Bb = BT + (long)n0*256;
  int g0 = t, g1 = 256 + t;
  int row0 = g0 >> 2, kq0 = g0 & 3;
  int row1 = g1 >> 2, kq1 = g1 & 3;
  f32x4 acc[4][4];
  #pragma unroll
  for (int i = 0; i < 4; i++)
    #pragma unroll
    for (int j = 0; j < 4; j++) acc[i][j] = (f32x4){0.f,0.f,0.f,0.f};

  for (int k0 = 0; k0 < 256; k0 += 32){
    gload16(Ab + (long)row0*256 + k0 + kq0*8, &As[g0*8]);
    gload16(Ab + (long)row1*256 + k0 + kq1*8, &As[g1*8]);
    gload16(Bb + (long)row0*256 + k0 + kq0*8, &Bs[g0*8]);
    gload16(Bb + (long)row1*256 + k0 + kq1*8, &Bs[g1*8]);
    __syncthreads();
    bf16x8 af[4], bfr[4];
    #pragma unroll
    for (int i = 0; i < 4; i++)
      af[i] = *(const bf16x8*)(&As[((wm*64 + i*16 + lrowi)*4 + lquad)*8]);
    #pragma unroll
    for (int j = 0; j < 4; j++)
      bfr[j] = *(const bf16x8*)(&Bs[((wn*64 + j*16 + lrowi)*4 + lquad)*8]);
    #pragma unroll
    for (int i = 0; i < 4; i++)
      #pragma unroll
      for (int j = 0; j < 4; j++)
        acc[i][j] = __builtin_amdgcn_mfma_f32_16x16x32_bf16(af[i], bfr[j], acc[i][j], 0, 0, 0);
    __syncthreads();
  }
  OT* Cb = C + (long)blockIdx.z*sCb;
  const float* Rb = RES ? (R + (long)blockIdx.z*sRb) : nullptr;
  #pragma unroll
  for (int j = 0; j < 4; j++){
    int col = n0 + wn*64 + j*16 + lrowi;
    float bv = bias[col];
    float gv = GATE ? gate[col] : 1.f;
    #pragma unroll
    for (int i = 0; i < 4; i++){
      #pragma unroll
      for (int r = 0; r < 4; r++){
        int row = m0 + wm*64 + i*16 + lquad*4 + r;
        float v = acc[i][j][r] + bv;
        if (GATE) v *= gv;
        if (RES) v += Rb[(long)row*256 + col];
        if constexpr (sizeof(OT) == 4) Cb[(long)row*ldc + col] = v;
        else                           Cb[(long)row*ldc + col] = f2bf(v);
      }
    }
  }
}

// ---------------- flash cross-attention, no-max softmax (exp-safe: |S|<~6 << 88) ----------------
template<int NFRAG>
__global__ __launch_bounds__(256) void flash_kernel(
    const unsigned short* __restrict__ Q, long sQb, int ldq,
    const unsigned short* __restrict__ Kt, const unsigned short* __restrict__ Vt,
    long sKb, int ldkv,
    unsigned short* __restrict__ O, long sOb,
    float* __restrict__ Opart, float* __restrict__ Lpart,
    int Nq, int Nk, int nsplit, float scale)
{
  __shared__ __align__(16) unsigned short Kl[32*72];
  __shared__ __align__(16) unsigned short Vl[64*36];
  __shared__ __align__(16) unsigned short Pl[4*NFRAG*16*36];
  int b = blockIdx.z, h = blockIdx.y;
  int nqg = Nq / (64*NFRAG);
  int qg = blockIdx.x % nqg, split = blockIdx.x / nqg;
  int kchunk = Nk / nsplit;
  int kbeg = split*kchunk, kend = kbeg + kchunk;
  int t = threadIdx.x, w = t >> 6, lane = t & 63, lrowi = lane & 15, lquad = lane >> 4;
  int q0 = qg*(64*NFRAG) + w*(16*NFRAG);
  const unsigned short* Qb = Q + (long)b*sQb + h*DHH;
  const unsigned short* Kb = Kt + (long)b*sKb + h*DHH;
  const unsigned short* Vb = Vt + (long)b*sKb + h*DHH;
  bf16x8 qa[NFRAG][2];
  #pragma unroll
  for (int f = 0; f < NFRAG; f++)
    #pragma unroll
    for (int kt = 0; kt < 2; kt++)
      qa[f][kt] = *(const bf16x8*)(Qb + (long)(q0 + f*16 + lrowi)*ldq + kt*32 + lquad*8);

  f32x4 o[NFRAG][4];
  float psum[NFRAG][4];
  #pragma unroll
  for (int f = 0; f < NFRAG; f++)
    #pragma unroll
    for (int cj = 0; cj < 4; cj++){
      o[f][cj] = (f32x4){0.f,0.f,0.f,0.f};
      psum[f][cj] = 0.f;
    }
  int skq = t >> 3, sdq = (t & 7)*8;     // K staging: coalesced global
  int vkq = t & 31, vdq = (t >> 5)*8;    // V staging: conflict-free LDS writes
  unsigned short* Pw = &Pl[w*(NFRAG*16*36)];
  const float ec = scale * 1.44269504089f;  // exp(S*scale) = exp2(S*ec)

  for (int kt0 = kbeg; kt0 < kend; kt0 += 32){
    {
      uint4 kv = *(const uint4*)(Kb + (long)(kt0+skq)*ldkv + sdq);
      *(uint4*)(&Kl[skq*72 + sdq]) = kv;
      uint4 vv = *(const uint4*)(Vb + (long)(kt0+vkq)*ldkv + vdq);
      const unsigned short* vp = (const unsigned short*)&vv;
      #pragma unroll
      for (int j = 0; j < 8; j++) Vl[(vdq+j)*36 + vkq] = vp[j];
    }
    __syncthreads();
    bf16x8 kb0 = *(const bf16x8*)(&Kl[(0*16+lrowi)*72 + lquad*8]);
    bf16x8 kb1 = *(const bf16x8*)(&Kl[(0*16+lrowi)*72 + 32 + lquad*8]);
    bf16x8 kb2 = *(const bf16x8*)(&Kl[(1*16+lrowi)*72 + lquad*8]);
    bf16x8 kb3 = *(const bf16x8*)(&Kl[(1*16+lrowi)*72 + 32 + lquad*8]);
    union { bf16x8 v8; bf16x4 v4[2]; } vbu[4];
    #pragma unroll
    for (int cj = 0; cj < 4; cj++){
      const unsigned short* vb = &Vl[(cj*16+lrowi)*36 + lquad*8];
      vbu[cj].v4[0] = *(const bf16x4*)vb;
      vbu[cj].v4[1] = *(const bf16x4*)(vb + 4);
    }
    #pragma unroll
    for (int f = 0; f < NFRAG; f++){
      f32x4 S0 = (f32x4){0.f,0.f,0.f,0.f}, S1 = (f32x4){0.f,0.f,0.f,0.f};
      S0 = __builtin_amdgcn_mfma_f32_16x16x32_bf16(qa[f][0], kb0, S0, 0, 0, 0);
      S0 = __builtin_amdgcn_mfma_f32_16x16x32_bf16(qa[f][1], kb1, S0, 0, 0, 0);
      S1 = __builtin_amdgcn_mfma_f32_16x16x32_bf16(qa[f][0], kb2, S1, 0, 0, 0);
      S1 = __builtin_amdgcn_mfma_f32_16x16x32_bf16(qa[f][1], kb3, S1, 0, 0, 0);
      unsigned short* Pf = Pw + f*(16*36);
      #pragma unroll
      for (int r = 0; r < 4; r++){
        float p0 = exp2f(S0[r]*ec);
        float p1 = exp2f(S1[r]*ec);
        psum[f][r] += p0 + p1;
        Pf[(lquad*4+r)*36 + lrowi]      = f2bf(p0);
        Pf[(lquad*4+r)*36 + 16 + lrowi] = f2bf(p1);
      }
    }
    __asm__ volatile("s_waitcnt lgkmcnt(0)" ::: "memory");
    #pragma unroll
    for (int f = 0; f < NFRAG; f++){
      const unsigned short* pp = &Pw[f*(16*36) + lrowi*36 + lquad*8];
      union { bf16x8 v8; bf16x4 v4[2]; } pa;
      pa.v4[0] = *(const bf16x4*)pp;
      pa.v4[1] = *(const bf16x4*)(pp + 4);
      #pragma unroll
      for (int cj = 0; cj < 4; cj++)
        o[f][cj] = __builtin_amdgcn_mfma_f32_16x16x32_bf16(pa.v8, vbu[cj].v8, o[f][cj], 0, 0, 0);
    }
    __syncthreads();
  }
  // one-time row-sum reduction across the 16 lanes holding each row
  float lsum[NFRAG][4];
  #pragma unroll
  for (int f = 0; f < NFRAG; f++)
    #pragma unroll
    for (int r = 0; r < 4; r++){
      float s = psum[f][r];
      #pragma unroll
      for (int off = 1; off < 16; off <<= 1) s += __shfl_xor(s, off);
      lsum[f][r] = s;
    }
  if (nsplit > 1){
    int p = (b*HH + h)*nsplit + split;
    float* Op = Opart + (long)p*Nq*DHH;
    #pragma unroll
    for (int f = 0; f < NFRAG; f++)
      #pragma unroll
      for (int r = 0; r < 4; r++){
        int row = q0 + f*16 + lquad*4 + r;
        #pragma unroll
        for (int cj = 0; cj < 4; cj++)
          Op[(long)row*DHH + cj*16 + lrowi] = o[f][cj][r];
        if (lrowi == 0) Lpart[(long)p*Nq + row] = lsum[f][r];
      }
  } else {
    unsigned short* Ob = O + (long)b*sOb + h*DHH;
    #pragma unroll
    for (int f = 0; f < NFRAG; f++)
      #pragma unroll
      for (int r = 0; r < 4; r++){
        float rl = 1.f/lsum[f][r];
        int row = q0 + f*16 + lquad*4 + r;
        #pragma unroll
        for (int cj = 0; cj < 4; cj++)
          Ob[(long)row*DD + cj*16 + lrowi] = f2bf(o[f][cj][r]*rl);
      }
  }
}

// ---------------- flash split combine (no max needed) ----------------
__global__ void flash_combine(const float* __restrict__ Opart, const float* __restrict__ Lpart,
                              unsigned short* __restrict__ O, long sOb, int Nq, int nsplit){
  int gr = blockIdx.x*4 + (threadIdx.x >> 6);
  int d = threadIdx.x & 63;
  int bh = gr / Nq, row = gr % Nq;
  float accO = 0.f, accL = 0.f;
  for (int s = 0; s < nsplit; s++){
    long p = (long)bh*nsplit + s;
    accL += Lpart[p*Nq + row];
    accO += Opart[(p*Nq + row)*DHH + d];
  }
  int b = bh / HH, h = bh % HH;
  O[(long)b*sOb + (long)row*DD + h*DHH + d] = f2bf(accO/accL);
}

// ---------------- host ----------------
extern "C" void kernel_launch(void* const* d_in, const int* in_sizes, int n_in,
                              void* d_out, int out_size, void* d_ws, size_t ws_size,
                              hipStream_t stream) {
  (void)in_sizes; (void)n_in; (void)out_size; (void)ws_size;
  const float* x        = (const float*)d_in[0];
  const int*   mask     = (const int*)d_in[1];
  const float* pos_emb  = (const float*)d_in[2];
  const float* sim_p_w  = (const float*)d_in[3];
  const float* sim_p_b  = (const float*)d_in[4];
  const float* sim_n_w  = (const float*)d_in[5];
  const float* sim_n_b  = (const float*)d_in[6];
  const float* adj_w    = (const float*)d_in[7];
  const float* gnn_p_w1 = (const float*)d_in[8];
  const float* gnn_p_w2 = (const float*)d_in[9];
  const float* gnn_n_w1 = (const float*)d_in[10];
  const float* gnn_n_w2 = (const float*)d_in[11];
  const float* ln1_g = (const float*)d_in[12]; const float* ln1_b = (const float*)d_in[13];
  const float* ln2_g = (const float*)d_in[14]; const float* ln2_b = (const float*)d_in[15];
  const float* ln3_g = (const float*)d_in[16]; const float* ln3_b = (const float*)d_in[17];
  const float* ln4_g = (const float*)d_in[18]; const float* ln4_b = (const float*)d_in[19];
  const float* ln5_g = (const float*)d_in[20]; const float* ln5_b = (const float*)d_in[21];
  const float* i2q_wq = (const float*)d_in[22];
  const float* i2q_wk = (const float*)d_in[23];
  const float* i2q_wv = (const float*)d_in[24];
  const float* i2q_wo = (const float*)d_in[25];
  const float* q2i_wq = (const float*)d_in[26];
  const float* q2i_wk = (const float*)d_in[27];
  const float* q2i_wv = (const float*)d_in[28];
  const float* q2i_wo = (const float*)d_in[29];
  const float* i2q_bo = (const float*)d_in[30];
  const float* q2i_bo = (const float*)d_in[31];
  const float* mlp_w  = (const float*)d_in[32];
  const float* mlp_b  = (const float*)d_in[33];
  const float* g_i2t  = (const float*)d_in[34];
  const float* g_t2i  = (const float*)d_in[35];

  float* out  = (float*)d_out;
  float* simP = out + (size_t)BB*NN*DD;
  float* simN = simP + (size_t)BB*NN;

  char* w8 = (char*)d_ws;
  size_t off = 0;
  auto take = [&](size_t bytes)->void*{
    void* p = (void*)(w8 + off);
    off += (bytes + 255) & ~(size_t)255;
    return p;
  };
  float* part   = (float*)take((size_t)BB*32*2*DD*4);
  float* pcnt   = (float*)take((size_t)BB*32*2*4);
  float* vvec   = (float*)take((size_t)BB*2*DD*4);
  float* cscal  = (float*)take((size_t)BB*2*4);
  int*   idxb   = (int*)take((size_t)BB*2*256*4);
  float* wb     = (float*)take((size_t)BB*2*256*4);
  float* node   = (float*)take((size_t)BB*384*DD*4);
  float* gA     = (float*)take((size_t)BB*384*DD*4);   // also t3
  float* gadjP  = (float*)take((size_t)BB*256*256*4);
  float* gadjN  = (float*)take((size_t)BB*128*128*4);
  float* query  = (float*)take((size_t)BB*384*DD*4);   // also t1
  float* query2 = (float*)take((size_t)BB*384*DD*4);   // also t2
  unsigned short* xhatq  = (unsigned short*)take((size_t)BB*384*DD*2);
  unsigned short* qh     = (unsigned short*)take((size_t)BB*384*DD*2);
  unsigned short* attnZ  = (unsigned short*)take((size_t)BB*384*DD*2);
  unsigned short* xhatq2 = (unsigned short*)take((size_t)BB*384*DD*2);
  unsigned short* kv2    = (unsigned short*)take((size_t)BB*384*512*2);
  unsigned short* xhat   = (unsigned short*)take((size_t)BB*NN*DD*2);
  unsigned short* kvq    = (unsigned short*)take((size_t)BB*NN*768*2);
  float* featb2 = (float*)take((size_t)BB*NN*DD*4);
  float* Lpart  = (float*)take((size_t)BB*HH*8*384*4);
  unsigned short* wTq1  = (unsigned short*)take((size_t)65536*2);
  unsigned short* wTbig = (unsigned short*)take((size_t)3*65536*2);
  unsigned short* wTkv2 = (unsigned short*)take((size_t)2*65536*2);
  unsigned short* wTmlp = (unsigned short*)take((size_t)65536*2);
  unsigned short* wTo1  = (unsigned short*)take((size_t)65536*2);
  unsigned short* wTo2  = (unsigned short*)take((size_t)65536*2);
  float* biasQ1  = (float*)take(256*4);
  float* biasBig = (float*)take(768*4);
  float* biasKV2 = (float*)take(512*4);
  float* biasMlp = (float*)take(256*4);
  // overlays (disjoint lifetimes):
  float* t1 = query;
  float* t2 = query2;
  float* t3 = gA;
  unsigned short* attn2 = xhat;
  unsigned short* xhat5 = kvq;
  float* Opart = featb2;

  const long sQ  = 384L*DD;
  const long sX  = (long)NN*DD;
  const float* NF = nullptr;

  // ---- weight folds ----
  FoldArgs fa;
  fa.W[0]=i2q_wq; fa.g[0]=ln1_g; fa.BT[0]=wTq1;
  fa.W[1]=i2q_wk; fa.g[1]=ln2_g; fa.BT[1]=wTbig;
  fa.W[2]=i2q_wv; fa.g[2]=ln2_g; fa.BT[2]=wTbig + 256*256;
  fa.W[3]=q2i_wq; fa.g[3]=ln3_g; fa.BT[3]=wTbig + 512*256;
  fa.W[4]=q2i_wk; fa.g[4]=ln4_g; fa.BT[4]=wTkv2;
  fa.W[5]=q2i_wv; fa.g[5]=ln4_g; fa.BT[5]=wTkv2 + 256*256;
  fa.W[6]=mlp_w;  fa.g[6]=ln5_g; fa.BT[6]=wTmlp;
  fa.W[7]=i2q_wo; fa.g[7]=nullptr; fa.BT[7]=wTo1;
  fa.W[8]=q2i_wo; fa.g[8]=nullptr; fa.BT[8]=wTo2;
  fold_w<<<dim3(16,9), 256, 0, stream>>>(fa);
  BiasArgs ba;
  ba.W[0]=i2q_wq; ba.b[0]=ln1_b; ba.addb[0]=nullptr; ba.out[0]=biasQ1;
  ba.W[1]=i2q_wk; ba.b[1]=ln2_b; ba.addb[1]=nullptr; ba.out[1]=biasBig;
  ba.W[2]=i2q_wv; ba.b[2]=ln2_b; ba.addb[2]=nullptr; ba.out[2]=biasBig+256;
  ba.W[3]=q2i_wq; ba.b[3]=ln3_b; ba.addb[3]=nullptr; ba.out[3]=biasBig+512;
  ba.W[4]=q2i_wk; ba.b[4]=ln4_b; ba.addb[4]=nullptr; ba.out[4]=biasKV2;
  ba.W[5]=q2i_wv; ba.b[5]=ln4_b; ba.addb[5]=nullptr; ba.out[5]=biasKV2+256;
  ba.W[6]=mlp_w;  ba.b[6]=ln5_b; ba.addb[6]=mlp_b;   ba.out[6]=biasMlp;
  fold_b<<<7, 256, 0, stream>>>(ba);

  // ---- stats / sims / topk+gather ----
  stats_part<<<dim3(32, BB), 256, 0, stream>>>(x, mask, part, pcnt);
  stats_vec<<<BB, 256, 0, stream>>>(part, pcnt, sim_p_w, sim_p_b, sim_n_w, sim_n_b, vvec, cscal);
  sim_norm_kernel<<<dim3(NN/4, BB), 256, 0, stream>>>(x, vvec, cscal, simP, simN, xhat);
  topk_radix<<<2*BB, 256, 0, stream>>>(simP, simN, x, idxb, wb, node);

  // ---- GCN (pos/neg paired) ----
  GP z = {};
  {
    GP4 g;
    g.p[0] = { node, 384L*DD, 256, adj_w, 0, 256, gA, 384L*DD, 256, nullptr, nullptr, 384, 256, 256, 1.f, 0 };
    g.p[1] = { node, 384L*DD, 256, gnn_p_w1, 0, 256, t1, 384L*DD, 256, nullptr, nullptr, 256, 256, 256, 1.f, 0 };
    g.p[2] = { node + 256L*DD, 384L*DD, 256, gnn_n_w1, 0, 256, t1 + 256L*DD, 384L*DD, 256, nullptr, nullptr, 128, 256, 256, 1.f, 0 };
    g.p[3] = z;
    gemm_multi<<<dim3(4,6,3*BB), 256, 0, stream>>>(g);
  }
  {
    GP4 g;
    g.p[0] = { gA, 384L*DD, 256, node, 384L*DD, 256, gadjP, 65536L, 256, nullptr, nullptr, 256, 256, 256, 0.0625f, FLAG_TRANSB };
    g.p[1] = { gA + 256L*DD, 384L*DD, 256, node + 256L*DD, 384L*DD, 256, gadjN, 16384L, 128, nullptr, nullptr, 128, 128, 256, 0.0625f, FLAG_TRANSB };
    g.p[2] = z; g.p[3] = z;
    gemm_multi<<<dim3(4,4,2*BB), 256, 0, stream>>>(g);
  }
  softmax_dual<<<768, 256, 0, stream>>>(gadjP, 256, 256, 65536L, BB*256,
                                        gadjN, 128, 128, 16384L, BB*128);
  {
    GP4 g;
    g.p[0] = { gadjP, 65536L, 256, t1, 384L*DD, 256, t2, 384L*DD, 256, nullptr, nullptr, 256, 256, 256, 1.f, FLAG_RELU };
    g.p[1] = { gadjN, 16384L, 128, t1 + 256L*DD, 384L*DD, 256, t2 + 256L*DD, 384L*DD, 256, nullptr, nullptr, 128, 256, 128, 1.f, FLAG_RELU };
    g.p[2] = z; g.p[3] = z;
    gemm_multi<<<dim3(4,4,2*BB), 256, 0, stream>>>(g);
  }
  {
    GP4 g;
    g.p[0] = { t2, 384L*DD, 256, gnn_p_w2, 0, 256, t3, 384L*DD, 256, nullptr, nullptr, 256, 256, 256, 1.f, 0 };
    g.p[1] = { t2 + 256L*DD, 384L*DD, 256, gnn_n_w2, 0, 256, t3 + 256L*DD, 384L*DD, 256, nullptr, nullptr, 128, 256, 256, 1.f, 0 };
    g.p[2] = z; g.p[3] = z;
    gemm_multi<<<dim3(4,4,2*BB), 256, 0, stream>>>(g);
  }
  {
    GP4 g;
    g.p[0] = { gadjP, 65536L, 256, t3, 384L*DD, 256, query, 384L*DD, 256, idxb, pos_emb, 256, 256, 256, 1.f, 0 };
    g.p[1] = { gadjN, 16384L, 128, t3 + 256L*DD, 384L*DD, 256, query + 256L*DD, 384L*DD, 256, idxb + 256, pos_emb, 128, 256, 128, 1.f, 0 };
    g.p[2] = z; g.p[3] = z;
    gemm_multi<<<dim3(4,4,2*BB), 256, 0, stream>>>(g);
  }

  // ---- LN core of query ----
  rownorm_kernel<<<BB*384/4, 256, 0, stream>>>(query, xhatq, BB*384);

  // (a) qh = xhatq @ wq' + b'
  gemm128<unsigned short,false,false><<<dim3(2,3,BB),256,0,stream>>>(
      xhatq, sQ, wTq1, qh, sQ, 256, NF, 0, biasQ1, NF);
  // (b) [kh|vh|qh2] = xhat @ [wk'|wv'|wq2'] + b'
  gemm128<unsigned short,false,false><<<dim3(6,32,BB),256,0,stream>>>(
      xhat, sX, wTbig, kvq, (long)NN*768, 768, NF, 0, biasBig, NF);
  // i2q flash (NFRAG=3, K-split 8) + combine
  flash_kernel<3><<<dim3(2*8, HH, BB), 256, 0, stream>>>(
      qh, sQ, 256, kvq, kvq + 256, (long)NN*768, 768,
      attnZ, sQ, Opart, Lpart, 384, NN, 8, 0.125f);
  flash_combine<<<BB*HH*384/4, 256, 0, stream>>>(Opart, Lpart, attnZ, sQ, 384, 8);
  // (c) query2 = query + g_i2t .* (attnZ @ wo + bo)
  gemm128<float,true,true><<<dim3(2,3,BB),256,0,stream>>>(
      attnZ, sQ, wTo1, query2, sQ, 256, query, sQ, i2q_bo, g_i2t);

  // ---- q2i ----
  rownorm_kernel<<<BB*384/4, 256, 0, stream>>>(query2, xhatq2, BB*384);
  // (d) [k2|v2] = xhatq2 @ [wk2'|wv2'] + b'
  gemm128<unsigned short,false,false><<<dim3(4,3,BB),256,0,stream>>>(
      xhatq2, sQ, wTkv2, kv2, 384L*512, 512, NF, 0, biasKV2, NF);
  flash_kernel<2><<<dim3(32, HH, BB), 256, 0, stream>>>(
      kvq + 512, (long)NN*768, 768, kv2, kv2 + 256, 384L*512, 512,
      attn2, sX, nullptr, nullptr, NN, 384, 1, 0.125f);
  // (e) featb2 = x + g_t2i .* (attn2 @ wo + bo)
  gemm128<float,true,true><<<dim3(2,32,BB),256,0,stream>>>(
      attn2, sX, wTo2, featb2, sX, 256, x, sX, q2i_bo, g_t2i);

  // ---- final MLP ----
  rownorm_kernel<<<BB*NN/4, 256, 0, stream>>>(featb2, xhat5, BB*NN);
  gemm128<float,true,false><<<dim3(2,32,BB),256,0,stream>>>(
      xhat5, sX, wTmlp, out, sX, 256, featb2, sX, biasMlp, NF);
}

// Round 7
// 498.645 us; speedup vs baseline: 1.8860x; 1.0415x over previous
//
#include <hip/hip_runtime.h>

#define BB 8
#define NN 4096
#define DD 256
#define HH 4
#define DHH 64
#define KPP 256
#define KNN 128
#define SCH 64   // stats chunks per batch (64 rows each)

typedef float f32x4 __attribute__((ext_vector_type(4)));
typedef short bf16x8 __attribute__((ext_vector_type(8)));
typedef short bf16x4 __attribute__((ext_vector_type(4)));

#define FLAG_TRANSB 1
#define FLAG_RELU   2

__device__ __forceinline__ float bf2f(unsigned short u){
  union { unsigned int i; float f; } v; v.i = ((unsigned int)u) << 16; return v.f;
}
__device__ __forceinline__ unsigned short f2bf(float f){
  union { float f; unsigned int i; } v; v.f = f;
  return (unsigned short)((v.i + 0x7FFFu + ((v.i >> 16) & 1u)) >> 16);
}
__device__ __forceinline__ void gload16(const void* g, void* l){
  __builtin_amdgcn_global_load_lds((const __attribute__((address_space(1))) void*)g,
                                   (__attribute__((address_space(3))) void*)l, 16, 0, 0);
}

// ---------------- masked-mean stats (float4, 4 rows in flight, 512 blocks) ----------------
__global__ __launch_bounds__(256) void stats_part(const float* __restrict__ x,
                                                  const int* __restrict__ mask,
                                                  float* __restrict__ part,
                                                  float* __restrict__ pcnt){
  int b = blockIdx.y, c = blockIdx.x, t = threadIdx.x;
  int w = t >> 6, lane = t & 63;
  const int R = NN / SCH;           // 64 rows per chunk
  int n0 = c * R;
  const float* xb = x + ((long)b*NN + n0)*DD;
  const int* mb = mask + (long)b*NN + n0;
  float4 sp = {0.f,0.f,0.f,0.f}, sn = {0.f,0.f,0.f,0.f};
  int cp = 0, cn = 0;
  #pragma unroll 4
  for (int r = w; r < R; r += 4){
    int mv = mb[r];
    float4 v = ((const float4*)(xb + (long)r*DD))[lane];
    if (mv == 1){ sp.x += v.x; sp.y += v.y; sp.z += v.z; sp.w += v.w; cp++; }
    else if (mv == -1){ sn.x += v.x; sn.y += v.y; sn.z += v.z; sn.w += v.w; cn++; }
  }
  __shared__ float red[2][4][256];
  __shared__ int cnt[2][4];
  ((float4*)&red[0][w][0])[lane] = sp;
  ((float4*)&red[1][w][0])[lane] = sn;
  if (lane == 0){ cnt[0][w] = cp; cnt[1][w] = cn; }
  __syncthreads();
  float s0 = red[0][0][t]+red[0][1][t]+red[0][2][t]+red[0][3][t];
  float s1 = red[1][0][t]+red[1][1][t]+red[1][2][t]+red[1][3][t];
  part[(((long)(b*SCH+c)*2+0)*DD)+t] = s0;
  part[(((long)(b*SCH+c)*2+1)*DD)+t] = s1;
  if (t == 0){
    pcnt[(b*SCH+c)*2+0] = (float)(cnt[0][0]+cnt[0][1]+cnt[0][2]+cnt[0][3]);
    pcnt[(b*SCH+c)*2+1] = (float)(cnt[1][0]+cnt[1][1]+cnt[1][2]+cnt[1][3]);
  }
}

// ---------------- merged stats_final + sim_vec ----------------
__global__ void stats_vec(const float* __restrict__ part, const float* __restrict__ pcnt,
                          const float* __restrict__ Wp, const float* __restrict__ bp,
                          const float* __restrict__ Wn, const float* __restrict__ bn,
                          float* __restrict__ vvec, float* __restrict__ cscal){
  int b = blockIdx.x, k = threadIdx.x;
  __shared__ float qp[256], qn[256], red[256];
  {
    float sp=0.f, sn=0.f, cp=0.f, cn=0.f;
    for (int c = 0; c < SCH; c++){
      sp += part[(((long)(b*SCH+c)*2+0)*DD)+k];
      sn += part[(((long)(b*SCH+c)*2+1)*DD)+k];
      cp += pcnt[(b*SCH+c)*2+0];
      cn += pcnt[(b*SCH+c)*2+1];
    }
    qp[k] = sp / (cp + 1e-6f);
    qn[k] = sn / (cn + 1e-6f);
  }
  __syncthreads();
  float vp = 0.f, vn = 0.f;
  for (int j = 0; j < DD; j++){ vp += Wp[(long)k*DD+j]*qp[j]; vn += Wn[(long)k*DD+j]*qn[j]; }
  vvec[(long)(b*2+0)*DD+k] = vp; vvec[(long)(b*2+1)*DD+k] = vn;
  red[k] = bp[k]*qp[k];
  __syncthreads();
  for (int s = 128; s > 0; s >>= 1){ if (k < s) red[k] += red[k+s]; __syncthreads(); }
  if (k == 0) cscal[b*2+0] = red[0];
  __syncthreads();
  red[k] = bn[k]*qn[k];
  __syncthreads();
  for (int s = 128; s > 0; s >>= 1){ if (k < s) red[k] += red[k+s]; __syncthreads(); }
  if (k == 0) cscal[b*2+1] = red[0];
}

// ---------------- fused sims + LN-core of x ----------------
__global__ void sim_norm_kernel(const float* __restrict__ x, const float* __restrict__ vvec,
                                const float* __restrict__ cscal,
                                float* __restrict__ simP, float* __restrict__ simN,
                                unsigned short* __restrict__ xhat){
  int b = blockIdx.y;
  int w = threadIdx.x >> 6, lane = threadIdx.x & 63;
  int n = blockIdx.x*4 + w;
  long row = (long)b*NN + n;
  const float4* xr = (const float4*)(x + row*DD);
  float4 xv = xr[lane];
  float4 a = ((const float4*)(vvec + (long)(b*2+0)*DD))[lane];
  float4 c = ((const float4*)(vvec + (long)(b*2+1)*DD))[lane];
  float sp = xv.x*a.x + xv.y*a.y + xv.z*a.z + xv.w*a.w;
  float sn = xv.x*c.x + xv.y*c.y + xv.z*c.z + xv.w*c.w;
  float s  = xv.x+xv.y+xv.z+xv.w;
  float q  = xv.x*xv.x+xv.y*xv.y+xv.z*xv.z+xv.w*xv.w;
  for (int off = 32; off; off >>= 1){
    sp += __shfl_xor(sp, off); sn += __shfl_xor(sn, off);
    s  += __shfl_xor(s, off);  q  += __shfl_xor(q, off);
  }
  float m = s*(1.f/256.f);
  float var = q*(1.f/256.f) - m*m;
  float rinv = rsqrtf(var + 1e-5f);
  ushort4 o;
  o.x = f2bf((xv.x-m)*rinv); o.y = f2bf((xv.y-m)*rinv);
  o.z = f2bf((xv.z-m)*rinv); o.w = f2bf((xv.w-m)*rinv);
  ((ushort4*)(xhat + row*DD))[lane] = o;
  if (lane == 0){
    float zp = sp + cscal[b*2+0], zn = sn + cscal[b*2+1];
    simP[row] = 1.f/(1.f+expf(-zp));
    simN[row] = 1.f/(1.f+expf(-zn));
  }
}

// ---------------- top-k (3-pass radix, parallel scans) + fused node gather ----------------
__global__ __launch_bounds__(256) void topk_radix(const float* __restrict__ simP,
                                                  const float* __restrict__ simN,
                                                  const float* __restrict__ x,
                                                  int* __restrict__ idxb, float* __restrict__ wb,
                                                  float* __restrict__ node){
  __shared__ unsigned int vals[4096];
  __shared__ unsigned int hist[4096];
  __shared__ unsigned short eql[4096];
  __shared__ unsigned int tsum[256];
  __shared__ unsigned int sB, sRem, sCG, sCnt, sEq;
  int id = blockIdx.x; int sgn = id & 1, b = id >> 1;
  int K = (sgn == 0) ? KPP : KNN;
  const float* s = (sgn == 0 ? simP : simN) + (long)b*NN;
  int t = threadIdx.x;
  if (t == 0){ sCG = 0; sCnt = 0; sEq = 0; }
  for (int i = t; i < 4096; i += 256){ vals[i] = __float_as_uint(s[i]); hist[i] = 0; }
  __syncthreads();

  auto find_thresh = [&](int NB, unsigned need){
    int per = NB >> 8;
    int base = t*per;
    unsigned local = 0;
    for (int j = 0; j < per; j++) local += hist[base+j];
    tsum[t] = local;
    __syncthreads();
    #pragma unroll
    for (int st = 1; st < 256; st <<= 1){
      unsigned v = (t + st < 256) ? tsum[t+st] : 0u;
      __syncthreads();
      tsum[t] += v;
      __syncthreads();
    }
    unsigned after = (t < 255) ? tsum[t+1] : 0u;
    if (after < need && after + local >= need){
      unsigned c = after;
      for (int j = per-1; j >= 0; j--){
        unsigned h = hist[base+j];
        c += h;
        if (c >= need){
          sB = (unsigned)(base+j);
          sRem = need - (c - h);
          atomicAdd(&sCG, c - h);
          break;
        }
      }
    }
    __syncthreads();
  };

  for (int i = t; i < 4096; i += 256) atomicAdd(&hist[vals[i] >> 20], 1u);
  __syncthreads();
  find_thresh(4096, (unsigned)K);
  unsigned B1 = sB, rem1 = sRem;
  __syncthreads();
  for (int i = t; i < 4096; i += 256) hist[i] = 0;
  __syncthreads();
  for (int i = t; i < 4096; i += 256){
    unsigned v = vals[i];
    if ((v >> 20) == B1) atomicAdd(&hist[(v >> 8) & 0xFFFu], 1u);
  }
  __syncthreads();
  find_thresh(4096, rem1);
  unsigned B2 = sB, rem2 = sRem;
  unsigned pre = (B1 << 12) | B2;
  __syncthreads();
  hist[t] = 0;
  __syncthreads();
  for (int i = t; i < 4096; i += 256){
    unsigned v = vals[i];
    if ((v >> 8) == pre) atomicAdd(&hist[v & 0xFFu], 1u);
  }
  __syncthreads();
  find_thresh(256, rem2);
  unsigned T = (pre << 8) | sB;
  unsigned cg = sCG;
  __syncthreads();
  hist[t] = 0;
  __syncthreads();

  int* oi = idxb + (long)id*256;
  float* ow = wb + (long)id*256;
  for (int i = t; i < 4096; i += 256){
    unsigned v = vals[i];
    if (v > T){
      unsigned p = atomicAdd(&sCnt, 1u);
      oi[p] = i; ow[p] = __uint_as_float(v);
      hist[p] = (unsigned)i; hist[256+p] = v;
    }
    else if (v == T){ unsigned e = atomicAdd(&sEq, 1u); eql[e] = (unsigned short)i; }
  }
  __syncthreads();
  int ne = K - (int)cg;
  int eqn = (int)sEq;
  for (int e = t; e < eqn; e += 256){
    int myi = eql[e]; int r = 0;
    for (int e2 = 0; e2 < eqn; e2++) r += (eql[e2] < myi);
    if (r < ne){
      oi[cg + r] = myi; ow[cg + r] = __uint_as_float(T);
      hist[cg + r] = (unsigned)myi; hist[256 + cg + r] = T;
    }
  }
  __syncthreads();
  int rbase = (sgn == 0) ? 0 : KPP;
  int lane = t & 63, rw = t >> 6;
  for (int i0 = 0; i0 < K; i0 += 4){
    int r = i0 + rw;
    int idx = (int)hist[r];
    float wv = __uint_as_float(hist[256 + r]);
    float4 vsel;
    if (wv > 0.6f) vsel = ((const float4*)(x + ((long)b*NN + idx)*DD))[lane];
    else vsel = (float4){0.f,0.f,0.f,0.f};
    ((float4*)(node + ((long)b*384 + rbase + r)*DD))[lane] = vsel;
  }
}

// ---------------- dual row softmax ----------------
__global__ void softmax_dual(float* __restrict__ A0, int L0, int rpb0, long bs0, int rows0,
                             float* __restrict__ A1, int L1, int rpb1, long bs1, int rows1){
  int w = threadIdx.x >> 6, lane = threadIdx.x & 63;
  long row = (long)blockIdx.x*4 + w;
  float* A; int L, rpb; long bs;
  if (row < rows0){ A = A0; L = L0; rpb = rpb0; bs = bs0; }
  else { row -= rows0; if (row >= rows1) return; A = A1; L = L1; rpb = rpb1; bs = bs1; }
  int b = (int)(row / rpb), r = (int)(row % rpb);
  float* a = A + (long)b*bs + (long)r*L;
  int e = L >> 6;
  float vals[4]; float mx = -1e30f;
  for (int j = 0; j < e; j++){ vals[j] = a[lane*e+j]; mx = fmaxf(mx, vals[j]); }
  for (int off = 32; off; off >>= 1) mx = fmaxf(mx, __shfl_xor(mx, off));
  float sum = 0.f;
  for (int j = 0; j < e; j++){ vals[j] = expf(vals[j]-mx); sum += vals[j]; }
  for (int off = 32; off; off >>= 1) sum += __shfl_xor(sum, off);
  float rinv = 1.f/sum;
  for (int j = 0; j < e; j++) a[lane*e+j] = vals[j]*rinv;
}

// ---------------- row LayerNorm core ----------------
__global__ void rownorm_kernel(const float* __restrict__ X, unsigned short* __restrict__ Y, int rows){
  int w = threadIdx.x >> 6, lane = threadIdx.x & 63;
  long row = (long)blockIdx.x*4 + w;
  if (row >= rows) return;
  const float4* xr = (const float4*)(X + row*DD);
  float4 xv = xr[lane];
  float s = xv.x+xv.y+xv.z+xv.w;
  float q = xv.x*xv.x+xv.y*xv.y+xv.z*xv.z+xv.w*xv.w;
  for (int off = 32; off; off >>= 1){ s += __shfl_xor(s, off); q += __shfl_xor(q, off); }
  float m = s*(1.f/256.f);
  float var = q*(1.f/256.f) - m*m;
  float rinv = rsqrtf(var + 1e-5f);
  ushort4 o;
  o.x = f2bf((xv.x-m)*rinv); o.y = f2bf((xv.y-m)*rinv);
  o.z = f2bf((xv.z-m)*rinv); o.w = f2bf((xv.w-m)*rinv);
  ((ushort4*)(Y + row*DD))[lane] = o;
}

// ---------------- weight fold ----------------
struct FoldArgs { const float* W[9]; const float* g[9]; unsigned short* BT[9]; };
struct BiasArgs { const float* W[7]; const float* b[7]; const float* addb[7]; float* out[7]; };

__global__ void fold_w(FoldArgs fa){
  int m = blockIdx.y, tile = blockIdx.x, t = threadIdx.x;
  const float* W = fa.W[m]; const float* g = fa.g[m]; unsigned short* BT = fa.BT[m];
  __shared__ float T[64][65];
  int tn = (tile & 3)*64, tk = (tile >> 2)*64;
  #pragma unroll 4
  for (int p = 0; p < 16; p++){
    int kl = p*4 + (t >> 6), nl = t & 63;
    float v = W[(long)(tk+kl)*256 + tn + nl];
    if (g) v *= g[tk+kl];
    T[kl][nl] = v;
  }
  __syncthreads();
  #pragma unroll 4
  for (int p = 0; p < 16; p++){
    int nl = p*4 + (t >> 6), kl = t & 63;
    BT[(long)(tn+nl)*256 + tk + kl] = f2bf(T[kl][nl]);
  }
}

__global__ void fold_b(BiasArgs ba){
  int m = blockIdx.x, n = threadIdx.x;
  const float* W = ba.W[m]; const float* b = ba.b[m];
  float s = (ba.addb[m] != nullptr) ? ba.addb[m][n] : 0.f;
  for (int k = 0; k < 256; k++) s += b[k]*W[(long)k*256+n];
  ba.out[m][n] = s;
}

// ---------------- multi-parameter f32 GEMM 64x64 (GCN path) ----------------
struct GP {
  const float* A; long sAb; int lda;
  const float* B; long sBb; int ldb;
  float* C; long sCb; int ldc;
  const int* pidx; const float* pe;
  int M, N, K; float alpha; int flags;
};
struct GP4 { GP p[4]; };

__global__ __launch_bounds__(256) void gemm_multi(GP4 g4){
  GP p = g4.p[blockIdx.z >> 3];
  int b = blockIdx.z & 7;
  int m0 = blockIdx.y*64, n0 = blockIdx.x*64;
  if (m0 >= p.M || n0 >= p.N) return;
  __shared__ __align__(16) unsigned short As[64*40];
  __shared__ __align__(16) unsigned short Bs[64*40];
  const float* Ab = p.A + (long)b*p.sAb;
  const float* Bb = p.B + (long)b*p.sBb;
  int t = threadIdx.x;
  int w = t >> 6, lane = t & 63, lrowi = lane & 15, lquad = lane >> 4;
  int wm = w >> 1, wn = w & 1;
  f32x4 acc[2][2];
  #pragma unroll
  for (int i = 0; i < 2; i++)
    #pragma unroll
    for (int j = 0; j < 2; j++) acc[i][j] = (f32x4){0.f,0.f,0.f,0.f};
  int am = t >> 2, akq = t & 3;
  for (int k0 = 0; k0 < p.K; k0 += 32){
    {
      const float4* s4 = (const float4*)(Ab + (long)(m0+am)*p.lda + k0 + akq*8);
      float4 u = s4[0], vv = s4[1];
      unsigned short tmp[8];
      tmp[0]=f2bf(u.x); tmp[1]=f2bf(u.y); tmp[2]=f2bf(u.z); tmp[3]=f2bf(u.w);
      tmp[4]=f2bf(vv.x); tmp[5]=f2bf(vv.y); tmp[6]=f2bf(vv.z); tmp[7]=f2bf(vv.w);
      *(uint4*)(&As[am*40 + akq*8]) = *(uint4*)tmp;
    }
    if (p.flags & FLAG_TRANSB){
      const float4* s4 = (const float4*)(Bb + (long)(n0+am)*p.ldb + k0 + akq*8);
      float4 u = s4[0], vv = s4[1];
      unsigned short tmp[8];
      tmp[0]=f2bf(u.x); tmp[1]=f2bf(u.y); tmp[2]=f2bf(u.z); tmp[3]=f2bf(u.w);
      tmp[4]=f2bf(vv.x); tmp[5]=f2bf(vv.y); tmp[6]=f2bf(vv.z); tmp[7]=f2bf(vv.w);
      *(uint4*)(&Bs[am*40 + akq*8]) = *(uint4*)tmp;
    } else {
      int bn = t & 63, bkb = (t >> 6)*8;
      #pragma unroll
      for (int j = 0; j < 8; j++)
        Bs[bn*40 + bkb + j] = f2bf(Bb[(long)(k0+bkb+j)*p.ldb + n0 + bn]);
    }
    __syncthreads();
    bf16x8 af[2], bfr[2];
    #pragma unroll
    for (int i = 0; i < 2; i++)
      af[i] = *(const bf16x8*)(&As[(wm*32 + i*16 + lrowi)*40 + lquad*8]);
    #pragma unroll
    for (int j = 0; j < 2; j++)
      bfr[j] = *(const bf16x8*)(&Bs[(wn*32 + j*16 + lrowi)*40 + lquad*8]);
    #pragma unroll
    for (int i = 0; i < 2; i++)
      #pragma unroll
      for (int j = 0; j < 2; j++)
        acc[i][j] = __builtin_amdgcn_mfma_f32_16x16x32_bf16(af[i], bfr[j], acc[i][j], 0, 0, 0);
    __syncthreads();
  }
  float* Cb = p.C + (long)b*p.sCb;
  #pragma unroll
  for (int i = 0; i < 2; i++)
    #pragma unroll
    for (int j = 0; j < 2; j++){
      int col = n0 + wn*32 + j*16 + lrowi;
      #pragma unroll
      for (int r = 0; r < 4; r++){
        int row = m0 + wm*32 + i*16 + lquad*4 + r;
        float v = p.alpha*acc[i][j][r];
        if (p.flags & FLAG_RELU) v = fmaxf(v, 0.f);
        if (p.pidx != nullptr){
          int idx = p.pidx[b*512 + row];
          v += p.pe[(long)idx*256 + col];
        }
        Cb[(long)row*p.ldc + col] = v;
      }
    }
}

// ---------------- fast 128x128 bf16 GEMM (K=256) ----------------
template<typename OT, bool RES, bool GATE>
__global__ __launch_bounds__(256) void gemm128(
    const unsigned short* __restrict__ A, long sAb,
    const unsigned short* __restrict__ BT,
    OT* __restrict__ C, long sCb, int ldc,
    const float* __restrict__ R, long sRb,
    const float* __restrict__ bias, const float* __restrict__ gate)
{
  __shared__ __align__(16) unsigned short As[4096];
  __shared__ __align__(16) unsigned short Bs[4096];
  int t = threadIdx.x;
  int w = t >> 6, lane = t & 63, lrowi = lane & 15, lquad = lane >> 4;
  int wm = w >> 1, wn = w & 1;
  int m0 = blockIdx.y*128, n0 = blockIdx.x*128;
  const unsigned short* Ab = A + (long)blockIdx.z*sAb + (long)m0*256;
  const unsigned short* Bb = BT + (long)n0*256;
  int g0 = t, g1 = 256 + t;
  int row0 = g0 >> 2, kq0 = g0 & 3;
  int row1 = g1 >> 2, kq1 = g1 & 3;
  f32x4 acc[4][4];
  #pragma unroll
  for (int i = 0; i < 4; i++)
    #pragma unroll
    for (int j = 0; j < 4; j++) acc[i][j] = (f32x4){0.f,0.f,0.f,0.f};

  for (int k0 = 0; k0 < 256; k0 += 32){
    gload16(Ab + (long)row0*256 + k0 + kq0*8, &As[g0*8]);
    gload16(Ab + (long)row1*256 + k0 + kq1*8, &As[g1*8]);
    gload16(Bb + (long)row0*256 + k0 + kq0*8, &Bs[g0*8]);
    gload16(Bb + (long)row1*256 + k0 + kq1*8, &Bs[g1*8]);
    __syncthreads();
    bf16x8 af[4], bfr[4];
    #pragma unroll
    for (int i = 0; i < 4; i++)
      af[i] = *(const bf16x8*)(&As[((wm*64 + i*16 + lrowi)*4 + lquad)*8]);
    #pragma unroll
    for (int j = 0; j < 4; j++)
      bfr[j] = *(const bf16x8*)(&Bs[((wn*64 + j*16 + lrowi)*4 + lquad)*8]);
    #pragma unroll
    for (int i = 0; i < 4; i++)
      #pragma unroll
      for (int j = 0; j < 4; j++)
        acc[i][j] = __builtin_amdgcn_mfma_f32_16x16x32_bf16(af[i], bfr[j], acc[i][j], 0, 0, 0);
    __syncthreads();
  }
  OT* Cb = C + (long)blockIdx.z*sCb;
  const float* Rb = RES ? (R + (long)blockIdx.z*sRb) : nullptr;
  #pragma unroll
  for (int j = 0; j < 4; j++){
    int col = n0 + wn*64 + j*16 + lrowi;
    float bv = bias[col];
    float gv = GATE ? gate[col] : 1.f;
    #pragma unroll
    for (int i = 0; i < 4; i++){
      #pragma unroll
      for (int r = 0; r < 4; r++){
        int row = m0 + wm*64 + i*16 + lquad*4 + r;
        float v = acc[i][j][r] + bv;
        if (GATE) v *= gv;
        if (RES) v += Rb[(long)row*256 + col];
        if constexpr (sizeof(OT) == 4) Cb[(long)row*ldc + col] = v;
        else                           Cb[(long)row*ldc + col] = f2bf(v);
      }
    }
  }
}

// ---------------- flash cross-attention, no-max softmax ----------------
template<int NFRAG>
__global__ __launch_bounds__(256) void flash_kernel(
    const unsigned short* __restrict__ Q, long sQb, int ldq,
    const unsigned short* __restrict__ Kt, const unsigned short* __restrict__ Vt,
    long sKb, int ldkv,
    unsigned short* __restrict__ O, long sOb,
    float* __restrict__ Opart, float* __restrict__ Lpart,
    int Nq, int Nk, int nsplit, float scale)
{
  __shared__ __align__(16) unsigned short Kl[32*72];
  __shared__ __align__(16) unsigned short Vl[64*36];
  __shared__ __align__(16) unsigned short Pl[4*NFRAG*16*36];
  int b = blockIdx.z, h = blockIdx.y;
  int nqg = Nq / (64*NFRAG);
  int qg = blockIdx.x % nqg, split = blockIdx.x / nqg;
  int kchunk = Nk / nsplit;
  int kbeg = split*kchunk, kend = kbeg + kchunk;
  int t = threadIdx.x, w = t >> 6, lane = t & 63, lrowi = lane & 15, lquad = lane >> 4;
  int q0 = qg*(64*NFRAG) + w*(16*NFRAG);
  const unsigned short* Qb = Q + (long)b*sQb + h*DHH;
  const unsigned short* Kb = Kt + (long)b*sKb + h*DHH;
  const unsigned short* Vb = Vt + (long)b*sKb + h*DHH;
  bf16x8 qa[NFRAG][2];
  #pragma unroll
  for (int f = 0; f < NFRAG; f++)
    #pragma unroll
    for (int kt = 0; kt < 2; kt++)
      qa[f][kt] = *(const bf16x8*)(Qb + (long)(q0 + f*16 + lrowi)*ldq + kt*32 + lquad*8);

  f32x4 o[NFRAG][4];
  float psum[NFRAG][4];
  #pragma unroll
  for (int f = 0; f < NFRAG; f++)
    #pragma unroll
    for (int cj = 0; cj < 4; cj++){
      o[f][cj] = (f32x4){0.f,0.f,0.f,0.f};
      psum[f][cj] = 0.f;
    }
  int skq = t >> 3, sdq = (t & 7)*8;
  int vkq = t & 31, vdq = (t >> 5)*8;
  unsigned short* Pw = &Pl[w*(NFRAG*16*36)];
  const float ec = scale * 1.44269504089f;

  for (int kt0 = kbeg; kt0 < kend; kt0 += 32){
    {
      uint4 kv = *(const uint4*)(Kb + (long)(kt0+skq)*ldkv + sdq);
      *(uint4*)(&Kl[skq*72 + sdq]) = kv;
      uint4 vv = *(const uint4*)(Vb + (long)(kt0+vkq)*ldkv + vdq);
      const unsigned short* vp = (const unsigned short*)&vv;
      #pragma unroll
      for (int j = 0; j < 8; j++) Vl[(vdq+j)*36 + vkq] = vp[j];
    }
    __syncthreads();
    bf16x8 kb0 = *(const bf16x8*)(&Kl[(0*16+lrowi)*72 + lquad*8]);
    bf16x8 kb1 = *(const bf16x8*)(&Kl[(0*16+lrowi)*72 + 32 + lquad*8]);
    bf16x8 kb2 = *(const bf16x8*)(&Kl[(1*16+lrowi)*72 + lquad*8]);
    bf16x8 kb3 = *(const bf16x8*)(&Kl[(1*16+lrowi)*72 + 32 + lquad*8]);
    union { bf16x8 v8; bf16x4 v4[2]; } vbu[4];
    #pragma unroll
    for (int cj = 0; cj < 4; cj++){
      const unsigned short* vb = &Vl[(cj*16+lrowi)*36 + lquad*8];
      vbu[cj].v4[0] = *(const bf16x4*)vb;
      vbu[cj].v4[1] = *(const bf16x4*)(vb + 4);
    }
    #pragma unroll
    for (int f = 0; f < NFRAG; f++){
      f32x4 S0 = (f32x4){0.f,0.f,0.f,0.f}, S1 = (f32x4){0.f,0.f,0.f,0.f};
      S0 = __builtin_amdgcn_mfma_f32_16x16x32_bf16(qa[f][0], kb0, S0, 0, 0, 0);
      S0 = __builtin_amdgcn_mfma_f32_16x16x32_bf16(qa[f][1], kb1, S0, 0, 0, 0);
      S1 = __builtin_amdgcn_mfma_f32_16x16x32_bf16(qa[f][0], kb2, S1, 0, 0, 0);
      S1 = __builtin_amdgcn_mfma_f32_16x16x32_bf16(qa[f][1], kb3, S1, 0, 0, 0);
      unsigned short* Pf = Pw + f*(16*36);
      #pragma unroll
      for (int r = 0; r < 4; r++){
        float p0 = exp2f(S0[r]*ec);
        float p1 = exp2f(S1[r]*ec);
        psum[f][r] += p0 + p1;
        Pf[(lquad*4+r)*36 + lrowi]      = f2bf(p0);
        Pf[(lquad*4+r)*36 + 16 + lrowi] = f2bf(p1);
      }
    }
    __asm__ volatile("s_waitcnt lgkmcnt(0)" ::: "memory");
    #pragma unroll
    for (int f = 0; f < NFRAG; f++){
      const unsigned short* pp = &Pw[f*(16*36) + lrowi*36 + lquad*8];
      union { bf16x8 v8; bf16x4 v4[2]; } pa;
      pa.v4[0] = *(const bf16x4*)pp;
      pa.v4[1] = *(const bf16x4*)(pp + 4);
      #pragma unroll
      for (int cj = 0; cj < 4; cj++)
        o[f][cj] = __builtin_amdgcn_mfma_f32_16x16x32_bf16(pa.v8, vbu[cj].v8, o[f][cj], 0, 0, 0);
    }
    __syncthreads();
  }
  float lsum[NFRAG][4];
  #pragma unroll
  for (int f = 0; f < NFRAG; f++)
    #pragma unroll
    for (int r = 0; r < 4; r++){
      float s = psum[f][r];
      #pragma unroll
      for (int off = 1; off < 16; off <<= 1) s += __shfl_xor(s, off);
      lsum[f][r] = s;
    }
  if (nsplit > 1){
    int p = (b*HH + h)*nsplit + split;
    float* Op = Opart + (long)p*Nq*DHH;
    #pragma unroll
    for (int f = 0; f < NFRAG; f++)
      #pragma unroll
      for (int r = 0; r < 4; r++){
        int row = q0 + f*16 + lquad*4 + r;
        #pragma unroll
        for (int cj = 0; cj < 4; cj++)
          Op[(long)row*DHH + cj*16 + lrowi] = o[f][cj][r];
        if (lrowi == 0) Lpart[(long)p*Nq + row] = lsum[f][r];
      }
  } else {
    unsigned short* Ob = O + (long)b*sOb + h*DHH;
    #pragma unroll
    for (int f = 0; f < NFRAG; f++)
      #pragma unroll
      for (int r = 0; r < 4; r++){
        float rl = 1.f/lsum[f][r];
        int row = q0 + f*16 + lquad*4 + r;
        #pragma unroll
        for (int cj = 0; cj < 4; cj++)
          Ob[(long)row*DD + cj*16 + lrowi] = f2bf(o[f][cj][r]*rl);
      }
  }
}

// ---------------- flash split combine ----------------
__global__ void flash_combine(const float* __restrict__ Opart, const float* __restrict__ Lpart,
                              unsigned short* __restrict__ O, long sOb, int Nq, int nsplit){
  int gr = blockIdx.x*4 + (threadIdx.x >> 6);
  int d = threadIdx.x & 63;
  int bh = gr / Nq, row = gr % Nq;
  float accO = 0.f, accL = 0.f;
  for (int s = 0; s < nsplit; s++){
    long p = (long)bh*nsplit + s;
    accL += Lpart[p*Nq + row];
    accO += Opart[(p*Nq + row)*DHH + d];
  }
  int b = bh / HH, h = bh % HH;
  O[(long)b*sOb + (long)row*DD + h*DHH + d] = f2bf(accO/accL);
}

// ---------------- host ----------------
extern "C" void kernel_launch(void* const* d_in, const int* in_sizes, int n_in,
                              void* d_out, int out_size, void* d_ws, size_t ws_size,
                              hipStream_t stream) {
  (void)in_sizes; (void)n_in; (void)out_size; (void)ws_size;
  const float* x        = (const float*)d_in[0];
  const int*   mask     = (const int*)d_in[1];
  const float* pos_emb  = (const float*)d_in[2];
  const float* sim_p_w  = (const float*)d_in[3];
  const float* sim_p_b  = (const float*)d_in[4];
  const float* sim_n_w  = (const float*)d_in[5];
  const float* sim_n_b  = (const float*)d_in[6];
  const float* adj_w    = (const float*)d_in[7];
  const float* gnn_p_w1 = (const float*)d_in[8];
  const float* gnn_p_w2 = (const float*)d_in[9];
  const float* gnn_n_w1 = (const float*)d_in[10];
  const float* gnn_n_w2 = (const float*)d_in[11];
  const float* ln1_g = (const float*)d_in[12]; const float* ln1_b = (const float*)d_in[13];
  const float* ln2_g = (const float*)d_in[14]; const float* ln2_b = (const float*)d_in[15];
  const float* ln3_g = (const float*)d_in[16]; const float* ln3_b = (const float*)d_in[17];
  const float* ln4_g = (const float*)d_in[18]; const float* ln4_b = (const float*)d_in[19];
  const float* ln5_g = (const float*)d_in[20]; const float* ln5_b = (const float*)d_in[21];
  const float* i2q_wq = (const float*)d_in[22];
  const float* i2q_wk = (const float*)d_in[23];
  const float* i2q_wv = (const float*)d_in[24];
  const float* i2q_wo = (const float*)d_in[25];
  const float* q2i_wq = (const float*)d_in[26];
  const float* q2i_wk = (const float*)d_in[27];
  const float* q2i_wv = (const float*)d_in[28];
  const float* q2i_wo = (const float*)d_in[29];
  const float* i2q_bo = (const float*)d_in[30];
  const float* q2i_bo = (const float*)d_in[31];
  const float* mlp_w  = (const float*)d_in[32];
  const float* mlp_b  = (const float*)d_in[33];
  const float* g_i2t  = (const float*)d_in[34];
  const float* g_t2i  = (const float*)d_in[35];

  float* out  = (float*)d_out;
  float* simP = out + (size_t)BB*NN*DD;
  float* simN = simP + (size_t)BB*NN;

  char* w8 = (char*)d_ws;
  size_t off = 0;
  auto take = [&](size_t bytes)->void*{
    void* p = (void*)(w8 + off);
    off += (bytes + 255) & ~(size_t)255;
    return p;
  };
  float* part   = (float*)take((size_t)BB*SCH*2*DD*4);
  float* pcnt   = (float*)take((size_t)BB*SCH*2*4);
  float* vvec   = (float*)take((size_t)BB*2*DD*4);
  float* cscal  = (float*)take((size_t)BB*2*4);
  int*   idxb   = (int*)take((size_t)BB*2*256*4);
  float* wb     = (float*)take((size_t)BB*2*256*4);
  float* node   = (float*)take((size_t)BB*384*DD*4);
  float* gA     = (float*)take((size_t)BB*384*DD*4);   // also t3
  float* gadjP  = (float*)take((size_t)BB*256*256*4);
  float* gadjN  = (float*)take((size_t)BB*128*128*4);
  float* query  = (float*)take((size_t)BB*384*DD*4);   // also t1
  float* query2 = (float*)take((size_t)BB*384*DD*4);   // also t2
  unsigned short* xhatq  = (unsigned short*)take((size_t)BB*384*DD*2);
  unsigned short* qh     = (unsigned short*)take((size_t)BB*384*DD*2);
  unsigned short* attnZ  = (unsigned short*)take((size_t)BB*384*DD*2);
  unsigned short* xhatq2 = (unsigned short*)take((size_t)BB*384*DD*2);
  unsigned short* kv2    = (unsigned short*)take((size_t)BB*384*512*2);
  unsigned short* xhat   = (unsigned short*)take((size_t)BB*NN*DD*2);
  unsigned short* kvq    = (unsigned short*)take((size_t)BB*NN*768*2);
  float* featb2 = (float*)take((size_t)BB*NN*DD*4);
  float* Lpart  = (float*)take((size_t)BB*HH*8*384*4);
  unsigned short* wTq1  = (unsigned short*)take((size_t)65536*2);
  unsigned short* wTbig = (unsigned short*)take((size_t)3*65536*2);
  unsigned short* wTkv2 = (unsigned short*)take((size_t)2*65536*2);
  unsigned short* wTmlp = (unsigned short*)take((size_t)65536*2);
  unsigned short* wTo1  = (unsigned short*)take((size_t)65536*2);
  unsigned short* wTo2  = (unsigned short*)take((size_t)65536*2);
  float* biasQ1  = (float*)take(256*4);
  float* biasBig = (float*)take(768*4);
  float* biasKV2 = (float*)take(512*4);
  float* biasMlp = (float*)take(256*4);
  // overlays (disjoint lifetimes):
  float* t1 = query;
  float* t2 = query2;
  float* t3 = gA;
  unsigned short* attn2 = xhat;
  unsigned short* xhat5 = kvq;
  float* Opart = featb2;

  const long sQ  = 384L*DD;
  const long sX  = (long)NN*DD;
  const float* NF = nullptr;

  // ---- weight folds ----
  FoldArgs fa;
  fa.W[0]=i2q_wq; fa.g[0]=ln1_g; fa.BT[0]=wTq1;
  fa.W[1]=i2q_wk; fa.g[1]=ln2_g; fa.BT[1]=wTbig;
  fa.W[2]=i2q_wv; fa.g[2]=ln2_g; fa.BT[2]=wTbig + 256*256;
  fa.W[3]=q2i_wq; fa.g[3]=ln3_g; fa.BT[3]=wTbig + 512*256;
  fa.W[4]=q2i_wk; fa.g[4]=ln4_g; fa.BT[4]=wTkv2;
  fa.W[5]=q2i_wv; fa.g[5]=ln4_g; fa.BT[5]=wTkv2 + 256*256;
  fa.W[6]=mlp_w;  fa.g[6]=ln5_g; fa.BT[6]=wTmlp;
  fa.W[7]=i2q_wo; fa.g[7]=nullptr; fa.BT[7]=wTo1;
  fa.W[8]=q2i_wo; fa.g[8]=nullptr; fa.BT[8]=wTo2;
  fold_w<<<dim3(16,9), 256, 0, stream>>>(fa);
  BiasArgs ba;
  ba.W[0]=i2q_wq; ba.b[0]=ln1_b; ba.addb[0]=nullptr; ba.out[0]=biasQ1;
  ba.W[1]=i2q_wk; ba.b[1]=ln2_b; ba.addb[1]=nullptr; ba.out[1]=biasBig;
  ba.W[2]=i2q_wv; ba.b[2]=ln2_b; ba.addb[2]=nullptr; ba.out[2]=biasBig+256;
  ba.W[3]=q2i_wq; ba.b[3]=ln3_b; ba.addb[3]=nullptr; ba.out[3]=biasBig+512;
  ba.W[4]=q2i_wk; ba.b[4]=ln4_b; ba.addb[4]=nullptr; ba.out[4]=biasKV2;
  ba.W[5]=q2i_wv; ba.b[5]=ln4_b; ba.addb[5]=nullptr; ba.out[5]=biasKV2+256;
  ba.W[6]=mlp_w;  ba.b[6]=ln5_b; ba.addb[6]=mlp_b;   ba.out[6]=biasMlp;
  fold_b<<<7, 256, 0, stream>>>(ba);

  // ---- stats / sims / topk+gather ----
  stats_part<<<dim3(SCH, BB), 256, 0, stream>>>(x, mask, part, pcnt);
  stats_vec<<<BB, 256, 0, stream>>>(part, pcnt, sim_p_w, sim_p_b, sim_n_w, sim_n_b, vvec, cscal);
  sim_norm_kernel<<<dim3(NN/4, BB), 256, 0, stream>>>(x, vvec, cscal, simP, simN, xhat);
  topk_radix<<<2*BB, 256, 0, stream>>>(simP, simN, x, idxb, wb, node);

  // ---- GCN (pos/neg paired) ----
  GP z = {};
  {
    GP4 g;
    g.p[0] = { node, 384L*DD, 256, adj_w, 0, 256, gA, 384L*DD, 256, nullptr, nullptr, 384, 256, 256, 1.f, 0 };
    g.p[1] = { node, 384L*DD, 256, gnn_p_w1, 0, 256, t1, 384L*DD, 256, nullptr, nullptr, 256, 256, 256, 1.f, 0 };
    g.p[2] = { node + 256L*DD, 384L*DD, 256, gnn_n_w1, 0, 256, t1 + 256L*DD, 384L*DD, 256, nullptr, nullptr, 128, 256, 256, 1.f, 0 };
    g.p[3] = z;
    gemm_multi<<<dim3(4,6,3*BB), 256, 0, stream>>>(g);
  }
  {
    GP4 g;
    g.p[0] = { gA, 384L*DD, 256, node, 384L*DD, 256, gadjP, 65536L, 256, nullptr, nullptr, 256, 256, 256, 0.0625f, FLAG_TRANSB };
    g.p[1] = { gA + 256L*DD, 384L*DD, 256, node + 256L*DD, 384L*DD, 256, gadjN, 16384L, 128, nullptr, nullptr, 128, 128, 256, 0.0625f, FLAG_TRANSB };
    g.p[2] = z; g.p[3] = z;
    gemm_multi<<<dim3(4,4,2*BB), 256, 0, stream>>>(g);
  }
  softmax_dual<<<768, 256, 0, stream>>>(gadjP, 256, 256, 65536L, BB*256,
                                        gadjN, 128, 128, 16384L, BB*128);
  {
    GP4 g;
    g.p[0] = { gadjP, 65536L, 256, t1, 384L*DD, 256, t2, 384L*DD, 256, nullptr, nullptr, 256, 256, 256, 1.f, FLAG_RELU };
    g.p[1] = { gadjN, 16384L, 128, t1 + 256L*DD, 384L*DD, 256, t2 + 256L*DD, 384L*DD, 256, nullptr, nullptr, 128, 256, 128, 1.f, FLAG_RELU };
    g.p[2] = z; g.p[3] = z;
    gemm_multi<<<dim3(4,4,2*BB), 256, 0, stream>>>(g);
  }
  {
    GP4 g;
    g.p[0] = { t2, 384L*DD, 256, gnn_p_w2, 0, 256, t3, 384L*DD, 256, nullptr, nullptr, 256, 256, 256, 1.f, 0 };
    g.p[1] = { t2 + 256L*DD, 384L*DD, 256, gnn_n_w2, 0, 256, t3 + 256L*DD, 384L*DD, 256, nullptr, nullptr, 128, 256, 256, 1.f, 0 };
    g.p[2] = z; g.p[3] = z;
    gemm_multi<<<dim3(4,4,2*BB), 256, 0, stream>>>(g);
  }
  {
    GP4 g;
    g.p[0] = { gadjP, 65536L, 256, t3, 384L*DD, 256, query, 384L*DD, 256, idxb, pos_emb, 256, 256, 256, 1.f, 0 };
    g.p[1] = { gadjN, 16384L, 128, t3 + 256L*DD, 384L*DD, 256, query + 256L*DD, 384L*DD, 256, idxb + 256, pos_emb, 128, 256, 128, 1.f, 0 };
    g.p[2] = z; g.p[3] = z;
    gemm_multi<<<dim3(4,4,2*BB), 256, 0, stream>>>(g);
  }

  // ---- LN core of query ----
  rownorm_kernel<<<BB*384/4, 256, 0, stream>>>(query, xhatq, BB*384);

  // (a) qh = xhatq @ wq' + b'
  gemm128<unsigned short,false,false><<<dim3(2,3,BB),256,0,stream>>>(
      xhatq, sQ, wTq1, qh, sQ, 256, NF, 0, biasQ1, NF);
  // (b) [kh|vh|qh2] = xhat @ [wk'|wv'|wq2'] + b'
  gemm128<unsigned short,false,false><<<dim3(6,32,BB),256,0,stream>>>(
      xhat, sX, wTbig, kvq, (long)NN*768, 768, NF, 0, biasBig, NF);
  // i2q flash (NFRAG=3, K-split 8) + combine
  flash_kernel<3><<<dim3(2*8, HH, BB), 256, 0, stream>>>(
      qh, sQ, 256, kvq, kvq + 256, (long)NN*768, 768,
      attnZ, sQ, Opart, Lpart, 384, NN, 8, 0.125f);
  flash_combine<<<BB*HH*384/4, 256, 0, stream>>>(Opart, Lpart, attnZ, sQ, 384, 8);
  // (c) query2 = query + g_i2t .* (attnZ @ wo + bo)
  gemm128<float,true,true><<<dim3(2,3,BB),256,0,stream>>>(
      attnZ, sQ, wTo1, query2, sQ, 256, query, sQ, i2q_bo, g_i2t);

  // ---- q2i ----
  rownorm_kernel<<<BB*384/4, 256, 0, stream>>>(query2, xhatq2, BB*384);
  // (d) [k2|v2] = xhatq2 @ [wk2'|wv2'] + b'
  gemm128<unsigned short,false,false><<<dim3(4,3,BB),256,0,stream>>>(
      xhatq2, sQ, wTkv2, kv2, 384L*512, 512, NF, 0, biasKV2, NF);
  flash_kernel<2><<<dim3(32, HH, BB), 256, 0, stream>>>(
      kvq + 512, (long)NN*768, 768, kv2, kv2 + 256, 384L*512, 512,
      attn2, sX, nullptr, nullptr, NN, 384, 1, 0.125f);
  // (e) featb2 = x + g_t2i .* (attn2 @ wo + bo)
  gemm128<float,true,true><<<dim3(2,32,BB),256,0,stream>>>(
      attn2, sX, wTo2, featb2, sX, 256, x, sX, q2i_bo, g_t2i);

  // ---- final MLP ----
  rownorm_kernel<<<BB*NN/4, 256, 0, stream>>>(featb2, xhat5, BB*NN);
  gemm128<float,true,false><<<dim3(2,32,BB),256,0,stream>>>(
      xhat5, sX, wTmlp, out, sX, 256, featb2, sX, biasMlp, NF);
}